// Round 13
// baseline (492.207 us; speedup 1.0000x reference)
//
#include <hip/hip_runtime.h>
#include <stdint.h>

#define DIM 512
#define NHD 16
#define HD 32
#define NTOK 16384

typedef unsigned short u16;
typedef __attribute__((ext_vector_type(8))) short short8;  // 8 bf16 (4 VGPRs)
typedef __attribute__((ext_vector_type(4))) float f32x4;

__device__ __forceinline__ float bflo(unsigned u){ union{unsigned i; float f;} c; c.i=u<<16; return c.f; }
__device__ __forceinline__ float bfhi(unsigned u){ union{unsigned i; float f;} c; c.i=u&0xffff0000u; return c.f; }
__device__ __forceinline__ u16 f2bf(float f){ union{float f; unsigned i;} c; c.f=f; unsigned r=(c.i + 0x7fffu + ((c.i>>16)&1u))>>16; return (u16)r; }

__device__ __forceinline__ int win_to_tok(int r, int shifted){
  int win = r >> 7, n = r & 127;
  int a = win >> 6, b = (win >> 3) & 7, c = win & 7;
  int ic = n >> 6, ih = (n >> 3) & 7, iw = n & 7;
  int gc = a*2 + ic, gh = b*8 + ih, gw = c*8 + iw;
  if (shifted){ gc = (gc + 1) & 3; gh = (gh + 4) & 63; gw = (gw + 4) & 63; }
  return (gc << 12) + (gh << 6) + gw;
}

__device__ __forceinline__ void gload16(const void* g, void* l){
  __builtin_amdgcn_global_load_lds(
    (const __attribute__((address_space(1))) unsigned int*)(unsigned long long)g,
    (__attribute__((address_space(3))) unsigned int*)(unsigned int)(unsigned long long)l,
    16, 0, 0);
}

// ---------------- weight transpose + bf16 cast (batched over 2 model-blocks via z) ----------------
__global__ __launch_bounds__(256)
void transpose_kernel(const float* __restrict__ W, u16* __restrict__ Wt, int K, int N)
{
  __shared__ float t[32][33];
  size_t zoff = (size_t)blockIdx.z * K * N;
  int n0 = blockIdx.x*32, k0 = blockIdx.y*32;
  int tx = threadIdx.x & 31, ty = threadIdx.x >> 5;
  #pragma unroll
  for (int i=0;i<4;i++) t[ty + i*8][tx] = W[zoff + (size_t)(k0 + ty + i*8)*N + n0 + tx];
  __syncthreads();
  #pragma unroll
  for (int i=0;i<4;i++) Wt[zoff + (size_t)(n0 + ty + i*8)*K + k0 + tx] = f2bf(t[tx][ty + i*8]);
}

// ---------------- fused first-LN: reads f32 x, writes LN->bufA (window order) AND raw bf16 -> xbf ----------------
__global__ __launch_bounds__(256)
void ln_f32cvt_kernel(const float* __restrict__ x, const float* __restrict__ g,
                      const float* __restrict__ b, u16* __restrict__ out, u16* __restrict__ xbf)
{
  int wave = threadIdx.x >> 6, lane = threadIdx.x & 63;
  int r = blockIdx.x * 4 + wave;
  int src = win_to_tok(r, 0);
  const float4* xr = (const float4*)(x + (size_t)src * DIM);
  float4 v0 = xr[lane*2], v1 = xr[lane*2+1];
  float xv[8] = {v0.x,v0.y,v0.z,v0.w,v1.x,v1.y,v1.z,v1.w};
  union{u16 us[8]; uint4 u;} raw;
  #pragma unroll
  for (int j=0;j<8;j++) raw.us[j] = f2bf(xv[j]);
  ((uint4*)(xbf + (size_t)src*DIM))[lane] = raw.u;
  float s = 0.f, sq = 0.f;
  #pragma unroll
  for (int j=0;j<8;j++){ s += xv[j]; sq += xv[j]*xv[j]; }
  #pragma unroll
  for (int o=32;o;o>>=1){ s += __shfl_xor(s,o); sq += __shfl_xor(sq,o); }
  float mean = s*(1.f/DIM);
  float var  = sq*(1.f/DIM) - mean*mean;
  float rstd = rsqrtf(var + 1e-5f);
  int c0 = lane*8;
  const float4* g4 = (const float4*)(g + c0);
  const float4* b4 = (const float4*)(b + c0);
  float4 ga = g4[0], gb = g4[1], ba = b4[0], bb = b4[1];
  float gg[8] = {ga.x,ga.y,ga.z,ga.w,gb.x,gb.y,gb.z,gb.w};
  float bv[8] = {ba.x,ba.y,ba.z,ba.w,bb.x,bb.y,bb.z,bb.w};
  union{u16 us[8]; uint4 u;} p;
  #pragma unroll
  for (int j=0;j<8;j++) p.us[j] = f2bf((xv[j]-mean)*rstd*gg[j] + bv[j]);
  ((uint4*)(out + (size_t)r*DIM))[lane] = p.u;
}

// ---------------- LayerNorm on bf16 residual (+optional window gather w/ roll) -> bf16 ----------------
__global__ __launch_bounds__(256)
void ln_kernel(const u16* __restrict__ x, const float* __restrict__ g,
               const float* __restrict__ b, u16* __restrict__ out, int mode)
{
  int wave = threadIdx.x >> 6, lane = threadIdx.x & 63;
  int r = blockIdx.x * 4 + wave;
  int src = (mode < 0) ? r : win_to_tok(r, mode);
  uint4 u = ((const uint4*)(x + (size_t)src * DIM))[lane];
  unsigned w[4] = {u.x, u.y, u.z, u.w};
  float xv[8];
  #pragma unroll
  for (int j=0;j<4;j++){ xv[2*j] = bflo(w[j]); xv[2*j+1] = bfhi(w[j]); }
  float s = 0.f, sq = 0.f;
  #pragma unroll
  for (int j=0;j<8;j++){ s += xv[j]; sq += xv[j]*xv[j]; }
  #pragma unroll
  for (int o=32;o;o>>=1){ s += __shfl_xor(s,o); sq += __shfl_xor(sq,o); }
  float mean = s*(1.f/DIM);
  float var  = sq*(1.f/DIM) - mean*mean;
  float rstd = rsqrtf(var + 1e-5f);
  int c0 = lane*8;
  const float4* g4 = (const float4*)(g + c0);
  const float4* b4 = (const float4*)(b + c0);
  float4 ga = g4[0], gb = g4[1], ba = b4[0], bb = b4[1];
  float gg[8] = {ga.x,ga.y,ga.z,ga.w,gb.x,gb.y,gb.z,gb.w};
  float bv[8] = {ba.x,ba.y,ba.z,ba.w,bb.x,bb.y,bb.z,bb.w};
  union{u16 us[8]; uint4 u;} p;
  #pragma unroll
  for (int j=0;j<8;j++) p.us[j] = f2bf((xv[j]-mean)*rstd*gg[j] + bv[j]);
  ((uint4*)(out + (size_t)r*DIM))[lane] = p.u;
}

// ============ gemm32w: 128x128 tile, BK=32, WAVE-PRIVATE double-buffer, ZERO K-loop barriers ============
// Each wave owns 16KB LDS: {A0,B0,A1,B1} x 4KB and stages its OWN 64x32 A/B halves.
// Pipeline per wave: ds_read(8) -> lgkmcnt(0) -> stage t+2 into freed buf -> 16 MFMA -> vmcnt(8).
// No cross-wave LDS sharing => no barriers until the epilogue repack.
// EPI 0: store bf16 (qkv)        EPI 1: scatter += into bf16 residual (proj, win_rev+roll)
// EPI 2: tanh-gelu -> bf16 (fc1) EPI 3: += bf16 residual (fc2 block0)
// EPI 4: final fc2: read bf16 residual, add, write f32 d_out
template<int EPI>
__global__ __launch_bounds__(256)
void gemm32w_kernel(const u16* __restrict__ X, const u16* __restrict__ Wt,
                    const float* __restrict__ bias, u16* __restrict__ obf,
                    u16* __restrict__ xbf, float* __restrict__ outf,
                    int M, int N, int K, int shifted)
{
  __shared__ u16 smem[32768];    // 64KB: wave w region @ w*8192; buf c: A @ +c*4096, B @ +c*4096+2048
  int tid = threadIdx.x, wave = tid>>6, lane = tid&63;
  int nwg = gridDim.x * gridDim.y;
  int bid = blockIdx.y * gridDim.x + blockIdx.x;
  int wg  = (bid & 7) * (nwg >> 3) + (bid >> 3);
  int n0 = (wg % gridDim.x) * 128;
  int m0 = (wg / gridDim.x) * 128;
  int wm = (wave>>1)*64, wn = (wave&1)*64;
  f32x4 acc[4][4] = {};

  // staging decode (wave-private [64][32], dest chunk = q*64+lane):
  // u = (lane&7)^(lane>>3); row(q) = q*16 + (lane>>3)*2 + (u>>2); chunk c = u&3
  int u_ = (lane&7) ^ (lane>>3);
  int rbase = ((lane>>3)<<1) + (u_>>2);
  int cofs8 = (u_&3)*8;

  const u16* Abase = X  + (size_t)(m0 + wm)*K;
  const u16* Bbase = Wt + (size_t)(n0 + wn)*K;
  u16* wreg = smem + wave*8192;

  auto stage = [&](int c, int kb){
    u16* Ad = wreg + c*4096;
    u16* Bd = Ad + 2048;
    #pragma unroll
    for (int q=0;q<4;q++)
      gload16(Abase + (size_t)(q*16 + rbase)*K + kb + cofs8, (void*)(Ad + q*512 + lane*8));
    #pragma unroll
    for (int q=0;q<4;q++)
      gload16(Bbase + (size_t)(q*16 + rbase)*K + kb + cofs8, (void*)(Bd + q*512 + lane*8));
  };
  auto ldfrag = [&](const u16* base, int row0)->short8 {
    int r = row0 + (lane&15);
    int slot = (((r&1)<<2) + (lane>>4)) ^ ((r>>1)&7);
    return *(const short8*)((const char*)base + (r>>1)*128 + slot*16);
  };

  int nt = K >> 5;
  stage(0, 0); stage(1, 32);
  asm volatile("s_waitcnt vmcnt(8)" ::: "memory");   // buf0's 8 retired; buf1's 8 in flight
  __builtin_amdgcn_sched_barrier(0);

  for (int t=0; t<nt; ++t){
    int cur = t & 1;
    const u16* Ab = wreg + cur*4096;
    const u16* Bb = Ab + 2048;
    short8 af[4], bfr[4];
    #pragma unroll
    for (int mi=0;mi<4;mi++) af[mi]  = ldfrag(Ab, mi*16);
    #pragma unroll
    for (int nj=0;nj<4;nj++) bfr[nj] = ldfrag(Bb, nj*16);
    asm volatile("s_waitcnt lgkmcnt(0)" ::: "memory");   // wave-local: reads of cur complete
    __builtin_amdgcn_sched_barrier(0);
    if (t+2 < nt) stage(cur, (t+2)<<5);                  // restage freed buffer, 2 ahead
    __builtin_amdgcn_s_setprio(1);
    #pragma unroll
    for (int mi=0;mi<4;mi++)
      #pragma unroll
      for (int nj=0;nj<4;nj++)
        acc[mi][nj] = __builtin_amdgcn_mfma_f32_16x16x32_bf16(af[mi], bfr[nj], acc[mi][nj], 0,0,0);
    __builtin_amdgcn_s_setprio(0);
    if (t+1 < nt){
      if (t+2 < nt) asm volatile("s_waitcnt vmcnt(8)" ::: "memory");  // t+1 resident, t+2 in flight
      else          asm volatile("s_waitcnt vmcnt(0)" ::: "memory");
      __builtin_amdgcn_sched_barrier(0);
    }
  }

  // ---- epilogue: one block-wide sync, then LDS repack (swizzled) -> coalesced global ----
  __syncthreads();
  int lr = (lane>>4)*4, lc = lane&15;
  if (EPI==0 || EPI==2){
    u16* et = smem;                         // [128][128] bf16 = 32KB, byte ^= ((row>>2)&3)<<5
    #pragma unroll
    for (int mi=0;mi<4;mi++){
      #pragma unroll
      for (int nj=0;nj<4;nj++){
        int col = wn + nj*16 + lc;
        float bv = bias[n0 + col];
        #pragma unroll
        for (int rr=0;rr<4;rr++){
          int row = wm + mi*16 + lr + rr;
          float v = acc[mi][nj][rr] + bv;
          if (EPI==2){
            float u2 = v*(1.5957691216057308f + 0.0713548162726f*v*v);
            v = v * __builtin_amdgcn_rcpf(1.f + __expf(-u2));   // tanh-GELU
          }
          *(u16*)((char*)et + ((row*256 + col*2) ^ (((row>>2)&3)<<5))) = f2bf(v);
        }
      }
    }
    __syncthreads();
    #pragma unroll
    for (int j=0;j<8;j++){
      int q = j*256 + tid;
      int row = q>>4, cc = q&15;
      uint4 d = *(const uint4*)((char*)et + ((row*256 + cc*16) ^ (((row>>2)&3)<<5)));
      *(uint4*)(obf + (size_t)(m0+row)*N + n0 + cc*8) = d;
    }
  } else {
    // EPI 1/3/4: f32 repack in two 64-row halves, then bf16-residual RMW (or f32 final store)
    float* et = (float*)smem;               // [64][128] f32 = 32KB, byte ^= ((row>>2)&1)<<6
    #pragma unroll
    for (int half=0; half<2; ++half){
      __syncthreads();
      if ((wm>>6) == half){
        #pragma unroll
        for (int mi=0;mi<4;mi++){
          #pragma unroll
          for (int nj=0;nj<4;nj++){
            int col = wn + nj*16 + lc;
            float bv = bias[n0 + col];
            #pragma unroll
            for (int rr=0;rr<4;rr++){
              int row = (wm & 63) + mi*16 + lr + rr;
              *(float*)((char*)et + ((row*512 + col*4) ^ (((row>>2)&1)<<6))) = acc[mi][nj][rr] + bv;
            }
          }
        }
      }
      __syncthreads();
      #pragma unroll
      for (int j=0;j<4;j++){
        int q = j*256 + tid;                // 1024 chunks of 8 cols
        int row = q>>4, c8 = q&15;
        int swz = ((row>>2)&1)<<6;
        float4 d0 = *(const float4*)((char*)et + ((row*512 + c8*32     ) ^ swz));
        float4 d1 = *(const float4*)((char*)et + ((row*512 + c8*32 + 16) ^ swz));
        int lrow = m0 + half*64 + row;
        int grow = (EPI==1) ? win_to_tok(lrow, shifted) : lrow;
        size_t gofs = (size_t)grow*DIM + n0 + c8*8;
        uint4 xv = *(const uint4*)(xbf + gofs);
        unsigned xw[4] = {xv.x, xv.y, xv.z, xv.w};
        float xs[8];
        #pragma unroll
        for (int k2=0;k2<4;k2++){ xs[2*k2] = bflo(xw[k2]); xs[2*k2+1] = bfhi(xw[k2]); }
        float ds[8] = {d0.x,d0.y,d0.z,d0.w,d1.x,d1.y,d1.z,d1.w};
        if (EPI==4){
          float4 o0 = {xs[0]+ds[0], xs[1]+ds[1], xs[2]+ds[2], xs[3]+ds[3]};
          float4 o1 = {xs[4]+ds[4], xs[5]+ds[5], xs[6]+ds[6], xs[7]+ds[7]};
          float4* op = (float4*)(outf + gofs);
          op[0] = o0; op[1] = o1;
        } else {
          union{u16 us[8]; uint4 u;} nw;
          #pragma unroll
          for (int k2=0;k2<8;k2++) nw.us[k2] = f2bf(xs[k2] + ds[k2]);
          *(uint4*)(xbf + gofs) = nw.u;
        }
      }
    }
  }
}

// ---------------- rel-pos bias expansion: biasM[h][q][k] ----------------
__global__ __launch_bounds__(256)
void bias_kernel(const float* __restrict__ btab, float* __restrict__ biasM)
{
  int gid = blockIdx.x*256 + threadIdx.x;   // 16*128*128
  int q = (gid >> 7) & 127, k = gid & 127, h = gid >> 14;
  int ic=q>>6, ih=(q>>3)&7, iw=q&7, jc=k>>6, jh=(k>>3)&7, jw=k&7;
  int idx = (ic-jc+1)*225 + (ih-jh+7)*15 + (iw-jw+7);
  biasM[gid] = btab[idx*16 + h];
}

// ---------------- MFMA windowed attention ----------------
__global__ __launch_bounds__(256)
void attn_kernel(const u16* __restrict__ qkv, const float* __restrict__ biasM,
                 u16* __restrict__ out, int shifted)
{
  __shared__ u16 Ks[128*32];
  __shared__ u16 VsT[32*128];
  __shared__ u16 Ps[4][32*128];
  __shared__ int rid[128];
  int win = blockIdx.x >> 4, h = blockIdx.x & 15;
  int tid = threadIdx.x, wave = tid>>6, lane = tid&63;
  size_t base = (size_t)win*128*1536 + (size_t)h*32;

  {
    int m = tid>>1, half = tid&1;
    const uint4* ks = (const uint4*)(qkv + base + (size_t)m*1536 + 512 + half*16);
    uint4 k0v = ks[0], k1v = ks[1];
    char* krow = (char*)Ks + m*64;
    int c0 = half*32, sw = (m&3)<<4;
    *(uint4*)(krow + ((c0     ) ^ sw)) = k0v;
    *(uint4*)(krow + ((c0 + 16) ^ sw)) = k1v;
    const uint4* vs = (const uint4*)(qkv + base + (size_t)m*1536 + 1024 + half*16);
    union{u16 us[16]; uint4 u[2];} vv; vv.u[0]=vs[0]; vv.u[1]=vs[1];
    #pragma unroll
    for (int j=0;j<16;j++){
      int d = half*16 + j;
      *(u16*)((char*)VsT + ((d*256 + m*2) ^ ((d&7)<<4))) = vv.us[j];
    }
  }
  if (shifted && tid < 128){
    int a=win>>6, b=(win>>3)&7, c=win&7;
    int gc=a*2+(tid>>6), gh=b*8+((tid>>3)&7), gw=c*8+(tid&7);
    int rc = (gc<2)?0:((gc<3)?1:2);
    int rh = (gh<56)?0:((gh<60)?1:2);
    int rw = (gw<56)?0:((gw<60)?1:2);
    rid[tid] = rc*9 + rh*3 + rw;
  }
  __syncthreads();

  int q0 = wave*32;
  short8 qf[2];
  #pragma unroll
  for (int mi=0;mi<2;mi++){
    int ql = 16*mi + (lane&15);
    qf[mi] = *(const short8*)(qkv + base + (size_t)(q0+ql)*1536 + (lane>>4)*8);
  }
  f32x4 s[2][8] = {};
  #pragma unroll
  for (int nj=0;nj<8;nj++){
    int row = (lane&15) + 16*nj;
    short8 kf = *(const short8*)((char*)Ks + row*64 + ((((lane>>4)<<4)) ^ ((row&3)<<4)));
    #pragma unroll
    for (int mi=0;mi<2;mi++)
      s[mi][nj] = __builtin_amdgcn_mfma_f32_16x16x32_bf16(qf[mi], kf, s[mi][nj], 0,0,0);
  }

  int rk[8];
  if (shifted){
    #pragma unroll
    for (int nj=0;nj<8;nj++) rk[nj] = rid[(lane&15) + 16*nj];
  }
  float invl[2][4];
  char* pbase = (char*)Ps[wave];
  #pragma unroll
  for (int mi=0;mi<2;mi++){
    #pragma unroll
    for (int r=0;r<4;r++){
      int ql = 16*mi + ((lane>>4)<<2) + r;
      int qw = q0 + ql;
      const float* bp = biasM + (((h<<7) + qw)<<7) + (lane&15);
      int rq = shifted ? rid[qw] : 0;
      float sv[8]; float mx = -1e30f;
      #pragma unroll
      for (int nj=0;nj<8;nj++){
        float v = s[mi][nj][r] * 0.17677669529663687f + bp[nj*16];
        if (shifted && rk[nj] != rq) v -= 100.f;
        sv[nj] = v; mx = fmaxf(mx, v);
      }
      #pragma unroll
      for (int o=1;o<16;o<<=1) mx = fmaxf(mx, __shfl_xor(mx, o));
      float sum = 0.f;
      #pragma unroll
      for (int nj=0;nj<8;nj++){ float p = __expf(sv[nj]-mx); sv[nj]=p; sum += p; }
      #pragma unroll
      for (int o=1;o<16;o<<=1) sum += __shfl_xor(sum, o);
      invl[mi][r] = 1.f/sum;
      char* prow = pbase + ql*256;
      int sw = (ql&7)<<4;
      #pragma unroll
      for (int nj=0;nj<8;nj++)
        *(u16*)(prow + ((((lane&15) + (nj<<4))<<1) ^ sw)) = f2bf(sv[nj]);
    }
  }

  f32x4 o2[2][2] = {};
  #pragma unroll
  for (int kk=0;kk<4;kk++){
    int coff = kk*64 + ((lane>>4)<<4);
    short8 pa[2], vb[2];
    #pragma unroll
    for (int mi=0;mi<2;mi++){
      int ql = 16*mi + (lane&15);
      pa[mi] = *(const short8*)(pbase + ql*256 + (coff ^ ((ql&7)<<4)));
    }
    #pragma unroll
    for (int nj=0;nj<2;nj++){
      int d = (lane&15) + 16*nj;
      vb[nj] = *(const short8*)((char*)VsT + d*256 + (coff ^ ((d&7)<<4)));
    }
    #pragma unroll
    for (int mi=0;mi<2;mi++)
      #pragma unroll
      for (int nj=0;nj<2;nj++)
        o2[mi][nj] = __builtin_amdgcn_mfma_f32_16x16x32_bf16(pa[mi], vb[nj], o2[mi][nj], 0,0,0);
  }

  #pragma unroll
  for (int mi=0;mi<2;mi++){
    #pragma unroll
    for (int nj=0;nj<2;nj++){
      #pragma unroll
      for (int r=0;r<4;r++){
        int ql = 16*mi + ((lane>>4)<<2) + r;
        int d  = (lane&15) + (nj<<4);
        out[(size_t)(win*128 + q0 + ql)*DIM + (h<<5) + d] = f2bf(o2[mi][nj][r] * invl[mi][r]);
      }
    }
  }
}

// ---------------- host launcher ----------------
extern "C" void kernel_launch(void* const* d_in, const int* in_sizes, int n_in,
                              void* d_out, int out_size, void* d_ws, size_t ws_size,
                              hipStream_t stream)
{
  const float* x_in   = (const float*)d_in[0];
  const float* ln1_g  = (const float*)d_in[1];
  const float* ln1_b  = (const float*)d_in[2];
  const float* qkv_w  = (const float*)d_in[3];
  const float* qkv_b  = (const float*)d_in[4];
  const float* btab   = (const float*)d_in[5];
  const float* proj_w = (const float*)d_in[6];
  const float* proj_b = (const float*)d_in[7];
  const float* ln2_g  = (const float*)d_in[8];
  const float* ln2_b  = (const float*)d_in[9];
  const float* fc1_w  = (const float*)d_in[10];
  const float* fc1_b  = (const float*)d_in[11];
  const float* fc2_w  = (const float*)d_in[12];
  const float* fc2_b  = (const float*)d_in[13];

  char* ws = (char*)d_ws;
  size_t off = 0;
  auto alloc = [&](size_t bytes)->char*{ char* p = ws + off; off += (bytes + 255) & ~(size_t)255; return p; };
  u16* wT_qkv = (u16*)alloc((size_t)2*512*1536*2);
  u16* wT_proj= (u16*)alloc((size_t)2*512*512*2);
  u16* wT_fc1 = (u16*)alloc((size_t)2*2048*512*2);
  u16* wT_fc2 = (u16*)alloc((size_t)2*512*2048*2);
  u16* bufA   = (u16*)alloc((size_t)16384*2048*2);
  u16* bufQ   = (u16*)alloc((size_t)16384*1536*2);
  u16* bufB   = (u16*)alloc((size_t)16384*512*2);
  u16* xbf    = (u16*)alloc((size_t)16384*512*2);
  float* biasM= (float*)alloc((size_t)16*128*128*4);
  (void)ws_size; (void)in_sizes; (void)n_in; (void)out_size;

  float* xout = (float*)d_out;

  transpose_kernel<<<dim3(1536/32, 512/32, 2), 256, 0, stream>>>(qkv_w, wT_qkv, 512, 1536);
  transpose_kernel<<<dim3( 512/32, 512/32, 2), 256, 0, stream>>>(proj_w, wT_proj, 512, 512);
  transpose_kernel<<<dim3(2048/32, 512/32, 2), 256, 0, stream>>>(fc1_w, wT_fc1, 512, 2048);
  transpose_kernel<<<dim3( 512/32,2048/32, 2), 256, 0, stream>>>(fc2_w, wT_fc2, 2048, 512);

  for (int i=0;i<2;i++){
    if (i==0)
      ln_f32cvt_kernel<<<4096, 256, 0, stream>>>(x_in, ln1_g, ln1_b, bufA, xbf);
    else
      ln_kernel<<<4096, 256, 0, stream>>>(xbf, ln1_g+512, ln1_b+512, bufA, 1);
    gemm32w_kernel<0><<<dim3(12,128), 256, 0, stream>>>(bufA, wT_qkv+(size_t)i*512*1536, qkv_b+i*1536, bufQ, nullptr, nullptr, NTOK,1536,512, 0);
    bias_kernel<<<1024, 256, 0, stream>>>(btab + (size_t)i*675*16, biasM);
    attn_kernel<<<2048, 256, 0, stream>>>(bufQ, biasM, bufB, i);
    gemm32w_kernel<1><<<dim3(4,128), 256, 0, stream>>>(bufB, wT_proj+(size_t)i*512*512, proj_b+i*512, nullptr, xbf, nullptr, NTOK,512,512, i);
    ln_kernel<<<4096, 256, 0, stream>>>(xbf, ln2_g+i*512, ln2_b+i*512, bufB, -1);
    gemm32w_kernel<2><<<dim3(16,128), 256, 0, stream>>>(bufB, wT_fc1+(size_t)i*2048*512, fc1_b+i*2048, bufA, nullptr, nullptr, NTOK,2048,512, 0);
    if (i==0)
      gemm32w_kernel<3><<<dim3(4,128), 256, 0, stream>>>(bufA, wT_fc2+(size_t)i*512*2048, fc2_b+i*512, nullptr, xbf, nullptr, NTOK,512,2048, 0);
    else
      gemm32w_kernel<4><<<dim3(4,128), 256, 0, stream>>>(bufA, wT_fc2+(size_t)i*512*2048, fc2_b+i*512, nullptr, xbf, xout, NTOK,512,2048, 0);
  }
}

// Round 14
// 455.189 us; speedup vs baseline: 1.0813x; 1.0813x over previous
//
#include <hip/hip_runtime.h>
#include <stdint.h>

#define DIM 512
#define NHD 16
#define HD 32
#define NTOK 16384

typedef unsigned short u16;
typedef __attribute__((ext_vector_type(8))) short short8;  // 8 bf16 (4 VGPRs)
typedef __attribute__((ext_vector_type(4))) float f32x4;

__device__ __forceinline__ float bflo(unsigned u){ union{unsigned i; float f;} c; c.i=u<<16; return c.f; }
__device__ __forceinline__ float bfhi(unsigned u){ union{unsigned i; float f;} c; c.i=u&0xffff0000u; return c.f; }
__device__ __forceinline__ u16 f2bf(float f){ union{float f; unsigned i;} c; c.f=f; unsigned r=(c.i + 0x7fffu + ((c.i>>16)&1u))>>16; return (u16)r; }

__device__ __forceinline__ int win_to_tok(int r, int shifted){
  int win = r >> 7, n = r & 127;
  int a = win >> 6, b = (win >> 3) & 7, c = win & 7;
  int ic = n >> 6, ih = (n >> 3) & 7, iw = n & 7;
  int gc = a*2 + ic, gh = b*8 + ih, gw = c*8 + iw;
  if (shifted){ gc = (gc + 1) & 3; gh = (gh + 4) & 63; gw = (gw + 4) & 63; }
  return (gc << 12) + (gh << 6) + gw;
}

__device__ __forceinline__ void gload16(const void* g, void* l){
  __builtin_amdgcn_global_load_lds(
    (const __attribute__((address_space(1))) unsigned int*)(unsigned long long)g,
    (__attribute__((address_space(3))) unsigned int*)(unsigned int)(unsigned long long)l,
    16, 0, 0);
}

// ---------------- weight transpose + bf16 cast (batched over 2 model-blocks via z) ----------------
__global__ __launch_bounds__(256)
void transpose_kernel(const float* __restrict__ W, u16* __restrict__ Wt, int K, int N)
{
  __shared__ float t[32][33];
  size_t zoff = (size_t)blockIdx.z * K * N;
  int n0 = blockIdx.x*32, k0 = blockIdx.y*32;
  int tx = threadIdx.x & 31, ty = threadIdx.x >> 5;
  #pragma unroll
  for (int i=0;i<4;i++) t[ty + i*8][tx] = W[zoff + (size_t)(k0 + ty + i*8)*N + n0 + tx];
  __syncthreads();
  #pragma unroll
  for (int i=0;i<4;i++) Wt[zoff + (size_t)(n0 + ty + i*8)*K + k0 + tx] = f2bf(t[tx][ty + i*8]);
}

// ---------------- fused first-LN: reads f32 x, writes LN->bufA (window order) AND raw bf16 -> xbf ----------------
__global__ __launch_bounds__(256)
void ln_f32cvt_kernel(const float* __restrict__ x, const float* __restrict__ g,
                      const float* __restrict__ b, u16* __restrict__ out, u16* __restrict__ xbf)
{
  int wave = threadIdx.x >> 6, lane = threadIdx.x & 63;
  int r = blockIdx.x * 4 + wave;
  int src = win_to_tok(r, 0);
  const float4* xr = (const float4*)(x + (size_t)src * DIM);
  float4 v0 = xr[lane*2], v1 = xr[lane*2+1];
  float xv[8] = {v0.x,v0.y,v0.z,v0.w,v1.x,v1.y,v1.z,v1.w};
  union{u16 us[8]; uint4 u;} raw;
  #pragma unroll
  for (int j=0;j<8;j++) raw.us[j] = f2bf(xv[j]);
  ((uint4*)(xbf + (size_t)src*DIM))[lane] = raw.u;
  float s = 0.f, sq = 0.f;
  #pragma unroll
  for (int j=0;j<8;j++){ s += xv[j]; sq += xv[j]*xv[j]; }
  #pragma unroll
  for (int o=32;o;o>>=1){ s += __shfl_xor(s,o); sq += __shfl_xor(sq,o); }
  float mean = s*(1.f/DIM);
  float var  = sq*(1.f/DIM) - mean*mean;
  float rstd = rsqrtf(var + 1e-5f);
  int c0 = lane*8;
  const float4* g4 = (const float4*)(g + c0);
  const float4* b4 = (const float4*)(b + c0);
  float4 ga = g4[0], gb = g4[1], ba = b4[0], bb = b4[1];
  float gg[8] = {ga.x,ga.y,ga.z,ga.w,gb.x,gb.y,gb.z,gb.w};
  float bv[8] = {ba.x,ba.y,ba.z,ba.w,bb.x,bb.y,bb.z,bb.w};
  union{u16 us[8]; uint4 u;} p;
  #pragma unroll
  for (int j=0;j<8;j++) p.us[j] = f2bf((xv[j]-mean)*rstd*gg[j] + bv[j]);
  ((uint4*)(out + (size_t)r*DIM))[lane] = p.u;
}

// ---------------- LayerNorm on bf16 residual (+optional window gather w/ roll) -> bf16 ----------------
__global__ __launch_bounds__(256)
void ln_kernel(const u16* __restrict__ x, const float* __restrict__ g,
               const float* __restrict__ b, u16* __restrict__ out, int mode)
{
  int wave = threadIdx.x >> 6, lane = threadIdx.x & 63;
  int r = blockIdx.x * 4 + wave;
  int src = (mode < 0) ? r : win_to_tok(r, mode);
  uint4 u = ((const uint4*)(x + (size_t)src * DIM))[lane];
  unsigned w[4] = {u.x, u.y, u.z, u.w};
  float xv[8];
  #pragma unroll
  for (int j=0;j<4;j++){ xv[2*j] = bflo(w[j]); xv[2*j+1] = bfhi(w[j]); }
  float s = 0.f, sq = 0.f;
  #pragma unroll
  for (int j=0;j<8;j++){ s += xv[j]; sq += xv[j]*xv[j]; }
  #pragma unroll
  for (int o=32;o;o>>=1){ s += __shfl_xor(s,o); sq += __shfl_xor(sq,o); }
  float mean = s*(1.f/DIM);
  float var  = sq*(1.f/DIM) - mean*mean;
  float rstd = rsqrtf(var + 1e-5f);
  int c0 = lane*8;
  const float4* g4 = (const float4*)(g + c0);
  const float4* b4 = (const float4*)(b + c0);
  float4 ga = g4[0], gb = g4[1], ba = b4[0], bb = b4[1];
  float gg[8] = {ga.x,ga.y,ga.z,ga.w,gb.x,gb.y,gb.z,gb.w};
  float bv[8] = {ba.x,ba.y,ba.z,ba.w,bb.x,bb.y,bb.z,bb.w};
  union{u16 us[8]; uint4 u;} p;
  #pragma unroll
  for (int j=0;j<8;j++) p.us[j] = f2bf((xv[j]-mean)*rstd*gg[j] + bv[j]);
  ((uint4*)(out + (size_t)r*DIM))[lane] = p.u;
}

// ============ gemm256r: 256x256 tile, 8 waves (2Mx4N, wave-tile 128x64), BK=32, 3-slot ring ============
// Rationale: per-CU L2 BW (~56B/cyc) caps 128^2/BK32 tiles at 77/293 = 26% MfmaUtil (the observed
// plateau). 256^2 stages 32KB per 4.2 MFLOP -> cap ~52%. One barrier/tile; counted vmcnt (R11 sched).
// EPI 0: store bf16 (qkv)   EPI 2: tanh-gelu -> bf16 (fc1)
template<int EPI>
__global__ __launch_bounds__(512, 1)
void gemm256r_kernel(const u16* __restrict__ X, const u16* __restrict__ Wt,
                     const float* __restrict__ bias, u16* __restrict__ obf,
                     int M, int N, int K)
{
  __shared__ u16 smem[49152];   // 96KB: slot s @ s*16384; A regions 0..3 @ +reg*4096, B @ +8192+reg*4096... 
  // layout per slot (16384 u16 = 32KB): A [256][32] as 4 regions of [64][32] @ reg*2048 u16; B same @ 8192 u16.
  int tid = threadIdx.x, wave = tid>>6, lane = tid&63;
  int wr = wave>>2, wc = wave&3;
  int nwg = gridDim.x * gridDim.y;
  int bid = blockIdx.y * gridDim.x + blockIdx.x;
  int wg  = (bid & 7) * (nwg >> 3) + (bid >> 3);
  int n0 = (wg % gridDim.x) * 256;
  int m0 = (wg / gridDim.x) * 256;
  f32x4 acc[8][4] = {};

  // staging decode: 128 threads per region (region = tid>>7), q in {0,1}:
  // line = q*16 + ((tid&127)>>3), slot8 = tid&7, u = slot8^(line&7), row = line*2+(u>>2), chunk = u&3
  int reg_ = tid>>7, t7 = tid&127;
  int rr_[2], cc_[2];
  #pragma unroll
  for (int q=0;q<2;q++){
    int line = q*16 + (t7>>3), sl = tid&7;
    int u = sl ^ (line&7);
    rr_[q] = reg_*64 + line*2 + (u>>2);
    cc_[q] = u&3;
  }

  auto stage = [&](int s, int kb){
    u16* base = smem + s*16384;
    #pragma unroll
    for (int q=0;q<2;q++){
      gload16(X  + (size_t)(m0 + rr_[q])*K + kb + cc_[q]*8, (void*)(base + reg_*2048 + q*1024 + t7*8));
      gload16(Wt + (size_t)(n0 + rr_[q])*K + kb + cc_[q]*8, (void*)(base + 8192 + reg_*2048 + q*1024 + t7*8));
    }
  };
  auto ldA = [&](int s, int mi)->short8{
    int row = wr*128 + mi*16 + (lane&15);
    int r = row&63;
    int ch = ((((r&1)<<2) + (lane>>4)) ^ ((r>>1)&7));
    return *(const short8*)((const char*)(smem + s*16384 + (row>>6)*2048) + (r>>1)*128 + ch*16);
  };
  auto ldB = [&](int s, int nj)->short8{
    int row = wc*64 + nj*16 + (lane&15);
    int r = row&63;
    int ch = ((((r&1)<<2) + (lane>>4)) ^ ((r>>1)&7));
    return *(const short8*)((const char*)(smem + s*16384 + 8192 + (row>>6)*2048) + (r>>1)*128 + ch*16);
  };

  int nt = K >> 5;
  stage(0, 0); stage(1, 32);
  asm volatile("s_waitcnt vmcnt(4)" ::: "memory");   // slot0 resident (4/thread); slot1's 4 in flight
  __builtin_amdgcn_sched_barrier(0);
  __builtin_amdgcn_s_barrier();
  __builtin_amdgcn_sched_barrier(0);

  int s = 0;
  for (int t=0; t<nt; ++t){
    int s2 = s+2; if (s2>=3) s2-=3;
    if (t+2 < nt) stage(s2, (t+2)<<5);
    short8 af[8], bfr[4];
    #pragma unroll
    for (int mi=0;mi<8;mi++) af[mi] = ldA(s, mi);
    #pragma unroll
    for (int nj=0;nj<4;nj++) bfr[nj] = ldB(s, nj);
    __builtin_amdgcn_s_setprio(1);
    #pragma unroll
    for (int mi=0;mi<8;mi++)
      #pragma unroll
      for (int nj=0;nj<4;nj++)
        acc[mi][nj] = __builtin_amdgcn_mfma_f32_16x16x32_bf16(af[mi], bfr[nj], acc[mi][nj], 0,0,0);
    __builtin_amdgcn_s_setprio(0);
    asm volatile("s_waitcnt lgkmcnt(0)" ::: "memory");
    __builtin_amdgcn_sched_barrier(0);
    if (t+1 < nt){
      if (t+2 < nt) asm volatile("s_waitcnt vmcnt(4)" ::: "memory");
      else          asm volatile("s_waitcnt vmcnt(0)" ::: "memory");
      __builtin_amdgcn_sched_barrier(0);
    }
    __builtin_amdgcn_s_barrier();
    __builtin_amdgcn_sched_barrier(0);
    s = (s==2) ? 0 : s+1;
  }

  // ---- epilogue: two half-passes [128][256] bf16 (64KB) through LDS -> coalesced stores ----
  __syncthreads();
  int lr = (lane>>4)*4, lc = lane&15;
  u16* et = smem;   // byte = rowl*512 + col*2, ^= ((rowl>>2)&3)<<5
  #pragma unroll
  for (int half=0; half<2; ++half){
    if (wr == half){
      #pragma unroll
      for (int mi=0;mi<8;mi++){
        #pragma unroll
        for (int nj=0;nj<4;nj++){
          int col = wc*64 + nj*16 + lc;
          float bv = bias[n0 + col];
          #pragma unroll
          for (int rx=0;rx<4;rx++){
            int rowl = mi*16 + lr + rx;
            float v = acc[mi][nj][rx] + bv;
            if (EPI==2){
              float u2 = v*(1.5957691216057308f + 0.0713548162726f*v*v);
              v = v * __builtin_amdgcn_rcpf(1.f + __expf(-u2));   // tanh-GELU
            }
            *(u16*)((char*)et + ((rowl*512 + col*2) ^ (((rowl>>2)&3)<<5))) = f2bf(v);
          }
        }
      }
    }
    __syncthreads();
    #pragma unroll
    for (int j=0;j<8;j++){
      int q = j*512 + tid;                 // 4096 16B-chunks
      int row = q>>5, cq = q&31;
      uint4 d = *(const uint4*)((char*)et + ((row*512 + cq*16) ^ (((row>>2)&3)<<5)));
      *(uint4*)(obf + (size_t)(m0 + half*128 + row)*N + n0 + cq*8) = d;
    }
    __syncthreads();
  }
}

// ============ gemm32r: 128x128 tile, BK=32, 3-slot LDS ring, counted vmcnt (R11-proven) ============
// EPI 1: scatter += into bf16 residual (proj, win_rev+roll)
// EPI 3: += bf16 residual (fc2 block0)   EPI 4: final fc2 -> f32 d_out
template<int EPI>
__global__ __launch_bounds__(256)
void gemm32r_kernel(const u16* __restrict__ X, const u16* __restrict__ Wt,
                    const float* __restrict__ bias, u16* __restrict__ obf,
                    u16* __restrict__ xbf, float* __restrict__ outf,
                    int M, int N, int K, int shifted)
{
  __shared__ u16 smem[24576];
  int tid = threadIdx.x, wave = tid>>6, lane = tid&63;
  int nwg = gridDim.x * gridDim.y;
  int bid = blockIdx.y * gridDim.x + blockIdx.x;
  int wg  = (bid & 7) * (nwg >> 3) + (bid >> 3);
  int n0 = (wg % gridDim.x) * 128;
  int m0 = (wg / gridDim.x) * 128;
  int wm = (wave>>1)*64, wn = (wave&1)*64;
  f32x4 acc[4][4] = {};

  int r_[2], c_[2];
  #pragma unroll
  for (int q=0;q<2;q++){
    int line = q*32 + (tid>>3), slot = tid&7;
    int u = slot ^ (line&7);
    r_[q] = line*2 + (u>>2); c_[q] = u&3;
  }

  auto stage = [&](int s, int kb){
    u16* Ad = smem + s*4096;
    u16* Bd = smem + 12288 + s*4096;
    #pragma unroll
    for (int q=0;q<2;q++){
      gload16(X + (size_t)(m0 + r_[q])*K + kb + c_[q]*8, (void*)(Ad + q*2048 + tid*8));
      gload16(Wt + (size_t)(n0 + r_[q])*K + kb + c_[q]*8, (void*)(Bd + q*2048 + tid*8));
    }
  };
  auto ldfrag = [&](const u16* base, int row0)->short8 {
    int r = row0 + (lane&15);
    int slot = (((r&1)<<2) + (lane>>4)) ^ ((r>>1)&7);
    return *(const short8*)((const char*)base + (r>>1)*128 + slot*16);
  };

  int nt = K >> 5;
  stage(0, 0); stage(1, 32);
  asm volatile("s_waitcnt vmcnt(4)" ::: "memory");
  __builtin_amdgcn_sched_barrier(0);
  __builtin_amdgcn_s_barrier();
  __builtin_amdgcn_sched_barrier(0);

  int s = 0;
  for (int t=0; t<nt; ++t){
    int s2 = s+2; if (s2>=3) s2-=3;
    if (t+2 < nt) stage(s2, (t+2)<<5);
    const u16* Ab = smem + s*4096;
    const u16* Bb = smem + 12288 + s*4096;
    short8 af[4], bfr[4];
    #pragma unroll
    for (int mi=0;mi<4;mi++) af[mi]  = ldfrag(Ab, wm + mi*16);
    #pragma unroll
    for (int nj=0;nj<4;nj++) bfr[nj] = ldfrag(Bb, wn + nj*16);
    __builtin_amdgcn_s_setprio(1);
    #pragma unroll
    for (int mi=0;mi<4;mi++)
      #pragma unroll
      for (int nj=0;nj<4;nj++)
        acc[mi][nj] = __builtin_amdgcn_mfma_f32_16x16x32_bf16(af[mi], bfr[nj], acc[mi][nj], 0,0,0);
    __builtin_amdgcn_s_setprio(0);
    asm volatile("s_waitcnt lgkmcnt(0)" ::: "memory");
    __builtin_amdgcn_sched_barrier(0);
    if (t+1 < nt){
      if (t+2 < nt) asm volatile("s_waitcnt vmcnt(4)" ::: "memory");
      else          asm volatile("s_waitcnt vmcnt(0)" ::: "memory");
      __builtin_amdgcn_sched_barrier(0);
    }
    __builtin_amdgcn_s_barrier();
    __builtin_amdgcn_sched_barrier(0);
    s = (s==2) ? 0 : s+1;
  }

  int lr = (lane>>4)*4, lc = lane&15;
  {
    float* et = (float*)smem;               // two passes of [64][128] f32 = 32KB
    #pragma unroll
    for (int half=0; half<2; ++half){
      __syncthreads();
      if ((wm>>6) == half){
        #pragma unroll
        for (int mi=0;mi<4;mi++){
          #pragma unroll
          for (int nj=0;nj<4;nj++){
            int col = wn + nj*16 + lc;
            float bv = bias[n0 + col];
            #pragma unroll
            for (int rx=0;rx<4;rx++){
              int row = (wm & 63) + mi*16 + lr + rx;
              *(float*)((char*)et + ((row*512 + col*4) ^ (((row>>2)&1)<<6))) = acc[mi][nj][rx] + bv;
            }
          }
        }
      }
      __syncthreads();
      #pragma unroll
      for (int j=0;j<4;j++){
        int q = j*256 + tid;                // 1024 chunks of 8 cols
        int row = q>>4, c8 = q&15;
        int swz = ((row>>2)&1)<<6;
        float4 d0 = *(const float4*)((char*)et + ((row*512 + c8*32     ) ^ swz));
        float4 d1 = *(const float4*)((char*)et + ((row*512 + c8*32 + 16) ^ swz));
        int lrow = m0 + half*64 + row;
        int grow = (EPI==1) ? win_to_tok(lrow, shifted) : lrow;
        size_t gofs = (size_t)grow*DIM + n0 + c8*8;
        uint4 xv = *(const uint4*)(xbf + gofs);
        unsigned xw[4] = {xv.x, xv.y, xv.z, xv.w};
        float xs[8];
        #pragma unroll
        for (int k2=0;k2<4;k2++){ xs[2*k2] = bflo(xw[k2]); xs[2*k2+1] = bfhi(xw[k2]); }
        float ds[8] = {d0.x,d0.y,d0.z,d0.w,d1.x,d1.y,d1.z,d1.w};
        if (EPI==4){
          float4 o0 = {xs[0]+ds[0], xs[1]+ds[1], xs[2]+ds[2], xs[3]+ds[3]};
          float4 o1 = {xs[4]+ds[4], xs[5]+ds[5], xs[6]+ds[6], xs[7]+ds[7]};
          float4* op = (float4*)(outf + gofs);
          op[0] = o0; op[1] = o1;
        } else {
          union{u16 us[8]; uint4 u;} nw;
          #pragma unroll
          for (int k2=0;k2<8;k2++) nw.us[k2] = f2bf(xs[k2] + ds[k2]);
          *(uint4*)(xbf + gofs) = nw.u;
        }
      }
    }
  }
}

// ---------------- rel-pos bias expansion: biasM[h][q][k] ----------------
__global__ __launch_bounds__(256)
void bias_kernel(const float* __restrict__ btab, float* __restrict__ biasM)
{
  int gid = blockIdx.x*256 + threadIdx.x;   // 16*128*128
  int q = (gid >> 7) & 127, k = gid & 127, h = gid >> 14;
  int ic=q>>6, ih=(q>>3)&7, iw=q&7, jc=k>>6, jh=(k>>3)&7, jw=k&7;
  int idx = (ic-jc+1)*225 + (ih-jh+7)*15 + (iw-jw+7);
  biasM[gid] = btab[idx*16 + h];
}

// ---------------- MFMA windowed attention ----------------
__global__ __launch_bounds__(256)
void attn_kernel(const u16* __restrict__ qkv, const float* __restrict__ biasM,
                 u16* __restrict__ out, int shifted)
{
  __shared__ u16 Ks[128*32];
  __shared__ u16 VsT[32*128];
  __shared__ u16 Ps[4][32*128];
  __shared__ int rid[128];
  int win = blockIdx.x >> 4, h = blockIdx.x & 15;
  int tid = threadIdx.x, wave = tid>>6, lane = tid&63;
  size_t base = (size_t)win*128*1536 + (size_t)h*32;

  {
    int m = tid>>1, half = tid&1;
    const uint4* ks = (const uint4*)(qkv + base + (size_t)m*1536 + 512 + half*16);
    uint4 k0v = ks[0], k1v = ks[1];
    char* krow = (char*)Ks + m*64;
    int c0 = half*32, sw = (m&3)<<4;
    *(uint4*)(krow + ((c0     ) ^ sw)) = k0v;
    *(uint4*)(krow + ((c0 + 16) ^ sw)) = k1v;
    const uint4* vs = (const uint4*)(qkv + base + (size_t)m*1536 + 1024 + half*16);
    union{u16 us[16]; uint4 u[2];} vv; vv.u[0]=vs[0]; vv.u[1]=vs[1];
    #pragma unroll
    for (int j=0;j<16;j++){
      int d = half*16 + j;
      *(u16*)((char*)VsT + ((d*256 + m*2) ^ ((d&7)<<4))) = vv.us[j];
    }
  }
  if (shifted && tid < 128){
    int a=win>>6, b=(win>>3)&7, c=win&7;
    int gc=a*2+(tid>>6), gh=b*8+((tid>>3)&7), gw=c*8+(tid&7);
    int rc = (gc<2)?0:((gc<3)?1:2);
    int rh = (gh<56)?0:((gh<60)?1:2);
    int rw = (gw<56)?0:((gw<60)?1:2);
    rid[tid] = rc*9 + rh*3 + rw;
  }
  __syncthreads();

  int q0 = wave*32;
  short8 qf[2];
  #pragma unroll
  for (int mi=0;mi<2;mi++){
    int ql = 16*mi + (lane&15);
    qf[mi] = *(const short8*)(qkv + base + (size_t)(q0+ql)*1536 + (lane>>4)*8);
  }
  f32x4 s[2][8] = {};
  #pragma unroll
  for (int nj=0;nj<8;nj++){
    int row = (lane&15) + 16*nj;
    short8 kf = *(const short8*)((char*)Ks + row*64 + ((((lane>>4)<<4)) ^ ((row&3)<<4)));
    #pragma unroll
    for (int mi=0;mi<2;mi++)
      s[mi][nj] = __builtin_amdgcn_mfma_f32_16x16x32_bf16(qf[mi], kf, s[mi][nj], 0,0,0);
  }

  int rk[8];
  if (shifted){
    #pragma unroll
    for (int nj=0;nj<8;nj++) rk[nj] = rid[(lane&15) + 16*nj];
  }
  float invl[2][4];
  char* pbase = (char*)Ps[wave];
  #pragma unroll
  for (int mi=0;mi<2;mi++){
    #pragma unroll
    for (int r=0;r<4;r++){
      int ql = 16*mi + ((lane>>4)<<2) + r;
      int qw = q0 + ql;
      const float* bp = biasM + (((h<<7) + qw)<<7) + (lane&15);
      int rq = shifted ? rid[qw] : 0;
      float sv[8]; float mx = -1e30f;
      #pragma unroll
      for (int nj=0;nj<8;nj++){
        float v = s[mi][nj][r] * 0.17677669529663687f + bp[nj*16];
        if (shifted && rk[nj] != rq) v -= 100.f;
        sv[nj] = v; mx = fmaxf(mx, v);
      }
      #pragma unroll
      for (int o=1;o<16;o<<=1) mx = fmaxf(mx, __shfl_xor(mx, o));
      float sum = 0.f;
      #pragma unroll
      for (int nj=0;nj<8;nj++){ float p = __expf(sv[nj]-mx); sv[nj]=p; sum += p; }
      #pragma unroll
      for (int o=1;o<16;o<<=1) sum += __shfl_xor(sum, o);
      invl[mi][r] = 1.f/sum;
      char* prow = pbase + ql*256;
      int sw = (ql&7)<<4;
      #pragma unroll
      for (int nj=0;nj<8;nj++)
        *(u16*)(prow + ((((lane&15) + (nj<<4))<<1) ^ sw)) = f2bf(sv[nj]);
    }
  }

  f32x4 o2[2][2] = {};
  #pragma unroll
  for (int kk=0;kk<4;kk++){
    int coff = kk*64 + ((lane>>4)<<4);
    short8 pa[2], vb[2];
    #pragma unroll
    for (int mi=0;mi<2;mi++){
      int ql = 16*mi + (lane&15);
      pa[mi] = *(const short8*)(pbase + ql*256 + (coff ^ ((ql&7)<<4)));
    }
    #pragma unroll
    for (int nj=0;nj<2;nj++){
      int d = (lane&15) + 16*nj;
      vb[nj] = *(const short8*)((char*)VsT + d*256 + (coff ^ ((d&7)<<4)));
    }
    #pragma unroll
    for (int mi=0;mi<2;mi++)
      #pragma unroll
      for (int nj=0;nj<2;nj++)
        o2[mi][nj] = __builtin_amdgcn_mfma_f32_16x16x32_bf16(pa[mi], vb[nj], o2[mi][nj], 0,0,0);
  }

  #pragma unroll
  for (int mi=0;mi<2;mi++){
    #pragma unroll
    for (int nj=0;nj<2;nj++){
      #pragma unroll
      for (int r=0;r<4;r++){
        int ql = 16*mi + ((lane>>4)<<2) + r;
        int d  = (lane&15) + (nj<<4);
        out[(size_t)(win*128 + q0 + ql)*DIM + (h<<5) + d] = f2bf(o2[mi][nj][r] * invl[mi][r]);
      }
    }
  }
}

// ---------------- host launcher ----------------
extern "C" void kernel_launch(void* const* d_in, const int* in_sizes, int n_in,
                              void* d_out, int out_size, void* d_ws, size_t ws_size,
                              hipStream_t stream)
{
  const float* x_in   = (const float*)d_in[0];
  const float* ln1_g  = (const float*)d_in[1];
  const float* ln1_b  = (const float*)d_in[2];
  const float* qkv_w  = (const float*)d_in[3];
  const float* qkv_b  = (const float*)d_in[4];
  const float* btab   = (const float*)d_in[5];
  const float* proj_w = (const float*)d_in[6];
  const float* proj_b = (const float*)d_in[7];
  const float* ln2_g  = (const float*)d_in[8];
  const float* ln2_b  = (const float*)d_in[9];
  const float* fc1_w  = (const float*)d_in[10];
  const float* fc1_b  = (const float*)d_in[11];
  const float* fc2_w  = (const float*)d_in[12];
  const float* fc2_b  = (const float*)d_in[13];

  char* ws = (char*)d_ws;
  size_t off = 0;
  auto alloc = [&](size_t bytes)->char*{ char* p = ws + off; off += (bytes + 255) & ~(size_t)255; return p; };
  u16* wT_qkv = (u16*)alloc((size_t)2*512*1536*2);
  u16* wT_proj= (u16*)alloc((size_t)2*512*512*2);
  u16* wT_fc1 = (u16*)alloc((size_t)2*2048*512*2);
  u16* wT_fc2 = (u16*)alloc((size_t)2*512*2048*2);
  u16* bufA   = (u16*)alloc((size_t)16384*2048*2);
  u16* bufQ   = (u16*)alloc((size_t)16384*1536*2);
  u16* bufB   = (u16*)alloc((size_t)16384*512*2);
  u16* xbf    = (u16*)alloc((size_t)16384*512*2);
  float* biasM= (float*)alloc((size_t)16*128*128*4);
  (void)ws_size; (void)in_sizes; (void)n_in; (void)out_size;

  float* xout = (float*)d_out;

  transpose_kernel<<<dim3(1536/32, 512/32, 2), 256, 0, stream>>>(qkv_w, wT_qkv, 512, 1536);
  transpose_kernel<<<dim3( 512/32, 512/32, 2), 256, 0, stream>>>(proj_w, wT_proj, 512, 512);
  transpose_kernel<<<dim3(2048/32, 512/32, 2), 256, 0, stream>>>(fc1_w, wT_fc1, 512, 2048);
  transpose_kernel<<<dim3( 512/32,2048/32, 2), 256, 0, stream>>>(fc2_w, wT_fc2, 2048, 512);

  for (int i=0;i<2;i++){
    if (i==0)
      ln_f32cvt_kernel<<<4096, 256, 0, stream>>>(x_in, ln1_g, ln1_b, bufA, xbf);
    else
      ln_kernel<<<4096, 256, 0, stream>>>(xbf, ln1_g+512, ln1_b+512, bufA, 1);
    gemm256r_kernel<0><<<dim3(6,64), 512, 0, stream>>>(bufA, wT_qkv+(size_t)i*512*1536, qkv_b+i*1536, bufQ, NTOK,1536,512);
    bias_kernel<<<1024, 256, 0, stream>>>(btab + (size_t)i*675*16, biasM);
    attn_kernel<<<2048, 256, 0, stream>>>(bufQ, biasM, bufB, i);
    gemm32r_kernel<1><<<dim3(4,128), 256, 0, stream>>>(bufB, wT_proj+(size_t)i*512*512, proj_b+i*512, nullptr, xbf, nullptr, NTOK,512,512, i);
    ln_kernel<<<4096, 256, 0, stream>>>(xbf, ln2_g+i*512, ln2_b+i*512, bufB, -1);
    gemm256r_kernel<2><<<dim3(8,64), 512, 0, stream>>>(bufB, wT_fc1+(size_t)i*2048*512, fc1_b+i*2048, bufA, NTOK,2048,512);
    if (i==0)
      gemm32r_kernel<3><<<dim3(4,128), 256, 0, stream>>>(bufA, wT_fc2+(size_t)i*512*2048, fc2_b+i*512, nullptr, xbf, nullptr, NTOK,512,2048, 0);
    else
      gemm32r_kernel<4><<<dim3(4,128), 256, 0, stream>>>(bufA, wT_fc2+(size_t)i*512*2048, fc2_b+i*512, nullptr, xbf, xout, NTOK,512,2048, 0);
  }
}

// Round 15
// 436.436 us; speedup vs baseline: 1.1278x; 1.0430x over previous
//
#include <hip/hip_runtime.h>
#include <stdint.h>

#define DIM 512
#define NHD 16
#define HD 32
#define NTOK 16384

typedef unsigned short u16;
typedef __attribute__((ext_vector_type(8))) short short8;  // 8 bf16 (4 VGPRs)
typedef __attribute__((ext_vector_type(4))) float f32x4;

__device__ __forceinline__ float bflo(unsigned u){ union{unsigned i; float f;} c; c.i=u<<16; return c.f; }
__device__ __forceinline__ float bfhi(unsigned u){ union{unsigned i; float f;} c; c.i=u&0xffff0000u; return c.f; }
__device__ __forceinline__ u16 f2bf(float f){ union{float f; unsigned i;} c; c.f=f; unsigned r=(c.i + 0x7fffu + ((c.i>>16)&1u))>>16; return (u16)r; }
__device__ __forceinline__ unsigned pk2(float a, float b){ return (unsigned)f2bf(a) | ((unsigned)f2bf(b)<<16); }

__device__ __forceinline__ int win_to_tok(int r, int shifted){
  int win = r >> 7, n = r & 127;
  int a = win >> 6, b = (win >> 3) & 7, c = win & 7;
  int ic = n >> 6, ih = (n >> 3) & 7, iw = n & 7;
  int gc = a*2 + ic, gh = b*8 + ih, gw = c*8 + iw;
  if (shifted){ gc = (gc + 1) & 3; gh = (gh + 4) & 63; gw = (gw + 4) & 63; }
  return (gc << 12) + (gh << 6) + gw;
}

__device__ __forceinline__ void gload16(const void* g, void* l){
  __builtin_amdgcn_global_load_lds(
    (const __attribute__((address_space(1))) unsigned int*)(unsigned long long)g,
    (__attribute__((address_space(3))) unsigned int*)(unsigned int)(unsigned long long)l,
    16, 0, 0);
}

// ---------------- weight transpose + bf16 cast (batched over 2 model-blocks via z) ----------------
__global__ __launch_bounds__(256)
void transpose_kernel(const float* __restrict__ W, u16* __restrict__ Wt, int K, int N)
{
  __shared__ float t[32][33];
  size_t zoff = (size_t)blockIdx.z * K * N;
  int n0 = blockIdx.x*32, k0 = blockIdx.y*32;
  int tx = threadIdx.x & 31, ty = threadIdx.x >> 5;
  #pragma unroll
  for (int i=0;i<4;i++) t[ty + i*8][tx] = W[zoff + (size_t)(k0 + ty + i*8)*N + n0 + tx];
  __syncthreads();
  #pragma unroll
  for (int i=0;i<4;i++) Wt[zoff + (size_t)(n0 + ty + i*8)*K + k0 + tx] = f2bf(t[tx][ty + i*8]);
}

// ---------------- fused first-LN: reads f32 x, writes LN->bufA (window order) AND raw bf16 -> xbf ----------------
__global__ __launch_bounds__(256)
void ln_f32cvt_kernel(const float* __restrict__ x, const float* __restrict__ g,
                      const float* __restrict__ b, u16* __restrict__ out, u16* __restrict__ xbf)
{
  int wave = threadIdx.x >> 6, lane = threadIdx.x & 63;
  int r = blockIdx.x * 4 + wave;
  int src = win_to_tok(r, 0);
  const float4* xr = (const float4*)(x + (size_t)src * DIM);
  float4 v0 = xr[lane*2], v1 = xr[lane*2+1];
  float xv[8] = {v0.x,v0.y,v0.z,v0.w,v1.x,v1.y,v1.z,v1.w};
  union{u16 us[8]; uint4 u;} raw;
  #pragma unroll
  for (int j=0;j<8;j++) raw.us[j] = f2bf(xv[j]);
  ((uint4*)(xbf + (size_t)src*DIM))[lane] = raw.u;
  float s = 0.f, sq = 0.f;
  #pragma unroll
  for (int j=0;j<8;j++){ s += xv[j]; sq += xv[j]*xv[j]; }
  #pragma unroll
  for (int o=32;o;o>>=1){ s += __shfl_xor(s,o); sq += __shfl_xor(sq,o); }
  float mean = s*(1.f/DIM);
  float var  = sq*(1.f/DIM) - mean*mean;
  float rstd = rsqrtf(var + 1e-5f);
  int c0 = lane*8;
  const float4* g4 = (const float4*)(g + c0);
  const float4* b4 = (const float4*)(b + c0);
  float4 ga = g4[0], gb = g4[1], ba = b4[0], bb = b4[1];
  float gg[8] = {ga.x,ga.y,ga.z,ga.w,gb.x,gb.y,gb.z,gb.w};
  float bv[8] = {ba.x,ba.y,ba.z,ba.w,bb.x,bb.y,bb.z,bb.w};
  union{u16 us[8]; uint4 u;} p;
  #pragma unroll
  for (int j=0;j<8;j++) p.us[j] = f2bf((xv[j]-mean)*rstd*gg[j] + bv[j]);
  ((uint4*)(out + (size_t)r*DIM))[lane] = p.u;
}

// ---------------- LayerNorm on bf16 residual (+optional window gather w/ roll) -> bf16 ----------------
__global__ __launch_bounds__(256)
void ln_kernel(const u16* __restrict__ x, const float* __restrict__ g,
               const float* __restrict__ b, u16* __restrict__ out, int mode)
{
  int wave = threadIdx.x >> 6, lane = threadIdx.x & 63;
  int r = blockIdx.x * 4 + wave;
  int src = (mode < 0) ? r : win_to_tok(r, mode);
  uint4 u = ((const uint4*)(x + (size_t)src * DIM))[lane];
  unsigned w[4] = {u.x, u.y, u.z, u.w};
  float xv[8];
  #pragma unroll
  for (int j=0;j<4;j++){ xv[2*j] = bflo(w[j]); xv[2*j+1] = bfhi(w[j]); }
  float s = 0.f, sq = 0.f;
  #pragma unroll
  for (int j=0;j<8;j++){ s += xv[j]; sq += xv[j]*xv[j]; }
  #pragma unroll
  for (int o=32;o;o>>=1){ s += __shfl_xor(s,o); sq += __shfl_xor(sq,o); }
  float mean = s*(1.f/DIM);
  float var  = sq*(1.f/DIM) - mean*mean;
  float rstd = rsqrtf(var + 1e-5f);
  int c0 = lane*8;
  const float4* g4 = (const float4*)(g + c0);
  const float4* b4 = (const float4*)(b + c0);
  float4 ga = g4[0], gb = g4[1], ba = b4[0], bb = b4[1];
  float gg[8] = {ga.x,ga.y,ga.z,ga.w,gb.x,gb.y,gb.z,gb.w};
  float bv[8] = {ba.x,ba.y,ba.z,ba.w,bb.x,bb.y,bb.z,bb.w};
  union{u16 us[8]; uint4 u;} p;
  #pragma unroll
  for (int j=0;j<8;j++) p.us[j] = f2bf((xv[j]-mean)*rstd*gg[j] + bv[j]);
  ((uint4*)(out + (size_t)r*DIM))[lane] = p.u;
}

// ============ gemm32r: 128x128 tile, BK=32, 3-slot LDS ring, counted vmcnt (R11-proven loop) ============
// C^T operand swap (R14): mfma(bfr, af) -> per lane M-row = lane&15, N-cols = (lane>>4)*4+rr
//   => epilogue writes 8B/16B vectors instead of 64 scalars.
// EPI 0: store bf16 (qkv)        EPI 1: scatter += into bf16 residual (proj, win_rev+roll)
// EPI 2: tanh-gelu -> bf16 (fc1) EPI 3: += bf16 residual (fc2 block0)
// EPI 4: final fc2: read bf16 residual, add, write f32 d_out
template<int EPI>
__global__ __launch_bounds__(256)
void gemm32r_kernel(const u16* __restrict__ X, const u16* __restrict__ Wt,
                    const float* __restrict__ bias, u16* __restrict__ obf,
                    u16* __restrict__ xbf, float* __restrict__ outf,
                    int M, int N, int K, int shifted)
{
  __shared__ u16 smem[24576];    // 48KB: A slot s @ s*4096, B slot s @ 12288+s*4096 (elems)
  int tid = threadIdx.x, wave = tid>>6, lane = tid&63;
  int nwg = gridDim.x * gridDim.y;
  int bid = blockIdx.y * gridDim.x + blockIdx.x;
  int wg  = (bid & 7) * (nwg >> 3) + (bid >> 3);
  int n0 = (wg % gridDim.x) * 128;
  int m0 = (wg / gridDim.x) * 128;
  int wm = (wave>>1)*64, wn = (wave&1)*64;
  f32x4 acc[4][4] = {};

  int r_[2], c_[2];
  #pragma unroll
  for (int q=0;q<2;q++){
    int line = q*32 + (tid>>3), slot = tid&7;
    int u = slot ^ (line&7);
    r_[q] = line*2 + (u>>2); c_[q] = u&3;
  }

  auto stage = [&](int s, int kb){
    u16* Ad = smem + s*4096;
    u16* Bd = smem + 12288 + s*4096;
    #pragma unroll
    for (int q=0;q<2;q++){
      gload16(X + (size_t)(m0 + r_[q])*K + kb + c_[q]*8, (void*)(Ad + q*2048 + tid*8));
      gload16(Wt + (size_t)(n0 + r_[q])*K + kb + c_[q]*8, (void*)(Bd + q*2048 + tid*8));
    }
  };
  auto ldfrag = [&](const u16* base, int row0)->short8 {
    int r = row0 + (lane&15);
    int slot = (((r&1)<<2) + (lane>>4)) ^ ((r>>1)&7);
    return *(const short8*)((const char*)base + (r>>1)*128 + slot*16);
  };

  int nt = K >> 5;
  stage(0, 0); stage(1, 32);
  asm volatile("s_waitcnt vmcnt(4)" ::: "memory");
  __builtin_amdgcn_sched_barrier(0);
  __builtin_amdgcn_s_barrier();
  __builtin_amdgcn_sched_barrier(0);

  int s = 0;
  for (int t=0; t<nt; ++t){
    int s2 = s+2; if (s2>=3) s2-=3;
    if (t+2 < nt) stage(s2, (t+2)<<5);
    const u16* Ab = smem + s*4096;
    const u16* Bb = smem + 12288 + s*4096;
    short8 af[4], bfr[4];
    #pragma unroll
    for (int mi=0;mi<4;mi++) af[mi]  = ldfrag(Ab, wm + mi*16);
    #pragma unroll
    for (int nj=0;nj<4;nj++) bfr[nj] = ldfrag(Bb, wn + nj*16);
    __builtin_amdgcn_s_setprio(1);
    #pragma unroll
    for (int mi=0;mi<4;mi++)
      #pragma unroll
      for (int nj=0;nj<4;nj++)
        acc[mi][nj] = __builtin_amdgcn_mfma_f32_16x16x32_bf16(bfr[nj], af[mi], acc[mi][nj], 0,0,0);  // C^T swap
    __builtin_amdgcn_s_setprio(0);
    asm volatile("s_waitcnt lgkmcnt(0)" ::: "memory");
    __builtin_amdgcn_sched_barrier(0);
    if (t+1 < nt){
      if (t+2 < nt) asm volatile("s_waitcnt vmcnt(4)" ::: "memory");
      else          asm volatile("s_waitcnt vmcnt(0)" ::: "memory");
      __builtin_amdgcn_sched_barrier(0);
    }
    __builtin_amdgcn_s_barrier();
    __builtin_amdgcn_sched_barrier(0);
    s = (s==2) ? 0 : s+1;
  }

  // ---- epilogue (C^T layout: M-row = lane&15, N-cols = (lane>>4)*4 + rr) ----
  if (EPI==0 || EPI==2){
    u16* et = smem;                         // [128][128] bf16 = 32KB, byte ^= ((row>>1)&7)<<4
    #pragma unroll
    for (int mi=0;mi<4;mi++){
      int row = wm + mi*16 + (lane&15);
      int swz = ((row>>1)&7)<<4;
      #pragma unroll
      for (int nj=0;nj<4;nj++){
        int col0 = wn + nj*16 + ((lane>>4)<<2);
        float4 bv = *(const float4*)(bias + n0 + col0);
        float v0 = acc[mi][nj][0] + bv.x, v1 = acc[mi][nj][1] + bv.y;
        float v2 = acc[mi][nj][2] + bv.z, v3 = acc[mi][nj][3] + bv.w;
        if (EPI==2){
          float u0 = v0*(1.5957691216057308f + 0.0713548162726f*v0*v0);
          float u1 = v1*(1.5957691216057308f + 0.0713548162726f*v1*v1);
          float u2 = v2*(1.5957691216057308f + 0.0713548162726f*v2*v2);
          float u3 = v3*(1.5957691216057308f + 0.0713548162726f*v3*v3);
          v0 *= __builtin_amdgcn_rcpf(1.f + __expf(-u0));
          v1 *= __builtin_amdgcn_rcpf(1.f + __expf(-u1));
          v2 *= __builtin_amdgcn_rcpf(1.f + __expf(-u2));
          v3 *= __builtin_amdgcn_rcpf(1.f + __expf(-u3));
        }
        uint2 pkd = { pk2(v0,v1), pk2(v2,v3) };
        *(uint2*)((char*)et + ((row*256 + col0*2) ^ swz)) = pkd;
      }
    }
    __syncthreads();
    #pragma unroll
    for (int j=0;j<8;j++){
      int q = j*256 + tid;
      int row = q>>4, cc = q&15;
      uint4 d = *(const uint4*)((char*)et + ((row*256 + cc*16) ^ (((row>>1)&7)<<4)));
      *(uint4*)(obf + (size_t)(m0+row)*N + n0 + cc*8) = d;
    }
  } else {
    // EPI 1/3/4: f32 repack in two 64-row halves, then bf16-residual RMW (or f32 final store)
    float* et = (float*)smem;               // [64][128] f32 = 32KB, byte ^= (row&7)<<4
    #pragma unroll
    for (int half=0; half<2; ++half){
      __syncthreads();
      if ((wm>>6) == half){
        #pragma unroll
        for (int mi=0;mi<4;mi++){
          int row = (wm & 63) + mi*16 + (lane&15);
          int swz = (row&7)<<4;
          #pragma unroll
          for (int nj=0;nj<4;nj++){
            int col0 = wn + nj*16 + ((lane>>4)<<2);
            float4 bv = *(const float4*)(bias + n0 + col0);
            float4 wv = { acc[mi][nj][0] + bv.x, acc[mi][nj][1] + bv.y,
                          acc[mi][nj][2] + bv.z, acc[mi][nj][3] + bv.w };
            *(float4*)((char*)et + ((row*512 + col0*4) ^ swz)) = wv;
          }
        }
      }
      __syncthreads();
      #pragma unroll
      for (int j=0;j<4;j++){
        int q = j*256 + tid;                // 1024 chunks of 8 cols
        int row = q>>4, c8 = q&15;
        int swz = (row&7)<<4;
        float4 d0 = *(const float4*)((char*)et + ((row*512 + c8*32     ) ^ swz));
        float4 d1 = *(const float4*)((char*)et + ((row*512 + c8*32 + 16) ^ swz));
        int lrow = m0 + half*64 + row;
        int grow = (EPI==1) ? win_to_tok(lrow, shifted) : lrow;
        size_t gofs = (size_t)grow*DIM + n0 + c8*8;
        uint4 xv = *(const uint4*)(xbf + gofs);
        unsigned xw[4] = {xv.x, xv.y, xv.z, xv.w};
        float xs[8];
        #pragma unroll
        for (int k2=0;k2<4;k2++){ xs[2*k2] = bflo(xw[k2]); xs[2*k2+1] = bfhi(xw[k2]); }
        float ds[8] = {d0.x,d0.y,d0.z,d0.w,d1.x,d1.y,d1.z,d1.w};
        if (EPI==4){
          float4 o0 = {xs[0]+ds[0], xs[1]+ds[1], xs[2]+ds[2], xs[3]+ds[3]};
          float4 o1 = {xs[4]+ds[4], xs[5]+ds[5], xs[6]+ds[6], xs[7]+ds[7]};
          float4* op = (float4*)(outf + gofs);
          op[0] = o0; op[1] = o1;
        } else {
          union{u16 us[8]; uint4 u;} nw;
          #pragma unroll
          for (int k2=0;k2<8;k2++) nw.us[k2] = f2bf(xs[k2] + ds[k2]);
          *(uint4*)(xbf + gofs) = nw.u;
        }
      }
    }
  }
}

// ---------------- rel-pos bias expansion: biasM[h][q][k] ----------------
__global__ __launch_bounds__(256)
void bias_kernel(const float* __restrict__ btab, float* __restrict__ biasM)
{
  int gid = blockIdx.x*256 + threadIdx.x;   // 16*128*128
  int q = (gid >> 7) & 127, k = gid & 127, h = gid >> 14;
  int ic=q>>6, ih=(q>>3)&7, iw=q&7, jc=k>>6, jh=(k>>3)&7, jw=k&7;
  int idx = (ic-jc+1)*225 + (ih-jh+7)*15 + (iw-jw+7);
  biasM[gid] = btab[idx*16 + h];
}

// ---------------- MFMA windowed attention ----------------
__global__ __launch_bounds__(256)
void attn_kernel(const u16* __restrict__ qkv, const float* __restrict__ biasM,
                 u16* __restrict__ out, int shifted)
{
  __shared__ u16 Ks[128*32];
  __shared__ u16 VsT[32*128];
  __shared__ u16 Ps[4][32*128];
  __shared__ int rid[128];
  int win = blockIdx.x >> 4, h = blockIdx.x & 15;
  int tid = threadIdx.x, wave = tid>>6, lane = tid&63;
  size_t base = (size_t)win*128*1536 + (size_t)h*32;

  {
    int m = tid>>1, half = tid&1;
    const uint4* ks = (const uint4*)(qkv + base + (size_t)m*1536 + 512 + half*16);
    uint4 k0v = ks[0], k1v = ks[1];
    char* krow = (char*)Ks + m*64;
    int c0 = half*32, sw = (m&3)<<4;
    *(uint4*)(krow + ((c0     ) ^ sw)) = k0v;
    *(uint4*)(krow + ((c0 + 16) ^ sw)) = k1v;
    const uint4* vs = (const uint4*)(qkv + base + (size_t)m*1536 + 1024 + half*16);
    union{u16 us[16]; uint4 u[2];} vv; vv.u[0]=vs[0]; vv.u[1]=vs[1];
    #pragma unroll
    for (int j=0;j<16;j++){
      int d = half*16 + j;
      *(u16*)((char*)VsT + ((d*256 + m*2) ^ ((d&7)<<4))) = vv.us[j];
    }
  }
  if (shifted && tid < 128){
    int a=win>>6, b=(win>>3)&7, c=win&7;
    int gc=a*2+(tid>>6), gh=b*8+((tid>>3)&7), gw=c*8+(tid&7);
    int rc = (gc<2)?0:((gc<3)?1:2);
    int rh = (gh<56)?0:((gh<60)?1:2);
    int rw = (gw<56)?0:((gw<60)?1:2);
    rid[tid] = rc*9 + rh*3 + rw;
  }
  __syncthreads();

  int q0 = wave*32;
  short8 qf[2];
  #pragma unroll
  for (int mi=0;mi<2;mi++){
    int ql = 16*mi + (lane&15);
    qf[mi] = *(const short8*)(qkv + base + (size_t)(q0+ql)*1536 + (lane>>4)*8);
  }
  f32x4 s[2][8] = {};
  #pragma unroll
  for (int nj=0;nj<8;nj++){
    int row = (lane&15) + 16*nj;
    short8 kf = *(const short8*)((char*)Ks + row*64 + ((((lane>>4)<<4)) ^ ((row&3)<<4)));
    #pragma unroll
    for (int mi=0;mi<2;mi++)
      s[mi][nj] = __builtin_amdgcn_mfma_f32_16x16x32_bf16(qf[mi], kf, s[mi][nj], 0,0,0);
  }

  int rk[8];
  if (shifted){
    #pragma unroll
    for (int nj=0;nj<8;nj++) rk[nj] = rid[(lane&15) + 16*nj];
  }
  float invl[2][4];
  char* pbase = (char*)Ps[wave];
  #pragma unroll
  for (int mi=0;mi<2;mi++){
    #pragma unroll
    for (int r=0;r<4;r++){
      int ql = 16*mi + ((lane>>4)<<2) + r;
      int qw = q0 + ql;
      const float* bp = biasM + (((h<<7) + qw)<<7) + (lane&15);
      int rq = shifted ? rid[qw] : 0;
      float sv[8]; float mx = -1e30f;
      #pragma unroll
      for (int nj=0;nj<8;nj++){
        float v = s[mi][nj][r] * 0.17677669529663687f + bp[nj*16];
        if (shifted && rk[nj] != rq) v -= 100.f;
        sv[nj] = v; mx = fmaxf(mx, v);
      }
      #pragma unroll
      for (int o=1;o<16;o<<=1) mx = fmaxf(mx, __shfl_xor(mx, o));
      float sum = 0.f;
      #pragma unroll
      for (int nj=0;nj<8;nj++){ float p = __expf(sv[nj]-mx); sv[nj]=p; sum += p; }
      #pragma unroll
      for (int o=1;o<16;o<<=1) sum += __shfl_xor(sum, o);
      invl[mi][r] = 1.f/sum;
      char* prow = pbase + ql*256;
      int sw = (ql&7)<<4;
      #pragma unroll
      for (int nj=0;nj<8;nj++)
        *(u16*)(prow + ((((lane&15) + (nj<<4))<<1) ^ sw)) = f2bf(sv[nj]);
    }
  }

  f32x4 o2[2][2] = {};
  #pragma unroll
  for (int kk=0;kk<4;kk++){
    int coff = kk*64 + ((lane>>4)<<4);
    short8 pa[2], vb[2];
    #pragma unroll
    for (int mi=0;mi<2;mi++){
      int ql = 16*mi + (lane&15);
      pa[mi] = *(const short8*)(pbase + ql*256 + (coff ^ ((ql&7)<<4)));
    }
    #pragma unroll
    for (int nj=0;nj<2;nj++){
      int d = (lane&15) + 16*nj;
      vb[nj] = *(const short8*)((char*)VsT + d*256 + (coff ^ ((d&7)<<4)));
    }
    #pragma unroll
    for (int mi=0;mi<2;mi++)
      #pragma unroll
      for (int nj=0;nj<2;nj++)
        o2[mi][nj] = __builtin_amdgcn_mfma_f32_16x16x32_bf16(pa[mi], vb[nj], o2[mi][nj], 0,0,0);
  }

  #pragma unroll
  for (int mi=0;mi<2;mi++){
    #pragma unroll
    for (int nj=0;nj<2;nj++){
      #pragma unroll
      for (int r=0;r<4;r++){
        int ql = 16*mi + ((lane>>4)<<2) + r;
        int d  = (lane&15) + (nj<<4);
        out[(size_t)(win*128 + q0 + ql)*DIM + (h<<5) + d] = f2bf(o2[mi][nj][r] * invl[mi][r]);
      }
    }
  }
}

// ---------------- host launcher ----------------
extern "C" void kernel_launch(void* const* d_in, const int* in_sizes, int n_in,
                              void* d_out, int out_size, void* d_ws, size_t ws_size,
                              hipStream_t stream)
{
  const float* x_in   = (const float*)d_in[0];
  const float* ln1_g  = (const float*)d_in[1];
  const float* ln1_b  = (const float*)d_in[2];
  const float* qkv_w  = (const float*)d_in[3];
  const float* qkv_b  = (const float*)d_in[4];
  const float* btab   = (const float*)d_in[5];
  const float* proj_w = (const float*)d_in[6];
  const float* proj_b = (const float*)d_in[7];
  const float* ln2_g  = (const float*)d_in[8];
  const float* ln2_b  = (const float*)d_in[9];
  const float* fc1_w  = (const float*)d_in[10];
  const float* fc1_b  = (const float*)d_in[11];
  const float* fc2_w  = (const float*)d_in[12];
  const float* fc2_b  = (const float*)d_in[13];

  char* ws = (char*)d_ws;
  size_t off = 0;
  auto alloc = [&](size_t bytes)->char*{ char* p = ws + off; off += (bytes + 255) & ~(size_t)255; return p; };
  u16* wT_qkv = (u16*)alloc((size_t)2*512*1536*2);
  u16* wT_proj= (u16*)alloc((size_t)2*512*512*2);
  u16* wT_fc1 = (u16*)alloc((size_t)2*2048*512*2);
  u16* wT_fc2 = (u16*)alloc((size_t)2*512*2048*2);
  u16* bufA   = (u16*)alloc((size_t)16384*2048*2);
  u16* bufQ   = (u16*)alloc((size_t)16384*1536*2);
  u16* bufB   = (u16*)alloc((size_t)16384*512*2);
  u16* xbf    = (u16*)alloc((size_t)16384*512*2);
  float* biasM= (float*)alloc((size_t)16*128*128*4);
  (void)ws_size; (void)in_sizes; (void)n_in; (void)out_size;

  float* xout = (float*)d_out;

  transpose_kernel<<<dim3(1536/32, 512/32, 2), 256, 0, stream>>>(qkv_w, wT_qkv, 512, 1536);
  transpose_kernel<<<dim3( 512/32, 512/32, 2), 256, 0, stream>>>(proj_w, wT_proj, 512, 512);
  transpose_kernel<<<dim3(2048/32, 512/32, 2), 256, 0, stream>>>(fc1_w, wT_fc1, 512, 2048);
  transpose_kernel<<<dim3( 512/32,2048/32, 2), 256, 0, stream>>>(fc2_w, wT_fc2, 2048, 512);

  for (int i=0;i<2;i++){
    if (i==0)
      ln_f32cvt_kernel<<<4096, 256, 0, stream>>>(x_in, ln1_g, ln1_b, bufA, xbf);
    else
      ln_kernel<<<4096, 256, 0, stream>>>(xbf, ln1_g+512, ln1_b+512, bufA, 1);
    gemm32r_kernel<0><<<dim3(12,128), 256, 0, stream>>>(bufA, wT_qkv+(size_t)i*512*1536, qkv_b+i*1536, bufQ, nullptr, nullptr, NTOK,1536,512, 0);
    bias_kernel<<<1024, 256, 0, stream>>>(btab + (size_t)i*675*16, biasM);
    attn_kernel<<<2048, 256, 0, stream>>>(bufQ, biasM, bufB, i);
    gemm32r_kernel<1><<<dim3(4,128), 256, 0, stream>>>(bufB, wT_proj+(size_t)i*512*512, proj_b+i*512, nullptr, xbf, nullptr, NTOK,512,512, i);
    ln_kernel<<<4096, 256, 0, stream>>>(xbf, ln2_g+i*512, ln2_b+i*512, bufB, -1);
    gemm32r_kernel<2><<<dim3(16,128), 256, 0, stream>>>(bufB, wT_fc1+(size_t)i*2048*512, fc1_b+i*2048, bufA, nullptr, nullptr, NTOK,2048,512, 0);
    if (i==0)
      gemm32r_kernel<3><<<dim3(4,128), 256, 0, stream>>>(bufA, wT_fc2+(size_t)i*512*2048, fc2_b+i*512, nullptr, xbf, nullptr, NTOK,512,2048, 0);
    else
      gemm32r_kernel<4><<<dim3(4,128), 256, 0, stream>>>(bufA, wT_fc2+(size_t)i*512*2048, fc2_b+i*512, nullptr, xbf, xout, NTOK,512,2048, 0);
  }
}

// Round 16
// 424.067 us; speedup vs baseline: 1.1607x; 1.0292x over previous
//
#include <hip/hip_runtime.h>
#include <stdint.h>

#define DIM 512
#define NHD 16
#define HD 32
#define NTOK 16384

typedef unsigned short u16;
typedef __attribute__((ext_vector_type(8))) short short8;  // 8 bf16 (4 VGPRs)
typedef __attribute__((ext_vector_type(4))) float f32x4;

__device__ __forceinline__ float bflo(unsigned u){ union{unsigned i; float f;} c; c.i=u<<16; return c.f; }
__device__ __forceinline__ float bfhi(unsigned u){ union{unsigned i; float f;} c; c.i=u&0xffff0000u; return c.f; }
__device__ __forceinline__ u16 f2bf(float f){ union{float f; unsigned i;} c; c.f=f; unsigned r=(c.i + 0x7fffu + ((c.i>>16)&1u))>>16; return (u16)r; }

__device__ __forceinline__ int win_to_tok(int r, int shifted){
  int win = r >> 7, n = r & 127;
  int a = win >> 6, b = (win >> 3) & 7, c = win & 7;
  int ic = n >> 6, ih = (n >> 3) & 7, iw = n & 7;
  int gc = a*2 + ic, gh = b*8 + ih, gw = c*8 + iw;
  if (shifted){ gc = (gc + 1) & 3; gh = (gh + 4) & 63; gw = (gw + 4) & 63; }
  return (gc << 12) + (gh << 6) + gw;
}

__device__ __forceinline__ void gload16(const void* g, void* l){
  __builtin_amdgcn_global_load_lds(
    (const __attribute__((address_space(1))) unsigned int*)(unsigned long long)g,
    (__attribute__((address_space(3))) unsigned int*)(unsigned int)(unsigned long long)l,
    16, 0, 0);
}

// ---------------- weight transpose + bf16 cast (batched over 2 model-blocks via z) ----------------
__global__ __launch_bounds__(256)
void transpose_kernel(const float* __restrict__ W, u16* __restrict__ Wt, int K, int N)
{
  __shared__ float t[32][33];
  size_t zoff = (size_t)blockIdx.z * K * N;
  int n0 = blockIdx.x*32, k0 = blockIdx.y*32;
  int tx = threadIdx.x & 31, ty = threadIdx.x >> 5;
  #pragma unroll
  for (int i=0;i<4;i++) t[ty + i*8][tx] = W[zoff + (size_t)(k0 + ty + i*8)*N + n0 + tx];
  __syncthreads();
  #pragma unroll
  for (int i=0;i<4;i++) Wt[zoff + (size_t)(n0 + ty + i*8)*K + k0 + tx] = f2bf(t[tx][ty + i*8]);
}

// ---------------- fused first-LN: reads f32 x, writes LN->bufA (window order) AND raw bf16 -> xbf ----------------
__global__ __launch_bounds__(256)
void ln_f32cvt_kernel(const float* __restrict__ x, const float* __restrict__ g,
                      const float* __restrict__ b, u16* __restrict__ out, u16* __restrict__ xbf)
{
  int wave = threadIdx.x >> 6, lane = threadIdx.x & 63;
  int r = blockIdx.x * 4 + wave;
  int src = win_to_tok(r, 0);
  const float4* xr = (const float4*)(x + (size_t)src * DIM);
  float4 v0 = xr[lane*2], v1 = xr[lane*2+1];
  float xv[8] = {v0.x,v0.y,v0.z,v0.w,v1.x,v1.y,v1.z,v1.w};
  union{u16 us[8]; uint4 u;} raw;
  #pragma unroll
  for (int j=0;j<8;j++) raw.us[j] = f2bf(xv[j]);
  ((uint4*)(xbf + (size_t)src*DIM))[lane] = raw.u;
  float s = 0.f, sq = 0.f;
  #pragma unroll
  for (int j=0;j<8;j++){ s += xv[j]; sq += xv[j]*xv[j]; }
  #pragma unroll
  for (int o=32;o;o>>=1){ s += __shfl_xor(s,o); sq += __shfl_xor(sq,o); }
  float mean = s*(1.f/DIM);
  float var  = sq*(1.f/DIM) - mean*mean;
  float rstd = rsqrtf(var + 1e-5f);
  int c0 = lane*8;
  const float4* g4 = (const float4*)(g + c0);
  const float4* b4 = (const float4*)(b + c0);
  float4 ga = g4[0], gb = g4[1], ba = b4[0], bb = b4[1];
  float gg[8] = {ga.x,ga.y,ga.z,ga.w,gb.x,gb.y,gb.z,gb.w};
  float bv[8] = {ba.x,ba.y,ba.z,ba.w,bb.x,bb.y,bb.z,bb.w};
  union{u16 us[8]; uint4 u;} p;
  #pragma unroll
  for (int j=0;j<8;j++) p.us[j] = f2bf((xv[j]-mean)*rstd*gg[j] + bv[j]);
  ((uint4*)(out + (size_t)r*DIM))[lane] = p.u;
}

// ---------------- LayerNorm on bf16 residual (+optional window gather w/ roll) -> bf16 ----------------
__global__ __launch_bounds__(256)
void ln_kernel(const u16* __restrict__ x, const float* __restrict__ g,
               const float* __restrict__ b, u16* __restrict__ out, int mode)
{
  int wave = threadIdx.x >> 6, lane = threadIdx.x & 63;
  int r = blockIdx.x * 4 + wave;
  int src = (mode < 0) ? r : win_to_tok(r, mode);
  uint4 u = ((const uint4*)(x + (size_t)src * DIM))[lane];
  unsigned w[4] = {u.x, u.y, u.z, u.w};
  float xv[8];
  #pragma unroll
  for (int j=0;j<4;j++){ xv[2*j] = bflo(w[j]); xv[2*j+1] = bfhi(w[j]); }
  float s = 0.f, sq = 0.f;
  #pragma unroll
  for (int j=0;j<8;j++){ s += xv[j]; sq += xv[j]*xv[j]; }
  #pragma unroll
  for (int o=32;o;o>>=1){ s += __shfl_xor(s,o); sq += __shfl_xor(sq,o); }
  float mean = s*(1.f/DIM);
  float var  = sq*(1.f/DIM) - mean*mean;
  float rstd = rsqrtf(var + 1e-5f);
  int c0 = lane*8;
  const float4* g4 = (const float4*)(g + c0);
  const float4* b4 = (const float4*)(b + c0);
  float4 ga = g4[0], gb = g4[1], ba = b4[0], bb = b4[1];
  float gg[8] = {ga.x,ga.y,ga.z,ga.w,gb.x,gb.y,gb.z,gb.w};
  float bv[8] = {ba.x,ba.y,ba.z,ba.w,bb.x,bb.y,bb.z,bb.w};
  union{u16 us[8]; uint4 u;} p;
  #pragma unroll
  for (int j=0;j<8;j++) p.us[j] = f2bf((xv[j]-mean)*rstd*gg[j] + bv[j]);
  ((uint4*)(out + (size_t)r*DIM))[lane] = p.u;
}

// ============ gemm32r: 128x128 tile, BK=32, 3-slot LDS ring, counted vmcnt (R12-proven) ============
// EPI 0: store bf16 (qkv)        EPI 1: scatter += into bf16 residual (proj, win_rev+roll)
// EPI 2: tanh-gelu -> bf16 (fc1) EPI 3: += bf16 residual (fc2 block0)
// EPI 4: final fc2: read bf16 residual, add, write f32 d_out
template<int EPI>
__global__ __launch_bounds__(256)
void gemm32r_kernel(const u16* __restrict__ X, const u16* __restrict__ Wt,
                    const float* __restrict__ bias, u16* __restrict__ obf,
                    u16* __restrict__ xbf, float* __restrict__ outf,
                    int M, int N, int K, int shifted)
{
  __shared__ u16 smem[24576];    // 48KB: A slot s @ s*4096, B slot s @ 12288+s*4096 (elems)
  int tid = threadIdx.x, wave = tid>>6, lane = tid&63;
  int nwg = gridDim.x * gridDim.y;
  int bid = blockIdx.y * gridDim.x + blockIdx.x;
  int wg  = (bid & 7) * (nwg >> 3) + (bid >> 3);
  int n0 = (wg % gridDim.x) * 128;
  int m0 = (wg / gridDim.x) * 128;
  int wm = (wave>>1)*64, wn = (wave&1)*64;
  f32x4 acc[4][4] = {};

  int r_[2], c_[2];
  #pragma unroll
  for (int q=0;q<2;q++){
    int line = q*32 + (tid>>3), slot = tid&7;
    int u = slot ^ (line&7);
    r_[q] = line*2 + (u>>2); c_[q] = u&3;
  }

  auto stage = [&](int s, int kb){
    u16* Ad = smem + s*4096;
    u16* Bd = smem + 12288 + s*4096;
    #pragma unroll
    for (int q=0;q<2;q++){
      gload16(X + (size_t)(m0 + r_[q])*K + kb + c_[q]*8, (void*)(Ad + q*2048 + tid*8));
      gload16(Wt + (size_t)(n0 + r_[q])*K + kb + c_[q]*8, (void*)(Bd + q*2048 + tid*8));
    }
  };
  auto ldfrag = [&](const u16* base, int row0)->short8 {
    int r = row0 + (lane&15);
    int slot = (((r&1)<<2) + (lane>>4)) ^ ((r>>1)&7);
    return *(const short8*)((const char*)base + (r>>1)*128 + slot*16);
  };

  int nt = K >> 5;
  stage(0, 0); stage(1, 32);
  asm volatile("s_waitcnt vmcnt(4)" ::: "memory");
  __builtin_amdgcn_sched_barrier(0);
  __builtin_amdgcn_s_barrier();
  __builtin_amdgcn_sched_barrier(0);

  int s = 0;
  for (int t=0; t<nt; ++t){
    int s2 = s+2; if (s2>=3) s2-=3;
    if (t+2 < nt) stage(s2, (t+2)<<5);
    const u16* Ab = smem + s*4096;
    const u16* Bb = smem + 12288 + s*4096;
    short8 af[4], bfr[4];
    #pragma unroll
    for (int mi=0;mi<4;mi++) af[mi]  = ldfrag(Ab, wm + mi*16);
    #pragma unroll
    for (int nj=0;nj<4;nj++) bfr[nj] = ldfrag(Bb, wn + nj*16);
    __builtin_amdgcn_s_setprio(1);
    #pragma unroll
    for (int mi=0;mi<4;mi++)
      #pragma unroll
      for (int nj=0;nj<4;nj++)
        acc[mi][nj] = __builtin_amdgcn_mfma_f32_16x16x32_bf16(af[mi], bfr[nj], acc[mi][nj], 0,0,0);
    __builtin_amdgcn_s_setprio(0);
    asm volatile("s_waitcnt lgkmcnt(0)" ::: "memory");
    __builtin_amdgcn_sched_barrier(0);
    if (t+1 < nt){
      if (t+2 < nt) asm volatile("s_waitcnt vmcnt(4)" ::: "memory");
      else          asm volatile("s_waitcnt vmcnt(0)" ::: "memory");
      __builtin_amdgcn_sched_barrier(0);
    }
    __builtin_amdgcn_s_barrier();
    __builtin_amdgcn_sched_barrier(0);
    s = (s==2) ? 0 : s+1;
  }

  // ---- epilogue (R12-proven) ----
  int lr = (lane>>4)*4, lc = lane&15;
  if (EPI==0 || EPI==2){
    u16* et = smem;                         // [128][128] bf16 = 32KB, byte ^= ((row>>2)&3)<<5
    #pragma unroll
    for (int mi=0;mi<4;mi++){
      #pragma unroll
      for (int nj=0;nj<4;nj++){
        int col = wn + nj*16 + lc;
        float bv = bias[n0 + col];
        #pragma unroll
        for (int rr=0;rr<4;rr++){
          int row = wm + mi*16 + lr + rr;
          float v = acc[mi][nj][rr] + bv;
          if (EPI==2){
            float u2 = v*(1.5957691216057308f + 0.0713548162726f*v*v);
            v = v * __builtin_amdgcn_rcpf(1.f + __expf(-u2));   // tanh-GELU
          }
          *(u16*)((char*)et + ((row*256 + col*2) ^ (((row>>2)&3)<<5))) = f2bf(v);
        }
      }
    }
    __syncthreads();
    #pragma unroll
    for (int j=0;j<8;j++){
      int q = j*256 + tid;
      int row = q>>4, cc = q&15;
      uint4 d = *(const uint4*)((char*)et + ((row*256 + cc*16) ^ (((row>>2)&3)<<5)));
      *(uint4*)(obf + (size_t)(m0+row)*N + n0 + cc*8) = d;
    }
  } else {
    // EPI 1/3/4: f32 repack in two 64-row halves, then bf16-residual RMW (or f32 final store)
    float* et = (float*)smem;               // [64][128] f32 = 32KB, byte ^= ((row>>2)&1)<<6
    #pragma unroll
    for (int half=0; half<2; ++half){
      __syncthreads();
      if ((wm>>6) == half){
        #pragma unroll
        for (int mi=0;mi<4;mi++){
          #pragma unroll
          for (int nj=0;nj<4;nj++){
            int col = wn + nj*16 + lc;
            float bv = bias[n0 + col];
            #pragma unroll
            for (int rr=0;rr<4;rr++){
              int row = (wm & 63) + mi*16 + lr + rr;
              *(float*)((char*)et + ((row*512 + col*4) ^ (((row>>2)&1)<<6))) = acc[mi][nj][rr] + bv;
            }
          }
        }
      }
      __syncthreads();
      #pragma unroll
      for (int j=0;j<4;j++){
        int q = j*256 + tid;                // 1024 chunks of 8 cols
        int row = q>>4, c8 = q&15;
        int swz = ((row>>2)&1)<<6;
        float4 d0 = *(const float4*)((char*)et + ((row*512 + c8*32     ) ^ swz));
        float4 d1 = *(const float4*)((char*)et + ((row*512 + c8*32 + 16) ^ swz));
        int lrow = m0 + half*64 + row;
        int grow = (EPI==1) ? win_to_tok(lrow, shifted) : lrow;
        size_t gofs = (size_t)grow*DIM + n0 + c8*8;
        uint4 xv = *(const uint4*)(xbf + gofs);
        unsigned xw[4] = {xv.x, xv.y, xv.z, xv.w};
        float xs[8];
        #pragma unroll
        for (int k2=0;k2<4;k2++){ xs[2*k2] = bflo(xw[k2]); xs[2*k2+1] = bfhi(xw[k2]); }
        float ds[8] = {d0.x,d0.y,d0.z,d0.w,d1.x,d1.y,d1.z,d1.w};
        if (EPI==4){
          float4 o0 = {xs[0]+ds[0], xs[1]+ds[1], xs[2]+ds[2], xs[3]+ds[3]};
          float4 o1 = {xs[4]+ds[4], xs[5]+ds[5], xs[6]+ds[6], xs[7]+ds[7]};
          float4* op = (float4*)(outf + gofs);
          op[0] = o0; op[1] = o1;
        } else {
          union{u16 us[8]; uint4 u;} nw;
          #pragma unroll
          for (int k2=0;k2<8;k2++) nw.us[k2] = f2bf(xs[k2] + ds[k2]);
          *(uint4*)(xbf + gofs) = nw.u;
        }
      }
    }
  }
}

// ---------------- rel-pos bias expansion for BOTH blocks: biasM2[i][h][q][k] ----------------
__global__ __launch_bounds__(256)
void bias_kernel(const float* __restrict__ btab, float* __restrict__ biasM2)
{
  int gid = blockIdx.x*256 + threadIdx.x;   // 2*16*128*128
  int q = (gid >> 7) & 127, k = gid & 127, h = (gid >> 14) & 15, i = gid >> 18;
  int ic=q>>6, ih=(q>>3)&7, iw=q&7, jc=k>>6, jh=(k>>3)&7, jw=k&7;
  int idx = (ic-jc+1)*225 + (ih-jh+7)*15 + (iw-jw+7);
  biasM2[gid] = btab[(size_t)i*675*16 + idx*16 + h];
}

// ---------------- MFMA windowed attention ----------------
__global__ __launch_bounds__(256)
void attn_kernel(const u16* __restrict__ qkv, const float* __restrict__ biasM,
                 u16* __restrict__ out, int shifted)
{
  __shared__ u16 Ks[128*32];
  __shared__ u16 VsT[32*128];
  __shared__ u16 Ps[4][32*128];
  __shared__ int rid[128];
  int win = blockIdx.x >> 4, h = blockIdx.x & 15;
  int tid = threadIdx.x, wave = tid>>6, lane = tid&63;
  size_t base = (size_t)win*128*1536 + (size_t)h*32;

  {
    int m = tid>>1, half = tid&1;
    const uint4* ks = (const uint4*)(qkv + base + (size_t)m*1536 + 512 + half*16);
    uint4 k0v = ks[0], k1v = ks[1];
    char* krow = (char*)Ks + m*64;
    int c0 = half*32, sw = (m&3)<<4;
    *(uint4*)(krow + ((c0     ) ^ sw)) = k0v;
    *(uint4*)(krow + ((c0 + 16) ^ sw)) = k1v;
    const uint4* vs = (const uint4*)(qkv + base + (size_t)m*1536 + 1024 + half*16);
    union{u16 us[16]; uint4 u[2];} vv; vv.u[0]=vs[0]; vv.u[1]=vs[1];
    #pragma unroll
    for (int j=0;j<16;j++){
      int d = half*16 + j;
      *(u16*)((char*)VsT + ((d*256 + m*2) ^ ((d&7)<<4))) = vv.us[j];
    }
  }
  if (shifted && tid < 128){
    int a=win>>6, b=(win>>3)&7, c=win&7;
    int gc=a*2+(tid>>6), gh=b*8+((tid>>3)&7), gw=c*8+(tid&7);
    int rc = (gc<2)?0:((gc<3)?1:2);
    int rh = (gh<56)?0:((gh<60)?1:2);
    int rw = (gw<56)?0:((gw<60)?1:2);
    rid[tid] = rc*9 + rh*3 + rw;
  }
  __syncthreads();

  int q0 = wave*32;
  short8 qf[2];
  #pragma unroll
  for (int mi=0;mi<2;mi++){
    int ql = 16*mi + (lane&15);
    qf[mi] = *(const short8*)(qkv + base + (size_t)(q0+ql)*1536 + (lane>>4)*8);
  }
  f32x4 s[2][8] = {};
  #pragma unroll
  for (int nj=0;nj<8;nj++){
    int row = (lane&15) + 16*nj;
    short8 kf = *(const short8*)((char*)Ks + row*64 + ((((lane>>4)<<4)) ^ ((row&3)<<4)));
    #pragma unroll
    for (int mi=0;mi<2;mi++)
      s[mi][nj] = __builtin_amdgcn_mfma_f32_16x16x32_bf16(qf[mi], kf, s[mi][nj], 0,0,0);
  }

  int rk[8];
  if (shifted){
    #pragma unroll
    for (int nj=0;nj<8;nj++) rk[nj] = rid[(lane&15) + 16*nj];
  }
  float invl[2][4];
  char* pbase = (char*)Ps[wave];
  #pragma unroll
  for (int mi=0;mi<2;mi++){
    #pragma unroll
    for (int r=0;r<4;r++){
      int ql = 16*mi + ((lane>>4)<<2) + r;
      int qw = q0 + ql;
      const float* bp = biasM + (((h<<7) + qw)<<7) + (lane&15);
      int rq = shifted ? rid[qw] : 0;
      float sv[8]; float mx = -1e30f;
      #pragma unroll
      for (int nj=0;nj<8;nj++){
        float v = s[mi][nj][r] * 0.17677669529663687f + bp[nj*16];
        if (shifted && rk[nj] != rq) v -= 100.f;
        sv[nj] = v; mx = fmaxf(mx, v);
      }
      #pragma unroll
      for (int o=1;o<16;o<<=1) mx = fmaxf(mx, __shfl_xor(mx, o));
      float sum = 0.f;
      #pragma unroll
      for (int nj=0;nj<8;nj++){ float p = __expf(sv[nj]-mx); sv[nj]=p; sum += p; }
      #pragma unroll
      for (int o=1;o<16;o<<=1) sum += __shfl_xor(sum, o);
      invl[mi][r] = 1.f/sum;
      char* prow = pbase + ql*256;
      int sw = (ql&7)<<4;
      #pragma unroll
      for (int nj=0;nj<8;nj++)
        *(u16*)(prow + ((((lane&15) + (nj<<4))<<1) ^ sw)) = f2bf(sv[nj]);
    }
  }

  f32x4 o2[2][2] = {};
  #pragma unroll
  for (int kk=0;kk<4;kk++){
    int coff = kk*64 + ((lane>>4)<<4);
    short8 pa[2], vb[2];
    #pragma unroll
    for (int mi=0;mi<2;mi++){
      int ql = 16*mi + (lane&15);
      pa[mi] = *(const short8*)(pbase + ql*256 + (coff ^ ((ql&7)<<4)));
    }
    #pragma unroll
    for (int nj=0;nj<2;nj++){
      int d = (lane&15) + 16*nj;
      vb[nj] = *(const short8*)((char*)VsT + d*256 + (coff ^ ((d&7)<<4)));
    }
    #pragma unroll
    for (int mi=0;mi<2;mi++)
      #pragma unroll
      for (int nj=0;nj<2;nj++)
        o2[mi][nj] = __builtin_amdgcn_mfma_f32_16x16x32_bf16(pa[mi], vb[nj], o2[mi][nj], 0,0,0);
  }

  #pragma unroll
  for (int mi=0;mi<2;mi++){
    #pragma unroll
    for (int nj=0;nj<2;nj++){
      #pragma unroll
      for (int r=0;r<4;r++){
        int ql = 16*mi + ((lane>>4)<<2) + r;
        int d  = (lane&15) + (nj<<4);
        out[(size_t)(win*128 + q0 + ql)*DIM + (h<<5) + d] = f2bf(o2[mi][nj][r] * invl[mi][r]);
      }
    }
  }
}

// ---------------- host launcher ----------------
extern "C" void kernel_launch(void* const* d_in, const int* in_sizes, int n_in,
                              void* d_out, int out_size, void* d_ws, size_t ws_size,
                              hipStream_t stream)
{
  const float* x_in   = (const float*)d_in[0];
  const float* ln1_g  = (const float*)d_in[1];
  const float* ln1_b  = (const float*)d_in[2];
  const float* qkv_w  = (const float*)d_in[3];
  const float* qkv_b  = (const float*)d_in[4];
  const float* btab   = (const float*)d_in[5];
  const float* proj_w = (const float*)d_in[6];
  const float* proj_b = (const float*)d_in[7];
  const float* ln2_g  = (const float*)d_in[8];
  const float* ln2_b  = (const float*)d_in[9];
  const float* fc1_w  = (const float*)d_in[10];
  const float* fc1_b  = (const float*)d_in[11];
  const float* fc2_w  = (const float*)d_in[12];
  const float* fc2_b  = (const float*)d_in[13];

  char* ws = (char*)d_ws;
  size_t off = 0;
  auto alloc = [&](size_t bytes)->char*{ char* p = ws + off; off += (bytes + 255) & ~(size_t)255; return p; };
  u16* wT_qkv = (u16*)alloc((size_t)2*512*1536*2);
  u16* wT_proj= (u16*)alloc((size_t)2*512*512*2);
  u16* wT_fc1 = (u16*)alloc((size_t)2*2048*512*2);
  u16* wT_fc2 = (u16*)alloc((size_t)2*512*2048*2);
  u16* bufA   = (u16*)alloc((size_t)16384*2048*2);
  u16* bufQ   = (u16*)alloc((size_t)16384*1536*2);
  u16* bufB   = (u16*)alloc((size_t)16384*512*2);
  u16* xbf    = (u16*)alloc((size_t)16384*512*2);
  float* biasM2=(float*)alloc((size_t)2*16*128*128*4);
  (void)ws_size; (void)in_sizes; (void)n_in; (void)out_size;

  float* xout = (float*)d_out;

  transpose_kernel<<<dim3(1536/32, 512/32, 2), 256, 0, stream>>>(qkv_w, wT_qkv, 512, 1536);
  transpose_kernel<<<dim3( 512/32, 512/32, 2), 256, 0, stream>>>(proj_w, wT_proj, 512, 512);
  transpose_kernel<<<dim3(2048/32, 512/32, 2), 256, 0, stream>>>(fc1_w, wT_fc1, 512, 2048);
  transpose_kernel<<<dim3( 512/32,2048/32, 2), 256, 0, stream>>>(fc2_w, wT_fc2, 2048, 512);
  bias_kernel<<<2048, 256, 0, stream>>>(btab, biasM2);

  for (int i=0;i<2;i++){
    if (i==0)
      ln_f32cvt_kernel<<<4096, 256, 0, stream>>>(x_in, ln1_g, ln1_b, bufA, xbf);
    else
      ln_kernel<<<4096, 256, 0, stream>>>(xbf, ln1_g+512, ln1_b+512, bufA, 1);
    gemm32r_kernel<0><<<dim3(12,128), 256, 0, stream>>>(bufA, wT_qkv+(size_t)i*512*1536, qkv_b+i*1536, bufQ, nullptr, nullptr, NTOK,1536,512, 0);
    attn_kernel<<<2048, 256, 0, stream>>>(bufQ, biasM2 + (size_t)i*16*128*128, bufB, i);
    gemm32r_kernel<1><<<dim3(4,128), 256, 0, stream>>>(bufB, wT_proj+(size_t)i*512*512, proj_b+i*512, nullptr, xbf, nullptr, NTOK,512,512, i);
    ln_kernel<<<4096, 256, 0, stream>>>(xbf, ln2_g+i*512, ln2_b+i*512, bufB, -1);
    gemm32r_kernel<2><<<dim3(16,128), 256, 0, stream>>>(bufB, wT_fc1+(size_t)i*2048*512, fc1_b+i*2048, bufA, nullptr, nullptr, NTOK,2048,512, 0);
    if (i==0)
      gemm32r_kernel<3><<<dim3(4,128), 256, 0, stream>>>(bufA, wT_fc2+(size_t)i*512*2048, fc2_b+i*512, nullptr, xbf, nullptr, NTOK,512,2048, 0);
    else
      gemm32r_kernel<4><<<dim3(4,128), 256, 0, stream>>>(bufA, wT_fc2+(size_t)i*512*2048, fc2_b+i*512, nullptr, xbf, xout, NTOK,512,2048, 0);
  }
}

// Round 17
// 420.992 us; speedup vs baseline: 1.1692x; 1.0073x over previous
//
#include <hip/hip_runtime.h>
#include <stdint.h>

#define DIM 512
#define NHD 16
#define HD 32
#define NTOK 16384

typedef unsigned short u16;
typedef __attribute__((ext_vector_type(8))) short short8;  // 8 bf16 (4 VGPRs)
typedef __attribute__((ext_vector_type(4))) float f32x4;

__device__ __forceinline__ float bflo(unsigned u){ union{unsigned i; float f;} c; c.i=u<<16; return c.f; }
__device__ __forceinline__ float bfhi(unsigned u){ union{unsigned i; float f;} c; c.i=u&0xffff0000u; return c.f; }
__device__ __forceinline__ u16 f2bf(float f){ union{float f; unsigned i;} c; c.f=f; unsigned r=(c.i + 0x7fffu + ((c.i>>16)&1u))>>16; return (u16)r; }

__device__ __forceinline__ int win_to_tok(int r, int shifted){
  int win = r >> 7, n = r & 127;
  int a = win >> 6, b = (win >> 3) & 7, c = win & 7;
  int ic = n >> 6, ih = (n >> 3) & 7, iw = n & 7;
  int gc = a*2 + ic, gh = b*8 + ih, gw = c*8 + iw;
  if (shifted){ gc = (gc + 1) & 3; gh = (gh + 4) & 63; gw = (gw + 4) & 63; }
  return (gc << 12) + (gh << 6) + gw;
}

__device__ __forceinline__ void gload16(const void* g, void* l){
  __builtin_amdgcn_global_load_lds(
    (const __attribute__((address_space(1))) unsigned int*)(unsigned long long)g,
    (__attribute__((address_space(3))) unsigned int*)(unsigned int)(unsigned long long)l,
    16, 0, 0);
}

// ---------------- weight transpose + bf16 cast (batched over 2 model-blocks via z) ----------------
__global__ __launch_bounds__(256)
void transpose_kernel(const float* __restrict__ W, u16* __restrict__ Wt, int K, int N)
{
  __shared__ float t[32][33];
  size_t zoff = (size_t)blockIdx.z * K * N;
  int n0 = blockIdx.x*32, k0 = blockIdx.y*32;
  int tx = threadIdx.x & 31, ty = threadIdx.x >> 5;
  #pragma unroll
  for (int i=0;i<4;i++) t[ty + i*8][tx] = W[zoff + (size_t)(k0 + ty + i*8)*N + n0 + tx];
  __syncthreads();
  #pragma unroll
  for (int i=0;i<4;i++) Wt[zoff + (size_t)(n0 + ty + i*8)*K + k0 + tx] = f2bf(t[tx][ty + i*8]);
}

// ---------------- fused first-LN: reads f32 x, writes LN->bufA (window order) AND raw bf16 -> xbf ----------------
__global__ __launch_bounds__(256)
void ln_f32cvt_kernel(const float* __restrict__ x, const float* __restrict__ g,
                      const float* __restrict__ b, u16* __restrict__ out, u16* __restrict__ xbf)
{
  int wave = threadIdx.x >> 6, lane = threadIdx.x & 63;
  int r = blockIdx.x * 4 + wave;
  int src = win_to_tok(r, 0);
  const float4* xr = (const float4*)(x + (size_t)src * DIM);
  float4 v0 = xr[lane*2], v1 = xr[lane*2+1];
  float xv[8] = {v0.x,v0.y,v0.z,v0.w,v1.x,v1.y,v1.z,v1.w};
  union{u16 us[8]; uint4 u;} raw;
  #pragma unroll
  for (int j=0;j<8;j++) raw.us[j] = f2bf(xv[j]);
  ((uint4*)(xbf + (size_t)src*DIM))[lane] = raw.u;
  float s = 0.f, sq = 0.f;
  #pragma unroll
  for (int j=0;j<8;j++){ s += xv[j]; sq += xv[j]*xv[j]; }
  #pragma unroll
  for (int o=32;o;o>>=1){ s += __shfl_xor(s,o); sq += __shfl_xor(sq,o); }
  float mean = s*(1.f/DIM);
  float var  = sq*(1.f/DIM) - mean*mean;
  float rstd = rsqrtf(var + 1e-5f);
  int c0 = lane*8;
  const float4* g4 = (const float4*)(g + c0);
  const float4* b4 = (const float4*)(b + c0);
  float4 ga = g4[0], gb = g4[1], ba = b4[0], bb = b4[1];
  float gg[8] = {ga.x,ga.y,ga.z,ga.w,gb.x,gb.y,gb.z,gb.w};
  float bv[8] = {ba.x,ba.y,ba.z,ba.w,bb.x,bb.y,bb.z,bb.w};
  union{u16 us[8]; uint4 u;} p;
  #pragma unroll
  for (int j=0;j<8;j++) p.us[j] = f2bf((xv[j]-mean)*rstd*gg[j] + bv[j]);
  ((uint4*)(out + (size_t)r*DIM))[lane] = p.u;
}

// ---------------- LayerNorm on bf16 residual (+optional window gather w/ roll) -> bf16 ----------------
__global__ __launch_bounds__(256)
void ln_kernel(const u16* __restrict__ x, const float* __restrict__ g,
               const float* __restrict__ b, u16* __restrict__ out, int mode)
{
  int wave = threadIdx.x >> 6, lane = threadIdx.x & 63;
  int r = blockIdx.x * 4 + wave;
  int src = (mode < 0) ? r : win_to_tok(r, mode);
  uint4 u = ((const uint4*)(x + (size_t)src * DIM))[lane];
  unsigned w[4] = {u.x, u.y, u.z, u.w};
  float xv[8];
  #pragma unroll
  for (int j=0;j<4;j++){ xv[2*j] = bflo(w[j]); xv[2*j+1] = bfhi(w[j]); }
  float s = 0.f, sq = 0.f;
  #pragma unroll
  for (int j=0;j<8;j++){ s += xv[j]; sq += xv[j]*xv[j]; }
  #pragma unroll
  for (int o=32;o;o>>=1){ s += __shfl_xor(s,o); sq += __shfl_xor(sq,o); }
  float mean = s*(1.f/DIM);
  float var  = sq*(1.f/DIM) - mean*mean;
  float rstd = rsqrtf(var + 1e-5f);
  int c0 = lane*8;
  const float4* g4 = (const float4*)(g + c0);
  const float4* b4 = (const float4*)(b + c0);
  float4 ga = g4[0], gb = g4[1], ba = b4[0], bb = b4[1];
  float gg[8] = {ga.x,ga.y,ga.z,ga.w,gb.x,gb.y,gb.z,gb.w};
  float bv[8] = {ba.x,ba.y,ba.z,ba.w,bb.x,bb.y,bb.z,bb.w};
  union{u16 us[8]; uint4 u;} p;
  #pragma unroll
  for (int j=0;j<8;j++) p.us[j] = f2bf((xv[j]-mean)*rstd*gg[j] + bv[j]);
  ((uint4*)(out + (size_t)r*DIM))[lane] = p.u;
}

// ============ gemm32r: 128x128 tile, BK=32, 3-slot LDS ring, counted vmcnt (R12-proven) ============
// EPI 0: store bf16 (qkv)        EPI 1: scatter += into bf16 residual (proj, win_rev+roll)
// EPI 2: tanh-gelu -> bf16 (fc1) EPI 3: += bf16 residual (fc2 block0)
// EPI 4: final fc2: read bf16 residual, add, write f32 d_out
template<int EPI>
__global__ __launch_bounds__(256)
void gemm32r_kernel(const u16* __restrict__ X, const u16* __restrict__ Wt,
                    const float* __restrict__ bias, u16* __restrict__ obf,
                    u16* __restrict__ xbf, float* __restrict__ outf,
                    int M, int N, int K, int shifted)
{
  __shared__ u16 smem[24576];    // 48KB: A slot s @ s*4096, B slot s @ 12288+s*4096 (elems)
  int tid = threadIdx.x, wave = tid>>6, lane = tid&63;
  int nwg = gridDim.x * gridDim.y;
  int bid = blockIdx.y * gridDim.x + blockIdx.x;
  int wg  = (bid & 7) * (nwg >> 3) + (bid >> 3);
  int n0 = (wg % gridDim.x) * 128;
  int m0 = (wg / gridDim.x) * 128;
  int wm = (wave>>1)*64, wn = (wave&1)*64;
  f32x4 acc[4][4] = {};

  int r_[2], c_[2];
  #pragma unroll
  for (int q=0;q<2;q++){
    int line = q*32 + (tid>>3), slot = tid&7;
    int u = slot ^ (line&7);
    r_[q] = line*2 + (u>>2); c_[q] = u&3;
  }

  auto stage = [&](int s, int kb){
    u16* Ad = smem + s*4096;
    u16* Bd = smem + 12288 + s*4096;
    #pragma unroll
    for (int q=0;q<2;q++){
      gload16(X + (size_t)(m0 + r_[q])*K + kb + c_[q]*8, (void*)(Ad + q*2048 + tid*8));
      gload16(Wt + (size_t)(n0 + r_[q])*K + kb + c_[q]*8, (void*)(Bd + q*2048 + tid*8));
    }
  };
  auto ldfrag = [&](const u16* base, int row0)->short8 {
    int r = row0 + (lane&15);
    int slot = (((r&1)<<2) + (lane>>4)) ^ ((r>>1)&7);
    return *(const short8*)((const char*)base + (r>>1)*128 + slot*16);
  };

  int nt = K >> 5;
  stage(0, 0); stage(1, 32);
  asm volatile("s_waitcnt vmcnt(4)" ::: "memory");
  __builtin_amdgcn_sched_barrier(0);
  __builtin_amdgcn_s_barrier();
  __builtin_amdgcn_sched_barrier(0);

  int s = 0;
  for (int t=0; t<nt; ++t){
    int s2 = s+2; if (s2>=3) s2-=3;
    if (t+2 < nt) stage(s2, (t+2)<<5);
    const u16* Ab = smem + s*4096;
    const u16* Bb = smem + 12288 + s*4096;
    short8 af[4], bfr[4];
    #pragma unroll
    for (int mi=0;mi<4;mi++) af[mi]  = ldfrag(Ab, wm + mi*16);
    #pragma unroll
    for (int nj=0;nj<4;nj++) bfr[nj] = ldfrag(Bb, wn + nj*16);
    __builtin_amdgcn_s_setprio(1);
    #pragma unroll
    for (int mi=0;mi<4;mi++)
      #pragma unroll
      for (int nj=0;nj<4;nj++)
        acc[mi][nj] = __builtin_amdgcn_mfma_f32_16x16x32_bf16(af[mi], bfr[nj], acc[mi][nj], 0,0,0);
    __builtin_amdgcn_s_setprio(0);
    asm volatile("s_waitcnt lgkmcnt(0)" ::: "memory");
    __builtin_amdgcn_sched_barrier(0);
    if (t+1 < nt){
      if (t+2 < nt) asm volatile("s_waitcnt vmcnt(4)" ::: "memory");
      else          asm volatile("s_waitcnt vmcnt(0)" ::: "memory");
      __builtin_amdgcn_sched_barrier(0);
    }
    __builtin_amdgcn_s_barrier();
    __builtin_amdgcn_sched_barrier(0);
    s = (s==2) ? 0 : s+1;
  }

  // ---- epilogue (R12-proven) ----
  int lr = (lane>>4)*4, lc = lane&15;
  if (EPI==0 || EPI==2){
    u16* et = smem;                         // [128][128] bf16 = 32KB, byte ^= ((row>>2)&3)<<5
    #pragma unroll
    for (int mi=0;mi<4;mi++){
      #pragma unroll
      for (int nj=0;nj<4;nj++){
        int col = wn + nj*16 + lc;
        float bv = bias[n0 + col];
        #pragma unroll
        for (int rr=0;rr<4;rr++){
          int row = wm + mi*16 + lr + rr;
          float v = acc[mi][nj][rr] + bv;
          if (EPI==2){
            float u2 = v*(1.5957691216057308f + 0.0713548162726f*v*v);
            v = v * __builtin_amdgcn_rcpf(1.f + __expf(-u2));   // tanh-GELU
          }
          *(u16*)((char*)et + ((row*256 + col*2) ^ (((row>>2)&3)<<5))) = f2bf(v);
        }
      }
    }
    __syncthreads();
    #pragma unroll
    for (int j=0;j<8;j++){
      int q = j*256 + tid;
      int row = q>>4, cc = q&15;
      uint4 d = *(const uint4*)((char*)et + ((row*256 + cc*16) ^ (((row>>2)&3)<<5)));
      *(uint4*)(obf + (size_t)(m0+row)*N + n0 + cc*8) = d;
    }
  } else {
    // EPI 1/3/4: f32 repack in two 64-row halves, then bf16-residual RMW (or f32 final store)
    float* et = (float*)smem;               // [64][128] f32 = 32KB, byte ^= ((row>>2)&1)<<6
    #pragma unroll
    for (int half=0; half<2; ++half){
      __syncthreads();
      if ((wm>>6) == half){
        #pragma unroll
        for (int mi=0;mi<4;mi++){
          #pragma unroll
          for (int nj=0;nj<4;nj++){
            int col = wn + nj*16 + lc;
            float bv = bias[n0 + col];
            #pragma unroll
            for (int rr=0;rr<4;rr++){
              int row = (wm & 63) + mi*16 + lr + rr;
              *(float*)((char*)et + ((row*512 + col*4) ^ (((row>>2)&1)<<6))) = acc[mi][nj][rr] + bv;
            }
          }
        }
      }
      __syncthreads();
      #pragma unroll
      for (int j=0;j<4;j++){
        int q = j*256 + tid;                // 1024 chunks of 8 cols
        int row = q>>4, c8 = q&15;
        int swz = ((row>>2)&1)<<6;
        float4 d0 = *(const float4*)((char*)et + ((row*512 + c8*32     ) ^ swz));
        float4 d1 = *(const float4*)((char*)et + ((row*512 + c8*32 + 16) ^ swz));
        int lrow = m0 + half*64 + row;
        int grow = (EPI==1) ? win_to_tok(lrow, shifted) : lrow;
        size_t gofs = (size_t)grow*DIM + n0 + c8*8;
        uint4 xv = *(const uint4*)(xbf + gofs);
        unsigned xw[4] = {xv.x, xv.y, xv.z, xv.w};
        float xs[8];
        #pragma unroll
        for (int k2=0;k2<4;k2++){ xs[2*k2] = bflo(xw[k2]); xs[2*k2+1] = bfhi(xw[k2]); }
        float ds[8] = {d0.x,d0.y,d0.z,d0.w,d1.x,d1.y,d1.z,d1.w};
        if (EPI==4){
          float4 o0 = {xs[0]+ds[0], xs[1]+ds[1], xs[2]+ds[2], xs[3]+ds[3]};
          float4 o1 = {xs[4]+ds[4], xs[5]+ds[5], xs[6]+ds[6], xs[7]+ds[7]};
          float4* op = (float4*)(outf + gofs);
          op[0] = o0; op[1] = o1;
        } else {
          union{u16 us[8]; uint4 u;} nw;
          #pragma unroll
          for (int k2=0;k2<8;k2++) nw.us[k2] = f2bf(xs[k2] + ds[k2]);
          *(uint4*)(xbf + gofs) = nw.u;
        }
      }
    }
  }
}

// ---------------- rel-pos bias in bf16, MFMA C-fragment order ----------------
// layout: biasF[i][h][wave][lane][j=mi*4+r][nj] bf16  (per thread: 64 consecutive bf16 = 8 uint4)
__global__ __launch_bounds__(256)
void biasf_kernel(const float* __restrict__ btab, u16* __restrict__ biasF)
{
  int gid = blockIdx.x*256 + threadIdx.x;   // 2*16*4*64*8 = 32768 entries of 8 bf16
  int j = gid & 7;
  int lane = (gid>>3) & 63;
  int wave = (gid>>9) & 3;
  int h = (gid>>11) & 15;
  int i = gid>>15;
  int mi = j>>2, r = j&3;
  int qw = wave*32 + mi*16 + ((lane>>4)<<2) + r;
  int ic=qw>>6, ih=(qw>>3)&7, iw=qw&7;
  const float* bt = btab + (size_t)i*675*16 + h;
  union{u16 us[8]; uint4 u[2];} o;
  #pragma unroll
  for (int nj=0;nj<8;nj++){
    int k = (lane&15) + nj*16;
    int jc=k>>6, jh=(k>>3)&7, jw=k&7;
    int idx = (ic-jc+1)*225 + (ih-jh+7)*15 + (iw-jw+7);
    o.us[nj] = f2bf(bt[idx*16]);
  }
  ((uint4*)(biasF))[gid*1] = o.u[0];
  ((uint4*)(biasF))[0] = ((uint4*)(biasF))[0];  // no-op guard (kept trivial)
  // store 16 bytes at offset gid*16 ... (two uint2 halves as one uint4 pair)
  *(uint4*)(biasF + (size_t)gid*8) = o.u[0];
  *(uint4*)(biasF + (size_t)gid*8 + 4) = o.u[1];
}

// ---------------- MFMA windowed attention (bias via bf16 fragment-order loads) ----------------
__global__ __launch_bounds__(256)
void attn_kernel(const u16* __restrict__ qkv, const u16* __restrict__ biasF,
                 u16* __restrict__ out, int shifted)
{
  __shared__ u16 Ks[128*32];
  __shared__ u16 VsT[32*128];
  __shared__ u16 Ps[4][32*128];
  __shared__ int rid[128];
  int win = blockIdx.x >> 4, h = blockIdx.x & 15;
  int tid = threadIdx.x, wave = tid>>6, lane = tid&63;
  size_t base = (size_t)win*128*1536 + (size_t)h*32;

  {
    int m = tid>>1, half = tid&1;
    const uint4* ks = (const uint4*)(qkv + base + (size_t)m*1536 + 512 + half*16);
    uint4 k0v = ks[0], k1v = ks[1];
    char* krow = (char*)Ks + m*64;
    int c0 = half*32, sw = (m&3)<<4;
    *(uint4*)(krow + ((c0     ) ^ sw)) = k0v;
    *(uint4*)(krow + ((c0 + 16) ^ sw)) = k1v;
    const uint4* vs = (const uint4*)(qkv + base + (size_t)m*1536 + 1024 + half*16);
    union{u16 us[16]; uint4 u[2];} vv; vv.u[0]=vs[0]; vv.u[1]=vs[1];
    #pragma unroll
    for (int j=0;j<16;j++){
      int d = half*16 + j;
      *(u16*)((char*)VsT + ((d*256 + m*2) ^ ((d&7)<<4))) = vv.us[j];
    }
  }
  if (shifted && tid < 128){
    int a=win>>6, b=(win>>3)&7, c=win&7;
    int gc=a*2+(tid>>6), gh=b*8+((tid>>3)&7), gw=c*8+(tid&7);
    int rc = (gc<2)?0:((gc<3)?1:2);
    int rh = (gh<56)?0:((gh<60)?1:2);
    int rw = (gw<56)?0:((gw<60)?1:2);
    rid[tid] = rc*9 + rh*3 + rw;
  }
  __syncthreads();

  int q0 = wave*32;
  short8 qf[2];
  #pragma unroll
  for (int mi=0;mi<2;mi++){
    int ql = 16*mi + (lane&15);
    qf[mi] = *(const short8*)(qkv + base + (size_t)(q0+ql)*1536 + (lane>>4)*8);
  }
  f32x4 s[2][8] = {};
  #pragma unroll
  for (int nj=0;nj<8;nj++){
    int row = (lane&15) + 16*nj;
    short8 kf = *(const short8*)((char*)Ks + row*64 + ((((lane>>4)<<4)) ^ ((row&3)<<4)));
    #pragma unroll
    for (int mi=0;mi<2;mi++)
      s[mi][nj] = __builtin_amdgcn_mfma_f32_16x16x32_bf16(qf[mi], kf, s[mi][nj], 0,0,0);
  }

  int rk[8];
  if (shifted){
    #pragma unroll
    for (int nj=0;nj<8;nj++) rk[nj] = rid[(lane&15) + 16*nj];
  }
  // per-thread bias base: 64 bf16 in fragment order
  const u16* bb = biasF + ((((size_t)h*4 + wave)*64 + lane)*64);
  float invl[2][4];
  char* pbase = (char*)Ps[wave];
  #pragma unroll
  for (int mi=0;mi<2;mi++){
    #pragma unroll
    for (int r=0;r<4;r++){
      int ql = 16*mi + ((lane>>4)<<2) + r;
      int qw = q0 + ql;
      uint4 bu = *(const uint4*)(bb + (mi*4+r)*8);
      unsigned ba[4] = {bu.x, bu.y, bu.z, bu.w};
      int rq = shifted ? rid[qw] : 0;
      float sv[8]; float mx = -1e30f;
      #pragma unroll
      for (int nj=0;nj<8;nj++){
        float bval = (nj&1) ? bfhi(ba[nj>>1]) : bflo(ba[nj>>1]);
        float v = fmaf(s[mi][nj][r], 0.17677669529663687f, bval);
        if (shifted && rk[nj] != rq) v -= 100.f;
        sv[nj] = v; mx = fmaxf(mx, v);
      }
      #pragma unroll
      for (int o=1;o<16;o<<=1) mx = fmaxf(mx, __shfl_xor(mx, o));
      float sum = 0.f;
      #pragma unroll
      for (int nj=0;nj<8;nj++){ float p = __expf(sv[nj]-mx); sv[nj]=p; sum += p; }
      #pragma unroll
      for (int o=1;o<16;o<<=1) sum += __shfl_xor(sum, o);
      invl[mi][r] = 1.f/sum;
      char* prow = pbase + ql*256;
      int sw = (ql&7)<<4;
      #pragma unroll
      for (int nj=0;nj<8;nj++)
        *(u16*)(prow + ((((lane&15) + (nj<<4))<<1) ^ sw)) = f2bf(sv[nj]);
    }
  }

  f32x4 o2[2][2] = {};
  #pragma unroll
  for (int kk=0;kk<4;kk++){
    int coff = kk*64 + ((lane>>4)<<4);
    short8 pa[2], vb[2];
    #pragma unroll
    for (int mi=0;mi<2;mi++){
      int ql = 16*mi + (lane&15);
      pa[mi] = *(const short8*)(pbase + ql*256 + (coff ^ ((ql&7)<<4)));
    }
    #pragma unroll
    for (int nj=0;nj<2;nj++){
      int d = (lane&15) + 16*nj;
      vb[nj] = *(const short8*)((char*)VsT + d*256 + (coff ^ ((d&7)<<4)));
    }
    #pragma unroll
    for (int mi=0;mi<2;mi++)
      #pragma unroll
      for (int nj=0;nj<2;nj++)
        o2[mi][nj] = __builtin_amdgcn_mfma_f32_16x16x32_bf16(pa[mi], vb[nj], o2[mi][nj], 0,0,0);
  }

  #pragma unroll
  for (int mi=0;mi<2;mi++){
    #pragma unroll
    for (int nj=0;nj<2;nj++){
      #pragma unroll
      for (int r=0;r<4;r++){
        int ql = 16*mi + ((lane>>4)<<2) + r;
        int d  = (lane&15) + (nj<<4);
        out[(size_t)(win*128 + q0 + ql)*DIM + (h<<5) + d] = f2bf(o2[mi][nj][r] * invl[mi][r]);
      }
    }
  }
}

// ---------------- host launcher ----------------
extern "C" void kernel_launch(void* const* d_in, const int* in_sizes, int n_in,
                              void* d_out, int out_size, void* d_ws, size_t ws_size,
                              hipStream_t stream)
{
  const float* x_in   = (const float*)d_in[0];
  const float* ln1_g  = (const float*)d_in[1];
  const float* ln1_b  = (const float*)d_in[2];
  const float* qkv_w  = (const float*)d_in[3];
  const float* qkv_b  = (const float*)d_in[4];
  const float* btab   = (const float*)d_in[5];
  const float* proj_w = (const float*)d_in[6];
  const float* proj_b = (const float*)d_in[7];
  const float* ln2_g  = (const float*)d_in[8];
  const float* ln2_b  = (const float*)d_in[9];
  const float* fc1_w  = (const float*)d_in[10];
  const float* fc1_b  = (const float*)d_in[11];
  const float* fc2_w  = (const float*)d_in[12];
  const float* fc2_b  = (const float*)d_in[13];

  char* ws = (char*)d_ws;
  size_t off = 0;
  auto alloc = [&](size_t bytes)->char*{ char* p = ws + off; off += (bytes + 255) & ~(size_t)255; return p; };
  u16* wT_qkv = (u16*)alloc((size_t)2*512*1536*2);
  u16* wT_proj= (u16*)alloc((size_t)2*512*512*2);
  u16* wT_fc1 = (u16*)alloc((size_t)2*2048*512*2);
  u16* wT_fc2 = (u16*)alloc((size_t)2*512*2048*2);
  u16* bufA   = (u16*)alloc((size_t)16384*2048*2);
  u16* bufQ   = (u16*)alloc((size_t)16384*1536*2);
  u16* bufB   = (u16*)alloc((size_t)16384*512*2);
  u16* xbf    = (u16*)alloc((size_t)16384*512*2);
  u16* biasF  = (u16*)alloc((size_t)2*16*4*64*64*2);
  (void)ws_size; (void)in_sizes; (void)n_in; (void)out_size;

  float* xout = (float*)d_out;

  transpose_kernel<<<dim3(1536/32, 512/32, 2), 256, 0, stream>>>(qkv_w, wT_qkv, 512, 1536);
  transpose_kernel<<<dim3( 512/32, 512/32, 2), 256, 0, stream>>>(proj_w, wT_proj, 512, 512);
  transpose_kernel<<<dim3(2048/32, 512/32, 2), 256, 0, stream>>>(fc1_w, wT_fc1, 512, 2048);
  transpose_kernel<<<dim3( 512/32,2048/32, 2), 256, 0, stream>>>(fc2_w, wT_fc2, 2048, 512);
  biasf_kernel<<<128, 256, 0, stream>>>(btab, biasF);

  for (int i=0;i<2;i++){
    if (i==0)
      ln_f32cvt_kernel<<<4096, 256, 0, stream>>>(x_in, ln1_g, ln1_b, bufA, xbf);
    else
      ln_kernel<<<4096, 256, 0, stream>>>(xbf, ln1_g+512, ln1_b+512, bufA, 1);
    gemm32r_kernel<0><<<dim3(12,128), 256, 0, stream>>>(bufA, wT_qkv+(size_t)i*512*1536, qkv_b+i*1536, bufQ, nullptr, nullptr, NTOK,1536,512, 0);
    attn_kernel<<<2048, 256, 0, stream>>>(bufQ, biasF + (size_t)i*16*4*64*64, bufB, i);
    gemm32r_kernel<1><<<dim3(4,128), 256, 0, stream>>>(bufB, wT_proj+(size_t)i*512*512, proj_b+i*512, nullptr, xbf, nullptr, NTOK,512,512, i);
    ln_kernel<<<4096, 256, 0, stream>>>(xbf, ln2_g+i*512, ln2_b+i*512, bufB, -1);
    gemm32r_kernel<2><<<dim3(16,128), 256, 0, stream>>>(bufB, wT_fc1+(size_t)i*2048*512, fc1_b+i*2048, bufA, nullptr, nullptr, NTOK,2048,512, 0);
    if (i==0)
      gemm32r_kernel<3><<<dim3(4,128), 256, 0, stream>>>(bufA, wT_fc2+(size_t)i*512*2048, fc2_b+i*512, nullptr, xbf, nullptr, NTOK,512,2048, 0);
    else
      gemm32r_kernel<4><<<dim3(4,128), 256, 0, stream>>>(bufA, wT_fc2+(size_t)i*512*2048, fc2_b+i*512, nullptr, xbf, xout, NTOK,512,2048, 0);
  }
}

// Round 18
// 419.880 us; speedup vs baseline: 1.1723x; 1.0026x over previous
//
#include <hip/hip_runtime.h>
#include <stdint.h>

#define DIM 512
#define NHD 16
#define HD 32
#define NTOK 16384

typedef unsigned short u16;
typedef __attribute__((ext_vector_type(8))) short short8;  // 8 bf16 (4 VGPRs)
typedef __attribute__((ext_vector_type(4))) float f32x4;

__device__ __forceinline__ float bflo(unsigned u){ union{unsigned i; float f;} c; c.i=u<<16; return c.f; }
__device__ __forceinline__ float bfhi(unsigned u){ union{unsigned i; float f;} c; c.i=u&0xffff0000u; return c.f; }
__device__ __forceinline__ u16 f2bf(float f){ union{float f; unsigned i;} c; c.f=f; unsigned r=(c.i + 0x7fffu + ((c.i>>16)&1u))>>16; return (u16)r; }

__device__ __forceinline__ int win_to_tok(int r, int shifted){
  int win = r >> 7, n = r & 127;
  int a = win >> 6, b = (win >> 3) & 7, c = win & 7;
  int ic = n >> 6, ih = (n >> 3) & 7, iw = n & 7;
  int gc = a*2 + ic, gh = b*8 + ih, gw = c*8 + iw;
  if (shifted){ gc = (gc + 1) & 3; gh = (gh + 4) & 63; gw = (gw + 4) & 63; }
  return (gc << 12) + (gh << 6) + gw;
}

__device__ __forceinline__ void gload16(const void* g, void* l){
  __builtin_amdgcn_global_load_lds(
    (const __attribute__((address_space(1))) unsigned int*)(unsigned long long)g,
    (__attribute__((address_space(3))) unsigned int*)(unsigned int)(unsigned long long)l,
    16, 0, 0);
}

// ---------------- weight transpose + bf16 cast (batched over 2 model-blocks via z) ----------------
__global__ __launch_bounds__(256)
void transpose_kernel(const float* __restrict__ W, u16* __restrict__ Wt, int K, int N)
{
  __shared__ float t[32][33];
  size_t zoff = (size_t)blockIdx.z * K * N;
  int n0 = blockIdx.x*32, k0 = blockIdx.y*32;
  int tx = threadIdx.x & 31, ty = threadIdx.x >> 5;
  #pragma unroll
  for (int i=0;i<4;i++) t[ty + i*8][tx] = W[zoff + (size_t)(k0 + ty + i*8)*N + n0 + tx];
  __syncthreads();
  #pragma unroll
  for (int i=0;i<4;i++) Wt[zoff + (size_t)(n0 + ty + i*8)*K + k0 + tx] = f2bf(t[tx][ty + i*8]);
}

// ---------------- fused first-LN: reads f32 x, writes LN->bufA (window order) AND raw bf16 -> xbf ----------------
__global__ __launch_bounds__(256)
void ln_f32cvt_kernel(const float* __restrict__ x, const float* __restrict__ g,
                      const float* __restrict__ b, u16* __restrict__ out, u16* __restrict__ xbf)
{
  int wave = threadIdx.x >> 6, lane = threadIdx.x & 63;
  int r = blockIdx.x * 4 + wave;
  int src = win_to_tok(r, 0);
  const float4* xr = (const float4*)(x + (size_t)src * DIM);
  float4 v0 = xr[lane*2], v1 = xr[lane*2+1];
  float xv[8] = {v0.x,v0.y,v0.z,v0.w,v1.x,v1.y,v1.z,v1.w};
  union{u16 us[8]; uint4 u;} raw;
  #pragma unroll
  for (int j=0;j<8;j++) raw.us[j] = f2bf(xv[j]);
  ((uint4*)(xbf + (size_t)src*DIM))[lane] = raw.u;
  float s = 0.f, sq = 0.f;
  #pragma unroll
  for (int j=0;j<8;j++){ s += xv[j]; sq += xv[j]*xv[j]; }
  #pragma unroll
  for (int o=32;o;o>>=1){ s += __shfl_xor(s,o); sq += __shfl_xor(sq,o); }
  float mean = s*(1.f/DIM);
  float var  = sq*(1.f/DIM) - mean*mean;
  float rstd = rsqrtf(var + 1e-5f);
  int c0 = lane*8;
  const float4* g4 = (const float4*)(g + c0);
  const float4* b4 = (const float4*)(b + c0);
  float4 ga = g4[0], gb = g4[1], ba = b4[0], bb = b4[1];
  float gg[8] = {ga.x,ga.y,ga.z,ga.w,gb.x,gb.y,gb.z,gb.w};
  float bv[8] = {ba.x,ba.y,ba.z,ba.w,bb.x,bb.y,bb.z,bb.w};
  union{u16 us[8]; uint4 u;} p;
  #pragma unroll
  for (int j=0;j<8;j++) p.us[j] = f2bf((xv[j]-mean)*rstd*gg[j] + bv[j]);
  ((uint4*)(out + (size_t)r*DIM))[lane] = p.u;
}

// ---------------- LayerNorm on bf16 residual (+optional window gather w/ roll) -> bf16 ----------------
__global__ __launch_bounds__(256)
void ln_kernel(const u16* __restrict__ x, const float* __restrict__ g,
               const float* __restrict__ b, u16* __restrict__ out, int mode)
{
  int wave = threadIdx.x >> 6, lane = threadIdx.x & 63;
  int r = blockIdx.x * 4 + wave;
  int src = (mode < 0) ? r : win_to_tok(r, mode);
  uint4 u = ((const uint4*)(x + (size_t)src * DIM))[lane];
  unsigned w[4] = {u.x, u.y, u.z, u.w};
  float xv[8];
  #pragma unroll
  for (int j=0;j<4;j++){ xv[2*j] = bflo(w[j]); xv[2*j+1] = bfhi(w[j]); }
  float s = 0.f, sq = 0.f;
  #pragma unroll
  for (int j=0;j<8;j++){ s += xv[j]; sq += xv[j]*xv[j]; }
  #pragma unroll
  for (int o=32;o;o>>=1){ s += __shfl_xor(s,o); sq += __shfl_xor(sq,o); }
  float mean = s*(1.f/DIM);
  float var  = sq*(1.f/DIM) - mean*mean;
  float rstd = rsqrtf(var + 1e-5f);
  int c0 = lane*8;
  const float4* g4 = (const float4*)(g + c0);
  const float4* b4 = (const float4*)(b + c0);
  float4 ga = g4[0], gb = g4[1], ba = b4[0], bb = b4[1];
  float gg[8] = {ga.x,ga.y,ga.z,ga.w,gb.x,gb.y,gb.z,gb.w};
  float bv[8] = {ba.x,ba.y,ba.z,ba.w,bb.x,bb.y,bb.z,bb.w};
  union{u16 us[8]; uint4 u;} p;
  #pragma unroll
  for (int j=0;j<8;j++) p.us[j] = f2bf((xv[j]-mean)*rstd*gg[j] + bv[j]);
  ((uint4*)(out + (size_t)r*DIM))[lane] = p.u;
}

// ============ gemmW: 256x128 block, 4 waves x (128x64) wave-tile, BK=32, 3-slot 72KB ring ============
// Rationale: K-loop is LDS-read-BW bound; 64x64 wave-tiles cost 512 B/MFMA (2x read amplification),
// 128x64 wave-tiles cost 384 B/MFMA at the SAME 8 waves/CU occupancy (72KB -> 2 blocks/CU).
// All 12 fragments preloaded before the 32-MFMA burst (avoids R9's per-mi serial chain).
// EPI 0: store bf16 (qkv)   EPI 2: tanh-gelu -> bf16 (fc1)
template<int EPI>
__global__ __launch_bounds__(256, 2)
void gemmW_kernel(const u16* __restrict__ X, const u16* __restrict__ Wt,
                  const float* __restrict__ bias, u16* __restrict__ obf,
                  int M, int N, int K)
{
  __shared__ u16 smem[36864];   // 72KB: slot s @ s*12288 u16; A 4x[64][32] regions @ +q*2048, B 2x @ +8192+q*2048
  int tid = threadIdx.x, wave = tid>>6, lane = tid&63;
  int nwg = gridDim.x * gridDim.y;
  int bid = blockIdx.y * gridDim.x + blockIdx.x;
  int wg  = (bid & 7) * (nwg >> 3) + (bid >> 3);
  int n0 = (wg % gridDim.x) * 128;
  int m0 = (wg / gridDim.x) * 256;
  int wm = (wave>>1)*128, wn = (wave&1)*64;
  f32x4 acc[8][4] = {};

  // staging decode (per region [64][32], pair-row swizzle; chunk = tid within region)
  int u_ = (tid&7) ^ ((tid>>3)&7);
  int rloc = ((tid>>3)<<1) + (u_>>2);
  int cofs = (u_&3)*8;

  auto stage = [&](int s, int kb){
    u16* As_ = smem + s*12288;
    u16* Bs_ = As_ + 8192;
    #pragma unroll
    for (int q=0;q<4;q++)
      gload16(X + (size_t)(m0 + q*64 + rloc)*K + kb + cofs, (void*)(As_ + q*2048 + tid*8));
    #pragma unroll
    for (int q=0;q<2;q++)
      gload16(Wt + (size_t)(n0 + q*64 + rloc)*K + kb + cofs, (void*)(Bs_ + q*2048 + tid*8));
  };
  auto ldA = [&](int s, int mi)->short8{
    int row = wm + mi*16 + (lane&15);
    int r = row & 63;
    int slot = (((r&1)<<2) + (lane>>4)) ^ ((r>>1)&7);
    return *(const short8*)((const char*)(smem + s*12288 + (row>>6)*2048) + (r>>1)*128 + slot*16);
  };
  auto ldB = [&](int s, int nj)->short8{
    int row = wn + nj*16 + (lane&15);
    int r = row & 63;
    int slot = (((r&1)<<2) + (lane>>4)) ^ ((r>>1)&7);
    return *(const short8*)((const char*)(smem + s*12288 + 8192 + (row>>6)*2048) + (r>>1)*128 + slot*16);
  };

  int nt = K >> 5;
  stage(0, 0); stage(1, 32);
  asm volatile("s_waitcnt vmcnt(6)" ::: "memory");   // slot0's 6 resident; slot1's 6 in flight
  __builtin_amdgcn_sched_barrier(0);
  __builtin_amdgcn_s_barrier();
  __builtin_amdgcn_sched_barrier(0);

  int s = 0;
  for (int t=0; t<nt; ++t){
    int s2 = s+2; if (s2>=3) s2-=3;
    if (t+2 < nt) stage(s2, (t+2)<<5);
    short8 af[8], bfr[4];
    #pragma unroll
    for (int mi=0;mi<8;mi++) af[mi] = ldA(s, mi);
    #pragma unroll
    for (int nj=0;nj<4;nj++) bfr[nj] = ldB(s, nj);
    __builtin_amdgcn_s_setprio(1);
    #pragma unroll
    for (int mi=0;mi<8;mi++)
      #pragma unroll
      for (int nj=0;nj<4;nj++)
        acc[mi][nj] = __builtin_amdgcn_mfma_f32_16x16x32_bf16(af[mi], bfr[nj], acc[mi][nj], 0,0,0);
    __builtin_amdgcn_s_setprio(0);
    asm volatile("s_waitcnt lgkmcnt(0)" ::: "memory");
    __builtin_amdgcn_sched_barrier(0);
    if (t+1 < nt){
      if (t+2 < nt) asm volatile("s_waitcnt vmcnt(6)" ::: "memory");
      else          asm volatile("s_waitcnt vmcnt(0)" ::: "memory");
      __builtin_amdgcn_sched_barrier(0);
    }
    __builtin_amdgcn_s_barrier();
    __builtin_amdgcn_sched_barrier(0);
    s = (s==2) ? 0 : s+1;
  }

  // ---- epilogue: [256][128] bf16 repack (64KB, R12-proven swizzle) -> coalesced stores ----
  __syncthreads();
  int lr = (lane>>4)*4, lc = lane&15;
  u16* et = smem;                         // byte = row*256 + col*2, ^= ((row>>2)&3)<<5
  #pragma unroll
  for (int mi=0;mi<8;mi++){
    #pragma unroll
    for (int nj=0;nj<4;nj++){
      int col = wn + nj*16 + lc;
      float bv = bias[n0 + col];
      #pragma unroll
      for (int rr=0;rr<4;rr++){
        int row = wm + mi*16 + lr + rr;
        float v = acc[mi][nj][rr] + bv;
        if (EPI==2){
          float u2 = v*(1.5957691216057308f + 0.0713548162726f*v*v);
          v = v * __builtin_amdgcn_rcpf(1.f + __expf(-u2));   // tanh-GELU
        }
        *(u16*)((char*)et + ((row*256 + col*2) ^ (((row>>2)&3)<<5))) = f2bf(v);
      }
    }
  }
  __syncthreads();
  #pragma unroll
  for (int j=0;j<16;j++){
    int q = j*256 + tid;                  // 4096 16B-chunks
    int row = q>>4, cc = q&15;
    uint4 d = *(const uint4*)((char*)et + ((row*256 + cc*16) ^ (((row>>2)&3)<<5)));
    *(uint4*)(obf + (size_t)(m0+row)*N + n0 + cc*8) = d;
  }
}

// ============ gemm32r: 128x128 tile, BK=32, 3-slot LDS ring, counted vmcnt (R12-proven) ============
// EPI 1: scatter += into bf16 residual (proj)  EPI 3: += bf16 residual (fc2 b0)  EPI 4: final -> f32 d_out
template<int EPI>
__global__ __launch_bounds__(256)
void gemm32r_kernel(const u16* __restrict__ X, const u16* __restrict__ Wt,
                    const float* __restrict__ bias, u16* __restrict__ obf,
                    u16* __restrict__ xbf, float* __restrict__ outf,
                    int M, int N, int K, int shifted)
{
  __shared__ u16 smem[24576];
  int tid = threadIdx.x, wave = tid>>6, lane = tid&63;
  int nwg = gridDim.x * gridDim.y;
  int bid = blockIdx.y * gridDim.x + blockIdx.x;
  int wg  = (bid & 7) * (nwg >> 3) + (bid >> 3);
  int n0 = (wg % gridDim.x) * 128;
  int m0 = (wg / gridDim.x) * 128;
  int wm = (wave>>1)*64, wn = (wave&1)*64;
  f32x4 acc[4][4] = {};

  int r_[2], c_[2];
  #pragma unroll
  for (int q=0;q<2;q++){
    int line = q*32 + (tid>>3), slot = tid&7;
    int u = slot ^ (line&7);
    r_[q] = line*2 + (u>>2); c_[q] = u&3;
  }

  auto stage = [&](int s, int kb){
    u16* Ad = smem + s*4096;
    u16* Bd = smem + 12288 + s*4096;
    #pragma unroll
    for (int q=0;q<2;q++){
      gload16(X + (size_t)(m0 + r_[q])*K + kb + c_[q]*8, (void*)(Ad + q*2048 + tid*8));
      gload16(Wt + (size_t)(n0 + r_[q])*K + kb + c_[q]*8, (void*)(Bd + q*2048 + tid*8));
    }
  };
  auto ldfrag = [&](const u16* base, int row0)->short8 {
    int r = row0 + (lane&15);
    int slot = (((r&1)<<2) + (lane>>4)) ^ ((r>>1)&7);
    return *(const short8*)((const char*)base + (r>>1)*128 + slot*16);
  };

  int nt = K >> 5;
  stage(0, 0); stage(1, 32);
  asm volatile("s_waitcnt vmcnt(4)" ::: "memory");
  __builtin_amdgcn_sched_barrier(0);
  __builtin_amdgcn_s_barrier();
  __builtin_amdgcn_sched_barrier(0);

  int s = 0;
  for (int t=0; t<nt; ++t){
    int s2 = s+2; if (s2>=3) s2-=3;
    if (t+2 < nt) stage(s2, (t+2)<<5);
    const u16* Ab = smem + s*4096;
    const u16* Bb = smem + 12288 + s*4096;
    short8 af[4], bfr[4];
    #pragma unroll
    for (int mi=0;mi<4;mi++) af[mi]  = ldfrag(Ab, wm + mi*16);
    #pragma unroll
    for (int nj=0;nj<4;nj++) bfr[nj] = ldfrag(Bb, wn + nj*16);
    __builtin_amdgcn_s_setprio(1);
    #pragma unroll
    for (int mi=0;mi<4;mi++)
      #pragma unroll
      for (int nj=0;nj<4;nj++)
        acc[mi][nj] = __builtin_amdgcn_mfma_f32_16x16x32_bf16(af[mi], bfr[nj], acc[mi][nj], 0,0,0);
    __builtin_amdgcn_s_setprio(0);
    asm volatile("s_waitcnt lgkmcnt(0)" ::: "memory");
    __builtin_amdgcn_sched_barrier(0);
    if (t+1 < nt){
      if (t+2 < nt) asm volatile("s_waitcnt vmcnt(4)" ::: "memory");
      else          asm volatile("s_waitcnt vmcnt(0)" ::: "memory");
      __builtin_amdgcn_sched_barrier(0);
    }
    __builtin_amdgcn_s_barrier();
    __builtin_amdgcn_sched_barrier(0);
    s = (s==2) ? 0 : s+1;
  }

  int lr = (lane>>4)*4, lc = lane&15;
  {
    float* et = (float*)smem;               // two passes of [64][128] f32 = 32KB
    #pragma unroll
    for (int half=0; half<2; ++half){
      __syncthreads();
      if ((wm>>6) == half){
        #pragma unroll
        for (int mi=0;mi<4;mi++){
          #pragma unroll
          for (int nj=0;nj<4;nj++){
            int col = wn + nj*16 + lc;
            float bv = bias[n0 + col];
            #pragma unroll
            for (int rr=0;rr<4;rr++){
              int row = (wm & 63) + mi*16 + lr + rr;
              *(float*)((char*)et + ((row*512 + col*4) ^ (((row>>2)&1)<<6))) = acc[mi][nj][rr] + bv;
            }
          }
        }
      }
      __syncthreads();
      #pragma unroll
      for (int j=0;j<4;j++){
        int q = j*256 + tid;
        int row = q>>4, c8 = q&15;
        int swz = ((row>>2)&1)<<6;
        float4 d0 = *(const float4*)((char*)et + ((row*512 + c8*32     ) ^ swz));
        float4 d1 = *(const float4*)((char*)et + ((row*512 + c8*32 + 16) ^ swz));
        int lrow = m0 + half*64 + row;
        int grow = (EPI==1) ? win_to_tok(lrow, shifted) : lrow;
        size_t gofs = (size_t)grow*DIM + n0 + c8*8;
        uint4 xv = *(const uint4*)(xbf + gofs);
        unsigned xw[4] = {xv.x, xv.y, xv.z, xv.w};
        float xs[8];
        #pragma unroll
        for (int k2=0;k2<4;k2++){ xs[2*k2] = bflo(xw[k2]); xs[2*k2+1] = bfhi(xw[k2]); }
        float ds[8] = {d0.x,d0.y,d0.z,d0.w,d1.x,d1.y,d1.z,d1.w};
        if (EPI==4){
          float4 o0 = {xs[0]+ds[0], xs[1]+ds[1], xs[2]+ds[2], xs[3]+ds[3]};
          float4 o1 = {xs[4]+ds[4], xs[5]+ds[5], xs[6]+ds[6], xs[7]+ds[7]};
          float4* op = (float4*)(outf + gofs);
          op[0] = o0; op[1] = o1;
        } else {
          union{u16 us[8]; uint4 u;} nw;
          #pragma unroll
          for (int k2=0;k2<8;k2++) nw.us[k2] = f2bf(xs[k2] + ds[k2]);
          *(uint4*)(xbf + gofs) = nw.u;
        }
      }
    }
  }
}

// ---------------- rel-pos bias in bf16, MFMA C-fragment order ----------------
__global__ __launch_bounds__(256)
void biasf_kernel(const float* __restrict__ btab, u16* __restrict__ biasF)
{
  int gid = blockIdx.x*256 + threadIdx.x;   // 2*16*4*64*8 = 32768 entries of 8 bf16
  int j = gid & 7;
  int lane = (gid>>3) & 63;
  int wave = (gid>>9) & 3;
  int h = (gid>>11) & 15;
  int i = gid>>15;
  int mi = j>>2, r = j&3;
  int qw = wave*32 + mi*16 + ((lane>>4)<<2) + r;
  int ic=qw>>6, ih=(qw>>3)&7, iw=qw&7;
  const float* bt = btab + (size_t)i*675*16 + h;
  union{u16 us[8]; uint4 u[2];} o;
  #pragma unroll
  for (int nj=0;nj<8;nj++){
    int k = (lane&15) + nj*16;
    int jc=k>>6, jh=(k>>3)&7, jw=k&7;
    int idx = (ic-jc+1)*225 + (ih-jh+7)*15 + (iw-jw+7);
    o.us[nj] = f2bf(bt[idx*16]);
  }
  *(uint4*)(biasF + (size_t)gid*8) = o.u[0];
  *(uint4*)(biasF + (size_t)gid*8 + 4) = o.u[1];
}

// ---------------- MFMA windowed attention (bias via bf16 fragment-order loads) ----------------
__global__ __launch_bounds__(256)
void attn_kernel(const u16* __restrict__ qkv, const u16* __restrict__ biasF,
                 u16* __restrict__ out, int shifted)
{
  __shared__ u16 Ks[128*32];
  __shared__ u16 VsT[32*128];
  __shared__ u16 Ps[4][32*128];
  __shared__ int rid[128];
  int win = blockIdx.x >> 4, h = blockIdx.x & 15;
  int tid = threadIdx.x, wave = tid>>6, lane = tid&63;
  size_t base = (size_t)win*128*1536 + (size_t)h*32;

  {
    int m = tid>>1, half = tid&1;
    const uint4* ks = (const uint4*)(qkv + base + (size_t)m*1536 + 512 + half*16);
    uint4 k0v = ks[0], k1v = ks[1];
    char* krow = (char*)Ks + m*64;
    int c0 = half*32, sw = (m&3)<<4;
    *(uint4*)(krow + ((c0     ) ^ sw)) = k0v;
    *(uint4*)(krow + ((c0 + 16) ^ sw)) = k1v;
    const uint4* vs = (const uint4*)(qkv + base + (size_t)m*1536 + 1024 + half*16);
    union{u16 us[16]; uint4 u[2];} vv; vv.u[0]=vs[0]; vv.u[1]=vs[1];
    #pragma unroll
    for (int j=0;j<16;j++){
      int d = half*16 + j;
      *(u16*)((char*)VsT + ((d*256 + m*2) ^ ((d&7)<<4))) = vv.us[j];
    }
  }
  if (shifted && tid < 128){
    int a=win>>6, b=(win>>3)&7, c=win&7;
    int gc=a*2+(tid>>6), gh=b*8+((tid>>3)&7), gw=c*8+(tid&7);
    int rc = (gc<2)?0:((gc<3)?1:2);
    int rh = (gh<56)?0:((gh<60)?1:2);
    int rw = (gw<56)?0:((gw<60)?1:2);
    rid[tid] = rc*9 + rh*3 + rw;
  }
  __syncthreads();

  int q0 = wave*32;
  short8 qf[2];
  #pragma unroll
  for (int mi=0;mi<2;mi++){
    int ql = 16*mi + (lane&15);
    qf[mi] = *(const short8*)(qkv + base + (size_t)(q0+ql)*1536 + (lane>>4)*8);
  }
  f32x4 s[2][8] = {};
  #pragma unroll
  for (int nj=0;nj<8;nj++){
    int row = (lane&15) + 16*nj;
    short8 kf = *(const short8*)((char*)Ks + row*64 + ((((lane>>4)<<4)) ^ ((row&3)<<4)));
    #pragma unroll
    for (int mi=0;mi<2;mi++)
      s[mi][nj] = __builtin_amdgcn_mfma_f32_16x16x32_bf16(qf[mi], kf, s[mi][nj], 0,0,0);
  }

  int rk[8];
  if (shifted){
    #pragma unroll
    for (int nj=0;nj<8;nj++) rk[nj] = rid[(lane&15) + 16*nj];
  }
  const u16* bb = biasF + ((((size_t)h*4 + wave)*64 + lane)*64);
  float invl[2][4];
  char* pbase = (char*)Ps[wave];
  #pragma unroll
  for (int mi=0;mi<2;mi++){
    #pragma unroll
    for (int r=0;r<4;r++){
      int ql = 16*mi + ((lane>>4)<<2) + r;
      int qw = q0 + ql;
      uint4 bu = *(const uint4*)(bb + (mi*4+r)*8);
      unsigned ba[4] = {bu.x, bu.y, bu.z, bu.w};
      int rq = shifted ? rid[qw] : 0;
      float sv[8]; float mx = -1e30f;
      #pragma unroll
      for (int nj=0;nj<8;nj++){
        float bval = (nj&1) ? bfhi(ba[nj>>1]) : bflo(ba[nj>>1]);
        float v = fmaf(s[mi][nj][r], 0.17677669529663687f, bval);
        if (shifted && rk[nj] != rq) v -= 100.f;
        sv[nj] = v; mx = fmaxf(mx, v);
      }
      #pragma unroll
      for (int o=1;o<16;o<<=1) mx = fmaxf(mx, __shfl_xor(mx, o));
      float sum = 0.f;
      #pragma unroll
      for (int nj=0;nj<8;nj++){ float p = __expf(sv[nj]-mx); sv[nj]=p; sum += p; }
      #pragma unroll
      for (int o=1;o<16;o<<=1) sum += __shfl_xor(sum, o);
      invl[mi][r] = 1.f/sum;
      char* prow = pbase + ql*256;
      int sw = (ql&7)<<4;
      #pragma unroll
      for (int nj=0;nj<8;nj++)
        *(u16*)(prow + ((((lane&15) + (nj<<4))<<1) ^ sw)) = f2bf(sv[nj]);
    }
  }

  f32x4 o2[2][2] = {};
  #pragma unroll
  for (int kk=0;kk<4;kk++){
    int coff = kk*64 + ((lane>>4)<<4);
    short8 pa[2], vb[2];
    #pragma unroll
    for (int mi=0;mi<2;mi++){
      int ql = 16*mi + (lane&15);
      pa[mi] = *(const short8*)(pbase + ql*256 + (coff ^ ((ql&7)<<4)));
    }
    #pragma unroll
    for (int nj=0;nj<2;nj++){
      int d = (lane&15) + 16*nj;
      vb[nj] = *(const short8*)((char*)VsT + d*256 + (coff ^ ((d&7)<<4)));
    }
    #pragma unroll
    for (int mi=0;mi<2;mi++)
      #pragma unroll
      for (int nj=0;nj<2;nj++)
        o2[mi][nj] = __builtin_amdgcn_mfma_f32_16x16x32_bf16(pa[mi], vb[nj], o2[mi][nj], 0,0,0);
  }

  #pragma unroll
  for (int mi=0;mi<2;mi++){
    #pragma unroll
    for (int nj=0;nj<2;nj++){
      #pragma unroll
      for (int r=0;r<4;r++){
        int ql = 16*mi + ((lane>>4)<<2) + r;
        int d  = (lane&15) + (nj<<4);
        out[(size_t)(win*128 + q0 + ql)*DIM + (h<<5) + d] = f2bf(o2[mi][nj][r] * invl[mi][r]);
      }
    }
  }
}

// ---------------- host launcher ----------------
extern "C" void kernel_launch(void* const* d_in, const int* in_sizes, int n_in,
                              void* d_out, int out_size, void* d_ws, size_t ws_size,
                              hipStream_t stream)
{
  const float* x_in   = (const float*)d_in[0];
  const float* ln1_g  = (const float*)d_in[1];
  const float* ln1_b  = (const float*)d_in[2];
  const float* qkv_w  = (const float*)d_in[3];
  const float* qkv_b  = (const float*)d_in[4];
  const float* btab   = (const float*)d_in[5];
  const float* proj_w = (const float*)d_in[6];
  const float* proj_b = (const float*)d_in[7];
  const float* ln2_g  = (const float*)d_in[8];
  const float* ln2_b  = (const float*)d_in[9];
  const float* fc1_w  = (const float*)d_in[10];
  const float* fc1_b  = (const float*)d_in[11];
  const float* fc2_w  = (const float*)d_in[12];
  const float* fc2_b  = (const float*)d_in[13];

  char* ws = (char*)d_ws;
  size_t off = 0;
  auto alloc = [&](size_t bytes)->char*{ char* p = ws + off; off += (bytes + 255) & ~(size_t)255; return p; };
  u16* wT_qkv = (u16*)alloc((size_t)2*512*1536*2);
  u16* wT_proj= (u16*)alloc((size_t)2*512*512*2);
  u16* wT_fc1 = (u16*)alloc((size_t)2*2048*512*2);
  u16* wT_fc2 = (u16*)alloc((size_t)2*512*2048*2);
  u16* bufA   = (u16*)alloc((size_t)16384*2048*2);
  u16* bufQ   = (u16*)alloc((size_t)16384*1536*2);
  u16* bufB   = (u16*)alloc((size_t)16384*512*2);
  u16* xbf    = (u16*)alloc((size_t)16384*512*2);
  u16* biasF  = (u16*)alloc((size_t)2*16*4*64*64*2);
  (void)ws_size; (void)in_sizes; (void)n_in; (void)out_size;

  float* xout = (float*)d_out;

  transpose_kernel<<<dim3(1536/32, 512/32, 2), 256, 0, stream>>>(qkv_w, wT_qkv, 512, 1536);
  transpose_kernel<<<dim3( 512/32, 512/32, 2), 256, 0, stream>>>(proj_w, wT_proj, 512, 512);
  transpose_kernel<<<dim3(2048/32, 512/32, 2), 256, 0, stream>>>(fc1_w, wT_fc1, 512, 2048);
  transpose_kernel<<<dim3( 512/32,2048/32, 2), 256, 0, stream>>>(fc2_w, wT_fc2, 2048, 512);
  biasf_kernel<<<128, 256, 0, stream>>>(btab, biasF);

  for (int i=0;i<2;i++){
    if (i==0)
      ln_f32cvt_kernel<<<4096, 256, 0, stream>>>(x_in, ln1_g, ln1_b, bufA, xbf);
    else
      ln_kernel<<<4096, 256, 0, stream>>>(xbf, ln1_g+512, ln1_b+512, bufA, 1);
    gemmW_kernel<0><<<dim3(12,64), 256, 0, stream>>>(bufA, wT_qkv+(size_t)i*512*1536, qkv_b+i*1536, bufQ, NTOK,1536,512);
    attn_kernel<<<2048, 256, 0, stream>>>(bufQ, biasF + (size_t)i*16*4*64*64, bufB, i);
    gemm32r_kernel<1><<<dim3(4,128), 256, 0, stream>>>(bufB, wT_proj+(size_t)i*512*512, proj_b+i*512, nullptr, xbf, nullptr, NTOK,512,512, i);
    ln_kernel<<<4096, 256, 0, stream>>>(xbf, ln2_g+i*512, ln2_b+i*512, bufB, -1);
    gemmW_kernel<2><<<dim3(16,64), 256, 0, stream>>>(bufB, wT_fc1+(size_t)i*2048*512, fc1_b+i*2048, bufA, NTOK,2048,512);
    if (i==0)
      gemm32r_kernel<3><<<dim3(4,128), 256, 0, stream>>>(bufA, wT_fc2+(size_t)i*512*2048, fc2_b+i*512, nullptr, xbf, nullptr, NTOK,512,2048, 0);
    else
      gemm32r_kernel<4><<<dim3(4,128), 256, 0, stream>>>(bufA, wT_fc2+(size_t)i*512*2048, fc2_b+i*512, nullptr, xbf, xout, NTOK,512,2048, 0);
  }
}

// Round 19
// 418.248 us; speedup vs baseline: 1.1768x; 1.0039x over previous
//
#include <hip/hip_runtime.h>
#include <stdint.h>

#define DIM 512
#define NHD 16
#define HD 32
#define NTOK 16384

typedef unsigned short u16;
typedef __attribute__((ext_vector_type(8))) short short8;  // 8 bf16 (4 VGPRs)
typedef __attribute__((ext_vector_type(4))) float f32x4;

__device__ __forceinline__ float bflo(unsigned u){ union{unsigned i; float f;} c; c.i=u<<16; return c.f; }
__device__ __forceinline__ float bfhi(unsigned u){ union{unsigned i; float f;} c; c.i=u&0xffff0000u; return c.f; }
__device__ __forceinline__ u16 f2bf(float f){ union{float f; unsigned i;} c; c.f=f; unsigned r=(c.i + 0x7fffu + ((c.i>>16)&1u))>>16; return (u16)r; }

__device__ __forceinline__ int win_to_tok(int r, int shifted){
  int win = r >> 7, n = r & 127;
  int a = win >> 6, b = (win >> 3) & 7, c = win & 7;
  int ic = n >> 6, ih = (n >> 3) & 7, iw = n & 7;
  int gc = a*2 + ic, gh = b*8 + ih, gw = c*8 + iw;
  if (shifted){ gc = (gc + 1) & 3; gh = (gh + 4) & 63; gw = (gw + 4) & 63; }
  return (gc << 12) + (gh << 6) + gw;
}

// region id for the shift mask, computed arithmetically (no LDS)
__device__ __forceinline__ int region_id(int win, int m){
  int gc = ((win>>6)<<1) + (m>>6);
  int gh = (((win>>3)&7)<<3) + ((m>>3)&7);
  int gw = ((win&7)<<3) + (m&7);
  int rc = (gc<2)?0:((gc<3)?1:2);
  int rh = (gh<56)?0:((gh<60)?1:2);
  int rw = (gw<56)?0:((gw<60)?1:2);
  return rc*9 + rh*3 + rw;
}

__device__ __forceinline__ void gload16(const void* g, void* l){
  __builtin_amdgcn_global_load_lds(
    (const __attribute__((address_space(1))) unsigned int*)(unsigned long long)g,
    (__attribute__((address_space(3))) unsigned int*)(unsigned int)(unsigned long long)l,
    16, 0, 0);
}

// ---------------- weight transpose + bf16 cast (batched over 2 model-blocks via z) ----------------
__global__ __launch_bounds__(256)
void transpose_kernel(const float* __restrict__ W, u16* __restrict__ Wt, int K, int N)
{
  __shared__ float t[32][33];
  size_t zoff = (size_t)blockIdx.z * K * N;
  int n0 = blockIdx.x*32, k0 = blockIdx.y*32;
  int tx = threadIdx.x & 31, ty = threadIdx.x >> 5;
  #pragma unroll
  for (int i=0;i<4;i++) t[ty + i*8][tx] = W[zoff + (size_t)(k0 + ty + i*8)*N + n0 + tx];
  __syncthreads();
  #pragma unroll
  for (int i=0;i<4;i++) Wt[zoff + (size_t)(n0 + ty + i*8)*K + k0 + tx] = f2bf(t[tx][ty + i*8]);
}

// ---------------- fused first-LN: reads f32 x, writes LN->bufA (window order) AND raw bf16 -> xbf ----------------
__global__ __launch_bounds__(256)
void ln_f32cvt_kernel(const float* __restrict__ x, const float* __restrict__ g,
                      const float* __restrict__ b, u16* __restrict__ out, u16* __restrict__ xbf)
{
  int wave = threadIdx.x >> 6, lane = threadIdx.x & 63;
  int r = blockIdx.x * 4 + wave;
  int src = win_to_tok(r, 0);
  const float4* xr = (const float4*)(x + (size_t)src * DIM);
  float4 v0 = xr[lane*2], v1 = xr[lane*2+1];
  float xv[8] = {v0.x,v0.y,v0.z,v0.w,v1.x,v1.y,v1.z,v1.w};
  union{u16 us[8]; uint4 u;} raw;
  #pragma unroll
  for (int j=0;j<8;j++) raw.us[j] = f2bf(xv[j]);
  ((uint4*)(xbf + (size_t)src*DIM))[lane] = raw.u;
  float s = 0.f, sq = 0.f;
  #pragma unroll
  for (int j=0;j<8;j++){ s += xv[j]; sq += xv[j]*xv[j]; }
  #pragma unroll
  for (int o=32;o;o>>=1){ s += __shfl_xor(s,o); sq += __shfl_xor(sq,o); }
  float mean = s*(1.f/DIM);
  float var  = sq*(1.f/DIM) - mean*mean;
  float rstd = rsqrtf(var + 1e-5f);
  int c0 = lane*8;
  const float4* g4 = (const float4*)(g + c0);
  const float4* b4 = (const float4*)(b + c0);
  float4 ga = g4[0], gb = g4[1], ba = b4[0], bb = b4[1];
  float gg[8] = {ga.x,ga.y,ga.z,ga.w,gb.x,gb.y,gb.z,gb.w};
  float bv[8] = {ba.x,ba.y,ba.z,ba.w,bb.x,bb.y,bb.z,bb.w};
  union{u16 us[8]; uint4 u;} p;
  #pragma unroll
  for (int j=0;j<8;j++) p.us[j] = f2bf((xv[j]-mean)*rstd*gg[j] + bv[j]);
  ((uint4*)(out + (size_t)r*DIM))[lane] = p.u;
}

// ---------------- LayerNorm on bf16 residual (+optional window gather w/ roll) -> bf16 ----------------
__global__ __launch_bounds__(256)
void ln_kernel(const u16* __restrict__ x, const float* __restrict__ g,
               const float* __restrict__ b, u16* __restrict__ out, int mode)
{
  int wave = threadIdx.x >> 6, lane = threadIdx.x & 63;
  int r = blockIdx.x * 4 + wave;
  int src = (mode < 0) ? r : win_to_tok(r, mode);
  uint4 u = ((const uint4*)(x + (size_t)src * DIM))[lane];
  unsigned w[4] = {u.x, u.y, u.z, u.w};
  float xv[8];
  #pragma unroll
  for (int j=0;j<4;j++){ xv[2*j] = bflo(w[j]); xv[2*j+1] = bfhi(w[j]); }
  float s = 0.f, sq = 0.f;
  #pragma unroll
  for (int j=0;j<8;j++){ s += xv[j]; sq += xv[j]*xv[j]; }
  #pragma unroll
  for (int o=32;o;o>>=1){ s += __shfl_xor(s,o); sq += __shfl_xor(sq,o); }
  float mean = s*(1.f/DIM);
  float var  = sq*(1.f/DIM) - mean*mean;
  float rstd = rsqrtf(var + 1e-5f);
  int c0 = lane*8;
  const float4* g4 = (const float4*)(g + c0);
  const float4* b4 = (const float4*)(b + c0);
  float4 ga = g4[0], gb = g4[1], ba = b4[0], bb = b4[1];
  float gg[8] = {ga.x,ga.y,ga.z,ga.w,gb.x,gb.y,gb.z,gb.w};
  float bv[8] = {ba.x,ba.y,ba.z,ba.w,bb.x,bb.y,bb.z,bb.w};
  union{u16 us[8]; uint4 u;} p;
  #pragma unroll
  for (int j=0;j<8;j++) p.us[j] = f2bf((xv[j]-mean)*rstd*gg[j] + bv[j]);
  ((uint4*)(out + (size_t)r*DIM))[lane] = p.u;
}

// ============ gemm32r: 128x128 tile, BK=32, 3-slot LDS ring, counted vmcnt (R12-proven) ============
// EPI 0: store bf16 (qkv)        EPI 1: scatter += into bf16 residual (proj, win_rev+roll)
// EPI 2: tanh-gelu -> bf16 (fc1) EPI 3: += bf16 residual (fc2 block0)
// EPI 4: final fc2: read bf16 residual, add, write f32 d_out
template<int EPI>
__global__ __launch_bounds__(256)
void gemm32r_kernel(const u16* __restrict__ X, const u16* __restrict__ Wt,
                    const float* __restrict__ bias, u16* __restrict__ obf,
                    u16* __restrict__ xbf, float* __restrict__ outf,
                    int M, int N, int K, int shifted)
{
  __shared__ u16 smem[24576];    // 48KB: A slot s @ s*4096, B slot s @ 12288+s*4096 (elems)
  int tid = threadIdx.x, wave = tid>>6, lane = tid&63;
  int nwg = gridDim.x * gridDim.y;
  int bid = blockIdx.y * gridDim.x + blockIdx.x;
  int wg  = (bid & 7) * (nwg >> 3) + (bid >> 3);
  int n0 = (wg % gridDim.x) * 128;
  int m0 = (wg / gridDim.x) * 128;
  int wm = (wave>>1)*64, wn = (wave&1)*64;
  f32x4 acc[4][4] = {};

  int r_[2], c_[2];
  #pragma unroll
  for (int q=0;q<2;q++){
    int line = q*32 + (tid>>3), slot = tid&7;
    int u = slot ^ (line&7);
    r_[q] = line*2 + (u>>2); c_[q] = u&3;
  }

  auto stage = [&](int s, int kb){
    u16* Ad = smem + s*4096;
    u16* Bd = smem + 12288 + s*4096;
    #pragma unroll
    for (int q=0;q<2;q++){
      gload16(X + (size_t)(m0 + r_[q])*K + kb + c_[q]*8, (void*)(Ad + q*2048 + tid*8));
      gload16(Wt + (size_t)(n0 + r_[q])*K + kb + c_[q]*8, (void*)(Bd + q*2048 + tid*8));
    }
  };
  auto ldfrag = [&](const u16* base, int row0)->short8 {
    int r = row0 + (lane&15);
    int slot = (((r&1)<<2) + (lane>>4)) ^ ((r>>1)&7);
    return *(const short8*)((const char*)base + (r>>1)*128 + slot*16);
  };

  int nt = K >> 5;
  stage(0, 0); stage(1, 32);
  asm volatile("s_waitcnt vmcnt(4)" ::: "memory");
  __builtin_amdgcn_sched_barrier(0);
  __builtin_amdgcn_s_barrier();
  __builtin_amdgcn_sched_barrier(0);

  int s = 0;
  for (int t=0; t<nt; ++t){
    int s2 = s+2; if (s2>=3) s2-=3;
    if (t+2 < nt) stage(s2, (t+2)<<5);
    const u16* Ab = smem + s*4096;
    const u16* Bb = smem + 12288 + s*4096;
    short8 af[4], bfr[4];
    #pragma unroll
    for (int mi=0;mi<4;mi++) af[mi]  = ldfrag(Ab, wm + mi*16);
    #pragma unroll
    for (int nj=0;nj<4;nj++) bfr[nj] = ldfrag(Bb, wn + nj*16);
    __builtin_amdgcn_s_setprio(1);
    #pragma unroll
    for (int mi=0;mi<4;mi++)
      #pragma unroll
      for (int nj=0;nj<4;nj++)
        acc[mi][nj] = __builtin_amdgcn_mfma_f32_16x16x32_bf16(af[mi], bfr[nj], acc[mi][nj], 0,0,0);
    __builtin_amdgcn_s_setprio(0);
    asm volatile("s_waitcnt lgkmcnt(0)" ::: "memory");
    __builtin_amdgcn_sched_barrier(0);
    if (t+1 < nt){
      if (t+2 < nt) asm volatile("s_waitcnt vmcnt(4)" ::: "memory");
      else          asm volatile("s_waitcnt vmcnt(0)" ::: "memory");
      __builtin_amdgcn_sched_barrier(0);
    }
    __builtin_amdgcn_s_barrier();
    __builtin_amdgcn_sched_barrier(0);
    s = (s==2) ? 0 : s+1;
  }

  // ---- epilogue (R12-proven) ----
  int lr = (lane>>4)*4, lc = lane&15;
  if (EPI==0 || EPI==2){
    u16* et = smem;                         // [128][128] bf16 = 32KB, byte ^= ((row>>2)&3)<<5
    #pragma unroll
    for (int mi=0;mi<4;mi++){
      #pragma unroll
      for (int nj=0;nj<4;nj++){
        int col = wn + nj*16 + lc;
        float bv = bias[n0 + col];
        #pragma unroll
        for (int rr=0;rr<4;rr++){
          int row = wm + mi*16 + lr + rr;
          float v = acc[mi][nj][rr] + bv;
          if (EPI==2){
            float u2 = v*(1.5957691216057308f + 0.0713548162726f*v*v);
            v = v * __builtin_amdgcn_rcpf(1.f + __expf(-u2));   // tanh-GELU
          }
          *(u16*)((char*)et + ((row*256 + col*2) ^ (((row>>2)&3)<<5))) = f2bf(v);
        }
      }
    }
    __syncthreads();
    #pragma unroll
    for (int j=0;j<8;j++){
      int q = j*256 + tid;
      int row = q>>4, cc = q&15;
      uint4 d = *(const uint4*)((char*)et + ((row*256 + cc*16) ^ (((row>>2)&3)<<5)));
      *(uint4*)(obf + (size_t)(m0+row)*N + n0 + cc*8) = d;
    }
  } else {
    // EPI 1/3/4: f32 repack in two 64-row halves, then bf16-residual RMW (or f32 final store)
    float* et = (float*)smem;               // [64][128] f32 = 32KB, byte ^= ((row>>2)&1)<<6
    #pragma unroll
    for (int half=0; half<2; ++half){
      __syncthreads();
      if ((wm>>6) == half){
        #pragma unroll
        for (int mi=0;mi<4;mi++){
          #pragma unroll
          for (int nj=0;nj<4;nj++){
            int col = wn + nj*16 + lc;
            float bv = bias[n0 + col];
            #pragma unroll
            for (int rr=0;rr<4;rr++){
              int row = (wm & 63) + mi*16 + lr + rr;
              *(float*)((char*)et + ((row*512 + col*4) ^ (((row>>2)&1)<<6))) = acc[mi][nj][rr] + bv;
            }
          }
        }
      }
      __syncthreads();
      #pragma unroll
      for (int j=0;j<4;j++){
        int q = j*256 + tid;                // 1024 chunks of 8 cols
        int row = q>>4, c8 = q&15;
        int swz = ((row>>2)&1)<<6;
        float4 d0 = *(const float4*)((char*)et + ((row*512 + c8*32     ) ^ swz));
        float4 d1 = *(const float4*)((char*)et + ((row*512 + c8*32 + 16) ^ swz));
        int lrow = m0 + half*64 + row;
        int grow = (EPI==1) ? win_to_tok(lrow, shifted) : lrow;
        size_t gofs = (size_t)grow*DIM + n0 + c8*8;
        uint4 xv = *(const uint4*)(xbf + gofs);
        unsigned xw[4] = {xv.x, xv.y, xv.z, xv.w};
        float xs[8];
        #pragma unroll
        for (int k2=0;k2<4;k2++){ xs[2*k2] = bflo(xw[k2]); xs[2*k2+1] = bfhi(xw[k2]); }
        float ds[8] = {d0.x,d0.y,d0.z,d0.w,d1.x,d1.y,d1.z,d1.w};
        if (EPI==4){
          float4 o0 = {xs[0]+ds[0], xs[1]+ds[1], xs[2]+ds[2], xs[3]+ds[3]};
          float4 o1 = {xs[4]+ds[4], xs[5]+ds[5], xs[6]+ds[6], xs[7]+ds[7]};
          float4* op = (float4*)(outf + gofs);
          op[0] = o0; op[1] = o1;
        } else {
          union{u16 us[8]; uint4 u;} nw;
          #pragma unroll
          for (int k2=0;k2<8;k2++) nw.us[k2] = f2bf(xs[k2] + ds[k2]);
          *(uint4*)(xbf + gofs) = nw.u;
        }
      }
    }
  }
}

// ---------------- rel-pos bias in bf16, MFMA C-fragment order ----------------
__global__ __launch_bounds__(256)
void biasf_kernel(const float* __restrict__ btab, u16* __restrict__ biasF)
{
  int gid = blockIdx.x*256 + threadIdx.x;   // 2*16*4*64*8 = 32768 entries of 8 bf16
  int j = gid & 7;
  int lane = (gid>>3) & 63;
  int wave = (gid>>9) & 3;
  int h = (gid>>11) & 15;
  int i = gid>>15;
  int mi = j>>2, r = j&3;
  int qw = wave*32 + mi*16 + ((lane>>4)<<2) + r;
  int ic=qw>>6, ih=(qw>>3)&7, iw=qw&7;
  const float* bt = btab + (size_t)i*675*16 + h;
  union{u16 us[8]; uint4 u[2];} o;
  #pragma unroll
  for (int nj=0;nj<8;nj++){
    int k = (lane&15) + nj*16;
    int jc=k>>6, jh=(k>>3)&7, jw=k&7;
    int idx = (ic-jc+1)*225 + (ih-jh+7)*15 + (iw-jw+7);
    o.us[nj] = f2bf(bt[idx*16]);
  }
  *(uint4*)(biasF + (size_t)gid*8) = o.u[0];
  *(uint4*)(biasF + (size_t)gid*8 + 4) = o.u[1];
}

// ---------------- MFMA windowed attention (40KB LDS -> 4 blocks/CU) ----------------
// LDS map: VsT @ 0 (8KB), Ks @ 4096 u16 (8KB, dead after QK^T), P: wave0 -> Ks region,
//          waves 1..3 @ 8192+(wave-1)*4096 u16. Barrier between QK^T and P-writes.
__global__ __launch_bounds__(256)
void attn_kernel(const u16* __restrict__ qkv, const u16* __restrict__ biasF,
                 u16* __restrict__ out, int shifted)
{
  __shared__ u16 sm[20480];   // 40960 B exactly
  u16* VsT = sm;
  u16* Ks  = sm + 4096;
  int win = blockIdx.x >> 4, h = blockIdx.x & 15;
  int tid = threadIdx.x, wave = tid>>6, lane = tid&63;
  size_t base = (size_t)win*128*1536 + (size_t)h*32;

  {
    int m = tid>>1, half = tid&1;
    const uint4* ks = (const uint4*)(qkv + base + (size_t)m*1536 + 512 + half*16);
    uint4 k0v = ks[0], k1v = ks[1];
    char* krow = (char*)Ks + m*64;
    int c0 = half*32, sw = (m&3)<<4;
    *(uint4*)(krow + ((c0     ) ^ sw)) = k0v;
    *(uint4*)(krow + ((c0 + 16) ^ sw)) = k1v;
    const uint4* vs = (const uint4*)(qkv + base + (size_t)m*1536 + 1024 + half*16);
    union{u16 us[16]; uint4 u[2];} vv; vv.u[0]=vs[0]; vv.u[1]=vs[1];
    #pragma unroll
    for (int j=0;j<16;j++){
      int d = half*16 + j;
      *(u16*)((char*)VsT + ((d*256 + m*2) ^ ((d&7)<<4))) = vv.us[j];
    }
  }
  __syncthreads();

  int q0 = wave*32;
  short8 qf[2];
  #pragma unroll
  for (int mi=0;mi<2;mi++){
    int ql = 16*mi + (lane&15);
    qf[mi] = *(const short8*)(qkv + base + (size_t)(q0+ql)*1536 + (lane>>4)*8);
  }
  f32x4 s[2][8] = {};
  #pragma unroll
  for (int nj=0;nj<8;nj++){
    int row = (lane&15) + 16*nj;
    short8 kf = *(const short8*)((char*)Ks + row*64 + ((((lane>>4)<<4)) ^ ((row&3)<<4)));
    #pragma unroll
    for (int mi=0;mi<2;mi++)
      s[mi][nj] = __builtin_amdgcn_mfma_f32_16x16x32_bf16(qf[mi], kf, s[mi][nj], 0,0,0);
  }
  __syncthreads();   // Ks now dead; wave0's P may overwrite it

  int rk[8];
  if (shifted){
    #pragma unroll
    for (int nj=0;nj<8;nj++) rk[nj] = region_id(win, (lane&15) + 16*nj);
  }
  const u16* bb = biasF + ((((size_t)h*4 + wave)*64 + lane)*64);
  float invl[2][4];
  char* pbase = (wave==0) ? (char*)Ks : (char*)(sm + 8192 + (wave-1)*4096);
  #pragma unroll
  for (int mi=0;mi<2;mi++){
    #pragma unroll
    for (int r=0;r<4;r++){
      int ql = 16*mi + ((lane>>4)<<2) + r;
      int qw = q0 + ql;
      uint4 bu = *(const uint4*)(bb + (mi*4+r)*8);
      unsigned ba[4] = {bu.x, bu.y, bu.z, bu.w};
      int rq = shifted ? region_id(win, qw) : 0;
      float sv[8]; float mx = -1e30f;
      #pragma unroll
      for (int nj=0;nj<8;nj++){
        float bval = (nj&1) ? bfhi(ba[nj>>1]) : bflo(ba[nj>>1]);
        float v = fmaf(s[mi][nj][r], 0.17677669529663687f, bval);
        if (shifted && rk[nj] != rq) v -= 100.f;
        sv[nj] = v; mx = fmaxf(mx, v);
      }
      #pragma unroll
      for (int o=1;o<16;o<<=1) mx = fmaxf(mx, __shfl_xor(mx, o));
      float sum = 0.f;
      #pragma unroll
      for (int nj=0;nj<8;nj++){ float p = __expf(sv[nj]-mx); sv[nj]=p; sum += p; }
      #pragma unroll
      for (int o=1;o<16;o<<=1) sum += __shfl_xor(sum, o);
      invl[mi][r] = 1.f/sum;
      char* prow = pbase + ql*256;
      int sw = (ql&7)<<4;
      #pragma unroll
      for (int nj=0;nj<8;nj++)
        *(u16*)(prow + ((((lane&15) + (nj<<4))<<1) ^ sw)) = f2bf(sv[nj]);
    }
  }

  f32x4 o2[2][2] = {};
  #pragma unroll
  for (int kk=0;kk<4;kk++){
    int coff = kk*64 + ((lane>>4)<<4);
    short8 pa[2], vb[2];
    #pragma unroll
    for (int mi=0;mi<2;mi++){
      int ql = 16*mi + (lane&15);
      pa[mi] = *(const short8*)(pbase + ql*256 + (coff ^ ((ql&7)<<4)));
    }
    #pragma unroll
    for (int nj=0;nj<2;nj++){
      int d = (lane&15) + 16*nj;
      vb[nj] = *(const short8*)((char*)VsT + d*256 + (coff ^ ((d&7)<<4)));
    }
    #pragma unroll
    for (int mi=0;mi<2;mi++)
      #pragma unroll
      for (int nj=0;nj<2;nj++)
        o2[mi][nj] = __builtin_amdgcn_mfma_f32_16x16x32_bf16(pa[mi], vb[nj], o2[mi][nj], 0,0,0);
  }

  #pragma unroll
  for (int mi=0;mi<2;mi++){
    #pragma unroll
    for (int nj=0;nj<2;nj++){
      #pragma unroll
      for (int r=0;r<4;r++){
        int ql = 16*mi + ((lane>>4)<<2) + r;
        int d  = (lane&15) + (nj<<4);
        out[(size_t)(win*128 + q0 + ql)*DIM + (h<<5) + d] = f2bf(o2[mi][nj][r] * invl[mi][r]);
      }
    }
  }
}

// ---------------- host launcher ----------------
extern "C" void kernel_launch(void* const* d_in, const int* in_sizes, int n_in,
                              void* d_out, int out_size, void* d_ws, size_t ws_size,
                              hipStream_t stream)
{
  const float* x_in   = (const float*)d_in[0];
  const float* ln1_g  = (const float*)d_in[1];
  const float* ln1_b  = (const float*)d_in[2];
  const float* qkv_w  = (const float*)d_in[3];
  const float* qkv_b  = (const float*)d_in[4];
  const float* btab   = (const float*)d_in[5];
  const float* proj_w = (const float*)d_in[6];
  const float* proj_b = (const float*)d_in[7];
  const float* ln2_g  = (const float*)d_in[8];
  const float* ln2_b  = (const float*)d_in[9];
  const float* fc1_w  = (const float*)d_in[10];
  const float* fc1_b  = (const float*)d_in[11];
  const float* fc2_w  = (const float*)d_in[12];
  const float* fc2_b  = (const float*)d_in[13];

  char* ws = (char*)d_ws;
  size_t off = 0;
  auto alloc = [&](size_t bytes)->char*{ char* p = ws + off; off += (bytes + 255) & ~(size_t)255; return p; };
  u16* wT_qkv = (u16*)alloc((size_t)2*512*1536*2);
  u16* wT_proj= (u16*)alloc((size_t)2*512*512*2);
  u16* wT_fc1 = (u16*)alloc((size_t)2*2048*512*2);
  u16* wT_fc2 = (u16*)alloc((size_t)2*512*2048*2);
  u16* bufA   = (u16*)alloc((size_t)16384*2048*2);
  u16* bufQ   = (u16*)alloc((size_t)16384*1536*2);
  u16* bufB   = (u16*)alloc((size_t)16384*512*2);
  u16* xbf    = (u16*)alloc((size_t)16384*512*2);
  u16* biasF  = (u16*)alloc((size_t)2*16*4*64*64*2);
  (void)ws_size; (void)in_sizes; (void)n_in; (void)out_size;

  float* xout = (float*)d_out;

  transpose_kernel<<<dim3(1536/32, 512/32, 2), 256, 0, stream>>>(qkv_w, wT_qkv, 512, 1536);
  transpose_kernel<<<dim3( 512/32, 512/32, 2), 256, 0, stream>>>(proj_w, wT_proj, 512, 512);
  transpose_kernel<<<dim3(2048/32, 512/32, 2), 256, 0, stream>>>(fc1_w, wT_fc1, 512, 2048);
  transpose_kernel<<<dim3( 512/32,2048/32, 2), 256, 0, stream>>>(fc2_w, wT_fc2, 2048, 512);
  biasf_kernel<<<128, 256, 0, stream>>>(btab, biasF);

  for (int i=0;i<2;i++){
    if (i==0)
      ln_f32cvt_kernel<<<4096, 256, 0, stream>>>(x_in, ln1_g, ln1_b, bufA, xbf);
    else
      ln_kernel<<<4096, 256, 0, stream>>>(xbf, ln1_g+512, ln1_b+512, bufA, 1);
    gemm32r_kernel<0><<<dim3(12,128), 256, 0, stream>>>(bufA, wT_qkv+(size_t)i*512*1536, qkv_b+i*1536, bufQ, nullptr, nullptr, NTOK,1536,512, 0);
    attn_kernel<<<2048, 256, 0, stream>>>(bufQ, biasF + (size_t)i*16*4*64*64, bufB, i);
    gemm32r_kernel<1><<<dim3(4,128), 256, 0, stream>>>(bufB, wT_proj+(size_t)i*512*512, proj_b+i*512, nullptr, xbf, nullptr, NTOK,512,512, i);
    ln_kernel<<<4096, 256, 0, stream>>>(xbf, ln2_g+i*512, ln2_b+i*512, bufB, -1);
    gemm32r_kernel<2><<<dim3(16,128), 256, 0, stream>>>(bufB, wT_fc1+(size_t)i*2048*512, fc1_b+i*2048, bufA, nullptr, nullptr, NTOK,2048,512, 0);
    if (i==0)
      gemm32r_kernel<3><<<dim3(4,128), 256, 0, stream>>>(bufA, wT_fc2+(size_t)i*512*2048, fc2_b+i*512, nullptr, xbf, nullptr, NTOK,512,2048, 0);
    else
      gemm32r_kernel<4><<<dim3(4,128), 256, 0, stream>>>(bufA, wT_fc2+(size_t)i*512*2048, fc2_b+i*512, nullptr, xbf, xout, NTOK,512,2048, 0);
  }
}

// Round 21
// 410.752 us; speedup vs baseline: 1.1983x; 1.0182x over previous
//
#include <hip/hip_runtime.h>
#include <stdint.h>

#define DIM 512
#define NHD 16
#define HD 32
#define NTOK 16384

typedef unsigned short u16;
typedef __attribute__((ext_vector_type(8))) short short8;  // 8 bf16 (4 VGPRs)
typedef __attribute__((ext_vector_type(4))) float f32x4;

__device__ __forceinline__ float bflo(unsigned u){ union{unsigned i; float f;} c; c.i=u<<16; return c.f; }
__device__ __forceinline__ float bfhi(unsigned u){ union{unsigned i; float f;} c; c.i=u&0xffff0000u; return c.f; }
__device__ __forceinline__ u16 f2bf(float f){ union{float f; unsigned i;} c; c.f=f; unsigned r=(c.i + 0x7fffu + ((c.i>>16)&1u))>>16; return (u16)r; }

__device__ __forceinline__ int win_to_tok(int r, int shifted){
  int win = r >> 7, n = r & 127;
  int a = win >> 6, b = (win >> 3) & 7, c = win & 7;
  int ic = n >> 6, ih = (n >> 3) & 7, iw = n & 7;
  int gc = a*2 + ic, gh = b*8 + ih, gw = c*8 + iw;
  if (shifted){ gc = (gc + 1) & 3; gh = (gh + 4) & 63; gw = (gw + 4) & 63; }
  return (gc << 12) + (gh << 6) + gw;
}

// region id for the shift mask, computed arithmetically (no LDS)
__device__ __forceinline__ int region_id(int win, int m){
  int gc = ((win>>6)<<1) + (m>>6);
  int gh = (((win>>3)&7)<<3) + ((m>>3)&7);
  int gw = ((win&7)<<3) + (m&7);
  int rc = (gc<2)?0:((gc<3)?1:2);
  int rh = (gh<56)?0:((gh<60)?1:2);
  int rw = (gw<56)?0:((gw<60)?1:2);
  return rc*9 + rh*3 + rw;
}

__device__ __forceinline__ void gload16(const void* g, void* l){
  __builtin_amdgcn_global_load_lds(
    (const __attribute__((address_space(1))) unsigned int*)(unsigned long long)g,
    (__attribute__((address_space(3))) unsigned int*)(unsigned int)(unsigned long long)l,
    16, 0, 0);
}

// ---------------- unified prep: all 4 weight transposes + biasF, one launch ----------------
// flat ranges: [0,1536) qkv | [1536,2048) proj | [2048,4096) fc1 | [4096,6144) fc2 | [6144,6272) biasF
__global__ __launch_bounds__(256)
void prep_kernel(const float* __restrict__ qkv_w, const float* __restrict__ proj_w,
                 const float* __restrict__ fc1_w, const float* __restrict__ fc2_w,
                 u16* __restrict__ wT_qkv, u16* __restrict__ wT_proj,
                 u16* __restrict__ wT_fc1, u16* __restrict__ wT_fc2,
                 const float* __restrict__ btab, u16* __restrict__ biasF)
{
  __shared__ float t[32][33];
  int bidf = blockIdx.x;
  if (bidf >= 6144){
    // ---- biasF (bf16, MFMA C-fragment order) ----
    int gid = (bidf - 6144)*256 + threadIdx.x;   // 2*16*4*64*8 = 32768 entries of 8 bf16
    int j = gid & 7;
    int lane = (gid>>3) & 63;
    int wave = (gid>>9) & 3;
    int h = (gid>>11) & 15;
    int i = gid>>15;
    int mi = j>>2, r = j&3;
    int qw = wave*32 + mi*16 + ((lane>>4)<<2) + r;
    int ic=qw>>6, ih=(qw>>3)&7, iw=qw&7;
    const float* bt = btab + (size_t)i*675*16 + h;
    union{u16 us[8]; uint4 u[2];} o;
    #pragma unroll
    for (int nj=0;nj<8;nj++){
      int k = (lane&15) + nj*16;
      int jc=k>>6, jh=(k>>3)&7, jw=k&7;
      int idx = (ic-jc+1)*225 + (ih-jh+7)*15 + (iw-jw+7);
      o.us[nj] = f2bf(bt[idx*16]);
    }
    *(uint4*)(biasF + (size_t)gid*8) = o.u[0];
    *(uint4*)(biasF + (size_t)gid*8 + 4) = o.u[1];
    return;
  }
  // ---- weight transpose + bf16 cast (true div/mod: tile counts are NOT all powers of 2) ----
  const float* W; u16* Wt; int K, N, nx, ky, iblk;
  if (bidf < 1536){
    iblk = bidf / 768; int r = bidf - iblk*768;           // 48x16 tiles per block
    W = qkv_w;  Wt = wT_qkv;  K = 512;  N = 1536; nx = r % 48; ky = r / 48;
  } else if (bidf < 2048){
    int l = bidf - 1536; iblk = l / 256; int r = l - iblk*256;   // 16x16
    W = proj_w; Wt = wT_proj; K = 512;  N = 512;  nx = r % 16; ky = r / 16;
  } else if (bidf < 4096){
    int l = bidf - 2048; iblk = l / 1024; int r = l - iblk*1024; // 64x16
    W = fc1_w;  Wt = wT_fc1;  K = 512;  N = 2048; nx = r % 64; ky = r / 64;
  } else {
    int l = bidf - 4096; iblk = l / 1024; int r = l - iblk*1024; // 16x64
    W = fc2_w;  Wt = wT_fc2;  K = 2048; N = 512;  nx = r % 16; ky = r / 16;
  }
  size_t zoff = (size_t)iblk * K * N;
  int n0 = nx*32, k0 = ky*32;
  int tx = threadIdx.x & 31, ty = threadIdx.x >> 5;
  #pragma unroll
  for (int i=0;i<4;i++) t[ty + i*8][tx] = W[zoff + (size_t)(k0 + ty + i*8)*N + n0 + tx];
  __syncthreads();
  #pragma unroll
  for (int i=0;i<4;i++) Wt[zoff + (size_t)(n0 + ty + i*8)*K + k0 + tx] = f2bf(t[tx][ty + i*8]);
}

// ---------------- fused first-LN: reads f32 x, writes LN->bufA (window order) AND raw bf16 -> xbf ----------------
__global__ __launch_bounds__(256)
void ln_f32cvt_kernel(const float* __restrict__ x, const float* __restrict__ g,
                      const float* __restrict__ b, u16* __restrict__ out, u16* __restrict__ xbf)
{
  int wave = threadIdx.x >> 6, lane = threadIdx.x & 63;
  int r = blockIdx.x * 4 + wave;
  int src = win_to_tok(r, 0);
  const float4* xr = (const float4*)(x + (size_t)src * DIM);
  float4 v0 = xr[lane*2], v1 = xr[lane*2+1];
  float xv[8] = {v0.x,v0.y,v0.z,v0.w,v1.x,v1.y,v1.z,v1.w};
  union{u16 us[8]; uint4 u;} raw;
  #pragma unroll
  for (int j=0;j<8;j++) raw.us[j] = f2bf(xv[j]);
  ((uint4*)(xbf + (size_t)src*DIM))[lane] = raw.u;
  float s = 0.f, sq = 0.f;
  #pragma unroll
  for (int j=0;j<8;j++){ s += xv[j]; sq += xv[j]*xv[j]; }
  #pragma unroll
  for (int o=32;o;o>>=1){ s += __shfl_xor(s,o); sq += __shfl_xor(sq,o); }
  float mean = s*(1.f/DIM);
  float var  = sq*(1.f/DIM) - mean*mean;
  float rstd = rsqrtf(var + 1e-5f);
  int c0 = lane*8;
  const float4* g4 = (const float4*)(g + c0);
  const float4* b4 = (const float4*)(b + c0);
  float4 ga = g4[0], gb = g4[1], ba = b4[0], bb = b4[1];
  float gg[8] = {ga.x,ga.y,ga.z,ga.w,gb.x,gb.y,gb.z,gb.w};
  float bv[8] = {ba.x,ba.y,ba.z,ba.w,bb.x,bb.y,bb.z,bb.w};
  union{u16 us[8]; uint4 u;} p;
  #pragma unroll
  for (int j=0;j<8;j++) p.us[j] = f2bf((xv[j]-mean)*rstd*gg[j] + bv[j]);
  ((uint4*)(out + (size_t)r*DIM))[lane] = p.u;
}

// ---------------- LayerNorm on bf16 residual (+optional window gather w/ roll) -> bf16 ----------------
__global__ __launch_bounds__(256)
void ln_kernel(const u16* __restrict__ x, const float* __restrict__ g,
               const float* __restrict__ b, u16* __restrict__ out, int mode)
{
  int wave = threadIdx.x >> 6, lane = threadIdx.x & 63;
  int r = blockIdx.x * 4 + wave;
  int src = (mode < 0) ? r : win_to_tok(r, mode);
  uint4 u = ((const uint4*)(x + (size_t)src * DIM))[lane];
  unsigned w[4] = {u.x, u.y, u.z, u.w};
  float xv[8];
  #pragma unroll
  for (int j=0;j<4;j++){ xv[2*j] = bflo(w[j]); xv[2*j+1] = bfhi(w[j]); }
  float s = 0.f, sq = 0.f;
  #pragma unroll
  for (int j=0;j<8;j++){ s += xv[j]; sq += xv[j]*xv[j]; }
  #pragma unroll
  for (int o=32;o;o>>=1){ s += __shfl_xor(s,o); sq += __shfl_xor(sq,o); }
  float mean = s*(1.f/DIM);
  float var  = sq*(1.f/DIM) - mean*mean;
  float rstd = rsqrtf(var + 1e-5f);
  int c0 = lane*8;
  const float4* g4 = (const float4*)(g + c0);
  const float4* b4 = (const float4*)(b + c0);
  float4 ga = g4[0], gb = g4[1], ba = b4[0], bb = b4[1];
  float gg[8] = {ga.x,ga.y,ga.z,ga.w,gb.x,gb.y,gb.z,gb.w};
  float bv[8] = {ba.x,ba.y,ba.z,ba.w,bb.x,bb.y,bb.z,bb.w};
  union{u16 us[8]; uint4 u;} p;
  #pragma unroll
  for (int j=0;j<8;j++) p.us[j] = f2bf((xv[j]-mean)*rstd*gg[j] + bv[j]);
  ((uint4*)(out + (size_t)r*DIM))[lane] = p.u;
}

// ============ gemm32r: 128x128 tile, BK=32, 3-slot LDS ring, counted vmcnt (R12-proven) ============
// EPI 0: store bf16 (qkv)        EPI 1: scatter += into bf16 residual (proj, win_rev+roll)
// EPI 2: tanh-gelu -> bf16 (fc1) EPI 3: += bf16 residual (fc2 block0)
// EPI 4: final fc2: read bf16 residual, add, write f32 d_out
template<int EPI>
__global__ __launch_bounds__(256)
void gemm32r_kernel(const u16* __restrict__ X, const u16* __restrict__ Wt,
                    const float* __restrict__ bias, u16* __restrict__ obf,
                    u16* __restrict__ xbf, float* __restrict__ outf,
                    int M, int N, int K, int shifted)
{
  __shared__ u16 smem[24576];    // 48KB: A slot s @ s*4096, B slot s @ 12288+s*4096 (elems)
  int tid = threadIdx.x, wave = tid>>6, lane = tid&63;
  int nwg = gridDim.x * gridDim.y;
  int bid = blockIdx.y * gridDim.x + blockIdx.x;
  int wg  = (bid & 7) * (nwg >> 3) + (bid >> 3);
  int n0 = (wg % gridDim.x) * 128;
  int m0 = (wg / gridDim.x) * 128;
  int wm = (wave>>1)*64, wn = (wave&1)*64;
  f32x4 acc[4][4] = {};

  int r_[2], c_[2];
  #pragma unroll
  for (int q=0;q<2;q++){
    int line = q*32 + (tid>>3), slot = tid&7;
    int u = slot ^ (line&7);
    r_[q] = line*2 + (u>>2); c_[q] = u&3;
  }

  auto stage = [&](int s, int kb){
    u16* Ad = smem + s*4096;
    u16* Bd = smem + 12288 + s*4096;
    #pragma unroll
    for (int q=0;q<2;q++){
      gload16(X + (size_t)(m0 + r_[q])*K + kb + c_[q]*8, (void*)(Ad + q*2048 + tid*8));
      gload16(Wt + (size_t)(n0 + r_[q])*K + kb + c_[q]*8, (void*)(Bd + q*2048 + tid*8));
    }
  };
  auto ldfrag = [&](const u16* base, int row0)->short8 {
    int r = row0 + (lane&15);
    int slot = (((r&1)<<2) + (lane>>4)) ^ ((r>>1)&7);
    return *(const short8*)((const char*)base + (r>>1)*128 + slot*16);
  };

  int nt = K >> 5;
  stage(0, 0); stage(1, 32);
  asm volatile("s_waitcnt vmcnt(4)" ::: "memory");
  __builtin_amdgcn_sched_barrier(0);
  __builtin_amdgcn_s_barrier();
  __builtin_amdgcn_sched_barrier(0);

  int s = 0;
  for (int t=0; t<nt; ++t){
    int s2 = s+2; if (s2>=3) s2-=3;
    if (t+2 < nt) stage(s2, (t+2)<<5);
    const u16* Ab = smem + s*4096;
    const u16* Bb = smem + 12288 + s*4096;
    short8 af[4], bfr[4];
    #pragma unroll
    for (int mi=0;mi<4;mi++) af[mi]  = ldfrag(Ab, wm + mi*16);
    #pragma unroll
    for (int nj=0;nj<4;nj++) bfr[nj] = ldfrag(Bb, wn + nj*16);
    __builtin_amdgcn_s_setprio(1);
    #pragma unroll
    for (int mi=0;mi<4;mi++)
      #pragma unroll
      for (int nj=0;nj<4;nj++)
        acc[mi][nj] = __builtin_amdgcn_mfma_f32_16x16x32_bf16(af[mi], bfr[nj], acc[mi][nj], 0,0,0);
    __builtin_amdgcn_s_setprio(0);
    asm volatile("s_waitcnt lgkmcnt(0)" ::: "memory");
    __builtin_amdgcn_sched_barrier(0);
    if (t+1 < nt){
      if (t+2 < nt) asm volatile("s_waitcnt vmcnt(4)" ::: "memory");
      else          asm volatile("s_waitcnt vmcnt(0)" ::: "memory");
      __builtin_amdgcn_sched_barrier(0);
    }
    __builtin_amdgcn_s_barrier();
    __builtin_amdgcn_sched_barrier(0);
    s = (s==2) ? 0 : s+1;
  }

  // ---- epilogue (R12-proven) ----
  int lr = (lane>>4)*4, lc = lane&15;
  if (EPI==0 || EPI==2){
    u16* et = smem;                         // [128][128] bf16 = 32KB, byte ^= ((row>>2)&3)<<5
    #pragma unroll
    for (int mi=0;mi<4;mi++){
      #pragma unroll
      for (int nj=0;nj<4;nj++){
        int col = wn + nj*16 + lc;
        float bv = bias[n0 + col];
        #pragma unroll
        for (int rr=0;rr<4;rr++){
          int row = wm + mi*16 + lr + rr;
          float v = acc[mi][nj][rr] + bv;
          if (EPI==2){
            float u2 = v*(1.5957691216057308f + 0.0713548162726f*v*v);
            v = v * __builtin_amdgcn_rcpf(1.f + __expf(-u2));   // tanh-GELU
          }
          *(u16*)((char*)et + ((row*256 + col*2) ^ (((row>>2)&3)<<5))) = f2bf(v);
        }
      }
    }
    __syncthreads();
    #pragma unroll
    for (int j=0;j<8;j++){
      int q = j*256 + tid;
      int row = q>>4, cc = q&15;
      uint4 d = *(const uint4*)((char*)et + ((row*256 + cc*16) ^ (((row>>2)&3)<<5)));
      *(uint4*)(obf + (size_t)(m0+row)*N + n0 + cc*8) = d;
    }
  } else {
    // EPI 1/3/4: f32 repack in two 64-row halves, then bf16-residual RMW (or f32 final store)
    float* et = (float*)smem;               // [64][128] f32 = 32KB, byte ^= ((row>>2)&1)<<6
    #pragma unroll
    for (int half=0; half<2; ++half){
      __syncthreads();
      if ((wm>>6) == half){
        #pragma unroll
        for (int mi=0;mi<4;mi++){
          #pragma unroll
          for (int nj=0;nj<4;nj++){
            int col = wn + nj*16 + lc;
            float bv = bias[n0 + col];
            #pragma unroll
            for (int rr=0;rr<4;rr++){
              int row = (wm & 63) + mi*16 + lr + rr;
              *(float*)((char*)et + ((row*512 + col*4) ^ (((row>>2)&1)<<6))) = acc[mi][nj][rr] + bv;
            }
          }
        }
      }
      __syncthreads();
      #pragma unroll
      for (int j=0;j<4;j++){
        int q = j*256 + tid;                // 1024 chunks of 8 cols
        int row = q>>4, c8 = q&15;
        int swz = ((row>>2)&1)<<6;
        float4 d0 = *(const float4*)((char*)et + ((row*512 + c8*32     ) ^ swz));
        float4 d1 = *(const float4*)((char*)et + ((row*512 + c8*32 + 16) ^ swz));
        int lrow = m0 + half*64 + row;
        int grow = (EPI==1) ? win_to_tok(lrow, shifted) : lrow;
        size_t gofs = (size_t)grow*DIM + n0 + c8*8;
        uint4 xv = *(const uint4*)(xbf + gofs);
        unsigned xw[4] = {xv.x, xv.y, xv.z, xv.w};
        float xs[8];
        #pragma unroll
        for (int k2=0;k2<4;k2++){ xs[2*k2] = bflo(xw[k2]); xs[2*k2+1] = bfhi(xw[k2]); }
        float ds[8] = {d0.x,d0.y,d0.z,d0.w,d1.x,d1.y,d1.z,d1.w};
        if (EPI==4){
          float4 o0 = {xs[0]+ds[0], xs[1]+ds[1], xs[2]+ds[2], xs[3]+ds[3]};
          float4 o1 = {xs[4]+ds[4], xs[5]+ds[5], xs[6]+ds[6], xs[7]+ds[7]};
          float4* op = (float4*)(outf + gofs);
          op[0] = o0; op[1] = o1;
        } else {
          union{u16 us[8]; uint4 u;} nw;
          #pragma unroll
          for (int k2=0;k2<8;k2++) nw.us[k2] = f2bf(xs[k2] + ds[k2]);
          *(uint4*)(xbf + gofs) = nw.u;
        }
      }
    }
  }
}

// ---------------- MFMA windowed attention (40KB LDS -> 4 blocks/CU) ----------------
__global__ __launch_bounds__(256)
void attn_kernel(const u16* __restrict__ qkv, const u16* __restrict__ biasF,
                 u16* __restrict__ out, int shifted)
{
  __shared__ u16 sm[20480];   // 40960 B exactly
  u16* VsT = sm;
  u16* Ks  = sm + 4096;
  int win = blockIdx.x >> 4, h = blockIdx.x & 15;
  int tid = threadIdx.x, wave = tid>>6, lane = tid&63;
  size_t base = (size_t)win*128*1536 + (size_t)h*32;

  {
    int m = tid>>1, half = tid&1;
    const uint4* ks = (const uint4*)(qkv + base + (size_t)m*1536 + 512 + half*16);
    uint4 k0v = ks[0], k1v = ks[1];
    char* krow = (char*)Ks + m*64;
    int c0 = half*32, sw = (m&3)<<4;
    *(uint4*)(krow + ((c0     ) ^ sw)) = k0v;
    *(uint4*)(krow + ((c0 + 16) ^ sw)) = k1v;
    const uint4* vs = (const uint4*)(qkv + base + (size_t)m*1536 + 1024 + half*16);
    union{u16 us[16]; uint4 u[2];} vv; vv.u[0]=vs[0]; vv.u[1]=vs[1];
    #pragma unroll
    for (int j=0;j<16;j++){
      int d = half*16 + j;
      *(u16*)((char*)VsT + ((d*256 + m*2) ^ ((d&7)<<4))) = vv.us[j];
    }
  }
  __syncthreads();

  int q0 = wave*32;
  short8 qf[2];
  #pragma unroll
  for (int mi=0;mi<2;mi++){
    int ql = 16*mi + (lane&15);
    qf[mi] = *(const short8*)(qkv + base + (size_t)(q0+ql)*1536 + (lane>>4)*8);
  }
  f32x4 s[2][8] = {};
  #pragma unroll
  for (int nj=0;nj<8;nj++){
    int row = (lane&15) + 16*nj;
    short8 kf = *(const short8*)((char*)Ks + row*64 + ((((lane>>4)<<4)) ^ ((row&3)<<4)));
    #pragma unroll
    for (int mi=0;mi<2;mi++)
      s[mi][nj] = __builtin_amdgcn_mfma_f32_16x16x32_bf16(qf[mi], kf, s[mi][nj], 0,0,0);
  }
  __syncthreads();   // Ks now dead; wave0's P may overwrite it

  int rk[8];
  if (shifted){
    #pragma unroll
    for (int nj=0;nj<8;nj++) rk[nj] = region_id(win, (lane&15) + 16*nj);
  }
  const u16* bb = biasF + ((((size_t)h*4 + wave)*64 + lane)*64);
  float invl[2][4];
  char* pbase = (wave==0) ? (char*)Ks : (char*)(sm + 8192 + (wave-1)*4096);
  #pragma unroll
  for (int mi=0;mi<2;mi++){
    #pragma unroll
    for (int r=0;r<4;r++){
      int ql = 16*mi + ((lane>>4)<<2) + r;
      int qw = q0 + ql;
      uint4 bu = *(const uint4*)(bb + (mi*4+r)*8);
      unsigned ba[4] = {bu.x, bu.y, bu.z, bu.w};
      int rq = shifted ? region_id(win, qw) : 0;
      float sv[8]; float mx = -1e30f;
      #pragma unroll
      for (int nj=0;nj<8;nj++){
        float bval = (nj&1) ? bfhi(ba[nj>>1]) : bflo(ba[nj>>1]);
        float v = fmaf(s[mi][nj][r], 0.17677669529663687f, bval);
        if (shifted && rk[nj] != rq) v -= 100.f;
        sv[nj] = v; mx = fmaxf(mx, v);
      }
      #pragma unroll
      for (int o=1;o<16;o<<=1) mx = fmaxf(mx, __shfl_xor(mx, o));
      float sum = 0.f;
      #pragma unroll
      for (int nj=0;nj<8;nj++){ float p = __expf(sv[nj]-mx); sv[nj]=p; sum += p; }
      #pragma unroll
      for (int o=1;o<16;o<<=1) sum += __shfl_xor(sum, o);
      invl[mi][r] = 1.f/sum;
      char* prow = pbase + ql*256;
      int sw = (ql&7)<<4;
      #pragma unroll
      for (int nj=0;nj<8;nj++)
        *(u16*)(prow + ((((lane&15) + (nj<<4))<<1) ^ sw)) = f2bf(sv[nj]);
    }
  }

  f32x4 o2[2][2] = {};
  #pragma unroll
  for (int kk=0;kk<4;kk++){
    int coff = kk*64 + ((lane>>4)<<4);
    short8 pa[2], vb[2];
    #pragma unroll
    for (int mi=0;mi<2;mi++){
      int ql = 16*mi + (lane&15);
      pa[mi] = *(const short8*)(pbase + ql*256 + (coff ^ ((ql&7)<<4)));
    }
    #pragma unroll
    for (int nj=0;nj<2;nj++){
      int d = (lane&15) + 16*nj;
      vb[nj] = *(const short8*)((char*)VsT + d*256 + (coff ^ ((d&7)<<4)));
    }
    #pragma unroll
    for (int mi=0;mi<2;mi++)
      #pragma unroll
      for (int nj=0;nj<2;nj++)
        o2[mi][nj] = __builtin_amdgcn_mfma_f32_16x16x32_bf16(pa[mi], vb[nj], o2[mi][nj], 0,0,0);
  }

  #pragma unroll
  for (int mi=0;mi<2;mi++){
    #pragma unroll
    for (int nj=0;nj<2;nj++){
      #pragma unroll
      for (int r=0;r<4;r++){
        int ql = 16*mi + ((lane>>4)<<2) + r;
        int d  = (lane&15) + (nj<<4);
        out[(size_t)(win*128 + q0 + ql)*DIM + (h<<5) + d] = f2bf(o2[mi][nj][r] * invl[mi][r]);
      }
    }
  }
}

// ---------------- host launcher ----------------
extern "C" void kernel_launch(void* const* d_in, const int* in_sizes, int n_in,
                              void* d_out, int out_size, void* d_ws, size_t ws_size,
                              hipStream_t stream)
{
  const float* x_in   = (const float*)d_in[0];
  const float* ln1_g  = (const float*)d_in[1];
  const float* ln1_b  = (const float*)d_in[2];
  const float* qkv_w  = (const float*)d_in[3];
  const float* qkv_b  = (const float*)d_in[4];
  const float* btab   = (const float*)d_in[5];
  const float* proj_w = (const float*)d_in[6];
  const float* proj_b = (const float*)d_in[7];
  const float* ln2_g  = (const float*)d_in[8];
  const float* ln2_b  = (const float*)d_in[9];
  const float* fc1_w  = (const float*)d_in[10];
  const float* fc1_b  = (const float*)d_in[11];
  const float* fc2_w  = (const float*)d_in[12];
  const float* fc2_b  = (const float*)d_in[13];

  char* ws = (char*)d_ws;
  size_t off = 0;
  auto alloc = [&](size_t bytes)->char*{ char* p = ws + off; off += (bytes + 255) & ~(size_t)255; return p; };
  u16* wT_qkv = (u16*)alloc((size_t)2*512*1536*2);
  u16* wT_proj= (u16*)alloc((size_t)2*512*512*2);
  u16* wT_fc1 = (u16*)alloc((size_t)2*2048*512*2);
  u16* wT_fc2 = (u16*)alloc((size_t)2*512*2048*2);
  u16* bufA   = (u16*)alloc((size_t)16384*2048*2);
  u16* bufQ   = (u16*)alloc((size_t)16384*1536*2);
  u16* bufB   = (u16*)alloc((size_t)16384*512*2);
  u16* xbf    = (u16*)alloc((size_t)16384*512*2);
  u16* biasF  = (u16*)alloc((size_t)2*16*4*64*64*2);
  (void)ws_size; (void)in_sizes; (void)n_in; (void)out_size;

  float* xout = (float*)d_out;

  prep_kernel<<<6272, 256, 0, stream>>>(qkv_w, proj_w, fc1_w, fc2_w,
                                        wT_qkv, wT_proj, wT_fc1, wT_fc2, btab, biasF);

  for (int i=0;i<2;i++){
    if (i==0)
      ln_f32cvt_kernel<<<4096, 256, 0, stream>>>(x_in, ln1_g, ln1_b, bufA, xbf);
    else
      ln_kernel<<<4096, 256, 0, stream>>>(xbf, ln1_g+512, ln1_b+512, bufA, 1);
    gemm32r_kernel<0><<<dim3(12,128), 256, 0, stream>>>(bufA, wT_qkv+(size_t)i*512*1536, qkv_b+i*1536, bufQ, nullptr, nullptr, NTOK,1536,512, 0);
    attn_kernel<<<2048, 256, 0, stream>>>(bufQ, biasF + (size_t)i*16*4*64*64, bufB, i);
    gemm32r_kernel<1><<<dim3(4,128), 256, 0, stream>>>(bufB, wT_proj+(size_t)i*512*512, proj_b+i*512, nullptr, xbf, nullptr, NTOK,512,512, i);
    ln_kernel<<<4096, 256, 0, stream>>>(xbf, ln2_g+i*512, ln2_b+i*512, bufB, -1);
    gemm32r_kernel<2><<<dim3(16,128), 256, 0, stream>>>(bufB, wT_fc1+(size_t)i*2048*512, fc1_b+i*2048, bufA, nullptr, nullptr, NTOK,2048,512, 0);
    if (i==0)
      gemm32r_kernel<3><<<dim3(4,128), 256, 0, stream>>>(bufA, wT_fc2+(size_t)i*512*2048, fc2_b+i*512, nullptr, xbf, nullptr, NTOK,512,2048, 0);
    else
      gemm32r_kernel<4><<<dim3(4,128), 256, 0, stream>>>(bufA, wT_fc2+(size_t)i*512*2048, fc2_b+i*512, nullptr, xbf, xout, NTOK,512,2048, 0);
  }
}